// Round 3
// baseline (722.002 us; speedup 1.0000x reference)
//
#include <hip/hip_runtime.h>

#define NPTS 32768
#define DIM 32
#define NH 8
#define NC 3
#define BSZ 128
#define NB 256
#define DH 35
#define DP 36
#define NSEG 24   // C*H

typedef unsigned long long ull;
typedef __attribute__((ext_vector_type(8))) short bf16x8;
typedef __attribute__((ext_vector_type(4))) float f32x4;

__device__ __forceinline__ unsigned fmap(float f){
  unsigned b = __float_as_uint(f);
  return (b & 0x80000000u) ? ~b : (b | 0x80000000u);
}
__device__ __forceinline__ float funmap(unsigned u){
  unsigned b = (u & 0x80000000u) ? (u & 0x7fffffffu) : ~u;
  return __uint_as_float(b);
}
__device__ __forceinline__ unsigned short f2bf(float f){
  unsigned u = __float_as_uint(f);
  u += 0x7fffu + ((u >> 16) & 1u);
  return (unsigned short)(u >> 16);
}
__device__ __forceinline__ float bf2f(unsigned short h){
  return __uint_as_float(((unsigned)h) << 16);
}

// ---------------- prep
__global__ __launch_bounds__(256) void k_prep(const float* __restrict__ w_rpe,
        float* __restrict__ qw_sqrt, unsigned* __restrict__ slots_hi,
        unsigned* __restrict__ slots_lo){
  int tid = threadIdx.x;
  if (tid < NSEG){ slots_hi[tid] = 0u; slots_lo[tid] = 0xFFFFFFFFu; }
  __shared__ float S[24][8];
  if (tid < 192){
    int hr = tid >> 3, kk = tid & 7;
    int h = hr / 3, r = hr % 3;
    float s = 0.f;
    #pragma unroll
    for (int d = 0; d < DIM; ++d) s += w_rpe[(h*DIM + d)*24 + (r*8 + kk)];
    S[hr][kk] = expf(fminf(s, 50.f));
  }
  __syncthreads();
  if (tid < 24){
    float q = 0.f;
    #pragma unroll
    for (int kk = 0; kk < 8; ++kk) q += S[tid][kk];
    qw_sqrt[tid] = sqrtf(2.f * q);
  }
}

// ---------------- LN1 + QKV projection fused
__global__ __launch_bounds__(256) void k_qkv(const float* __restrict__ x,
        const float* __restrict__ n1w, const float* __restrict__ n1b,
        const float* __restrict__ coords, const float* __restrict__ wq,
        const float* __restrict__ wk, const float* __restrict__ wv,
        const float* __restrict__ qw_sqrt,
        float* __restrict__ q_hat, float* __restrict__ k_hat,
        float* __restrict__ val){
  __shared__ float W[3][DIM][NH*DIM];   // 96 KB
  __shared__ float XT[32][33];
  int tid = threadIdx.x;
  for (int idx = tid; idx < 3*DIM*NH*DIM; idx += 256){
    int which = idx / (DIM*NH*DIM);
    int rem = idx % (DIM*NH*DIM);
    const float* src = which==0 ? wq : (which==1 ? wk : wv);
    W[which][rem/(NH*DIM)][rem%(NH*DIM)] = src[rem];
  }
  int base = blockIdx.x * 32;
  if (tid < 32){
    const float4* xr4 = (const float4*)(x + (size_t)(base + tid)*DIM);
    float4 v[8];
    float s = 0.f;
    #pragma unroll
    for (int u = 0; u < 8; ++u){ v[u] = xr4[u]; s += v[u].x+v[u].y+v[u].z+v[u].w; }
    float mu = s * (1.f/32.f);
    float var = 0.f;
    #pragma unroll
    for (int u = 0; u < 8; ++u){
      float a0=v[u].x-mu, a1=v[u].y-mu, a2=v[u].z-mu, a3=v[u].w-mu;
      var += a0*a0+a1*a1+a2*a2+a3*a3;
    }
    var *= (1.f/32.f);
    float rs = rsqrtf(var + 1e-5f);
    #pragma unroll
    for (int u = 0; u < 8; ++u){
      XT[tid][u*4+0] = (v[u].x-mu)*rs*n1w[u*4+0] + n1b[u*4+0];
      XT[tid][u*4+1] = (v[u].y-mu)*rs*n1w[u*4+1] + n1b[u*4+1];
      XT[tid][u*4+2] = (v[u].z-mu)*rs*n1w[u*4+2] + n1b[u*4+2];
      XT[tid][u*4+3] = (v[u].w-mu)*rs*n1w[u*4+3] + n1b[u*4+3];
    }
  }
  __syncthreads();
  int h = tid >> 5, i = tid & 31;
  int n = base + i;
  float xr[32];
  #pragma unroll
  for (int d = 0; d < 32; ++d) xr[d] = XT[i][d];
  float cpart[3];
  #pragma unroll
  for (int r = 0; r < 3; ++r) cpart[r] = qw_sqrt[h*3+r] * coords[(size_t)n*3 + r];

  float* dq = q_hat + ((size_t)h*NPTS + n)*DP;
  float* dk = k_hat + ((size_t)h*NPTS + n)*DP;
  float* dv = val   + ((size_t)h*NPTS + n)*DIM;
  #pragma unroll
  for (int which = 0; which < 3; ++which){
    for (int j0 = 0; j0 < 32; j0 += 4){
      float4 acc = {0.f,0.f,0.f,0.f};
      #pragma unroll
      for (int d = 0; d < 32; ++d){
        float4 wv4 = *(const float4*)&W[which][d][h*32 + j0];
        acc.x += xr[d]*wv4.x; acc.y += xr[d]*wv4.y;
        acc.z += xr[d]*wv4.z; acc.w += xr[d]*wv4.w;
      }
      if (which == 0)      *(float4*)&dq[j0] = acc;
      else if (which == 1) *(float4*)&dk[j0] = acc;
      else                 *(float4*)&dv[j0] = acc;
    }
  }
  dq[32]=cpart[0]; dq[33]=cpart[1]; dq[34]=cpart[2]; dq[35]=0.f;
  dk[32]=cpart[0]; dk[33]=cpart[1]; dk[34]=cpart[2]; dk[35]=0.f;
}

// ---------------- LSH hash values + per-(c,h) hi/lo
__global__ __launch_bounds__(256) void k_hash(const float* __restrict__ q_hat,
        const float* __restrict__ k_hat, const float* __restrict__ alpha,
        float* __restrict__ qh_buf, float* __restrict__ kh_buf,
        unsigned* __restrict__ slots_hi, unsigned* __restrict__ slots_lo){
  int h = blockIdx.y;
  int n = blockIdx.x*256 + threadIdx.x;
  __shared__ float A[DH][NC];
  for (int idx = threadIdx.x; idx < DH*NC; idx += 256)
    A[idx/3][idx%3] = alpha[h*DH*NC + idx];
  __syncthreads();
  float qr[36], kr[36];
  const float4* qp = (const float4*)(q_hat + ((size_t)h*NPTS + n)*DP);
  const float4* kp = (const float4*)(k_hat + ((size_t)h*NPTS + n)*DP);
  #pragma unroll
  for (int u = 0; u < 9; ++u){
    *(float4*)&qr[u*4] = qp[u];
    *(float4*)&kr[u*4] = kp[u];
  }
  #pragma unroll
  for (int c = 0; c < NC; ++c){
    float qh = 0.f, kh = 0.f;
    #pragma unroll
    for (int d = 0; d < DH; ++d){ qh += qr[d]*A[d][c]; kh += kr[d]*A[d][c]; }
    qh_buf[((size_t)(c*NH + h))*NPTS + n] = qh;
    kh_buf[((size_t)(c*NH + h))*NPTS + n] = kh;
    float hi = fmaxf(qh, kh), lo = fminf(qh, kh);
    #pragma unroll
    for (int off = 32; off; off >>= 1){
      hi = fmaxf(hi, __shfl_xor(hi, off));
      lo = fminf(lo, __shfl_xor(lo, off));
    }
    if ((threadIdx.x & 63) == 0){
      atomicMax(&slots_hi[c*NH + h], fmap(hi));
      atomicMin(&slots_lo[c*NH + h], fmap(lo));
    }
  }
}

// ---------------- pack + first bitonic stage fused (k=2..8192 within 8192-chunk)
__global__ __launch_bounds__(256) void k_sort_pack_local(
        const float* __restrict__ qh_buf, const float* __restrict__ kh_buf,
        const int* __restrict__ shifts,
        const unsigned* __restrict__ slots_hi, const unsigned* __restrict__ slots_lo,
        ull* __restrict__ packed){
  __shared__ ull ld[8192];     // 64 KB
  int chunk = blockIdx.x;            // 0..191
  int lst = chunk >> 2;              // 0..47 (0..23 q, 24..47 k)
  int seg = lst < NSEG ? lst : lst - NSEG;
  const float* buf = lst < NSEG ? qh_buf : kh_buf;
  unsigned coff = (unsigned)(chunk & 3) * 8192u;
  float hs = funmap(slots_hi[seg]) - funmap(slots_lo[seg]);
  for (int idx = threadIdx.x; idx < 8192; idx += 256){
    unsigned n = coff + idx;
    size_t gi = (size_t)seg*NPTS + n;
    float key = buf[gi] + (float)shifts[gi] * hs;
    ld[idx] = ((ull)fmap(key) << 32) | n;
  }
  __syncthreads();
  for (unsigned k = 2; k <= 8192u; k <<= 1){
    unsigned j0 = (k >> 1) < 4096u ? (k >> 1) : 4096u;
    for (unsigned j = j0; j > 0; j >>= 1){
      for (unsigned p = threadIdx.x; p < 4096; p += 256){
        unsigned i  = ((p & ~(j-1)) << 1) | (p & (j-1));
        unsigned x2 = i | j;
        bool up = (((coff + i) & k) == 0);
        ull a = ld[i], b = ld[x2];
        if ((a > b) == up){ ld[i] = b; ld[x2] = a; }
      }
      __syncthreads();
    }
  }
  size_t base = (size_t)lst*NPTS + coff;
  for (int idx = threadIdx.x; idx < 8192; idx += 256) packed[base + idx] = ld[idx];
}

// ---------------- bitonic sort: LDS chunk kernel
__global__ __launch_bounds__(256) void k_sort_local(ull* __restrict__ data,
        unsigned k_lo, unsigned k_hi){
  __shared__ ull ld[8192];     // 64 KB
  int chunk = blockIdx.x;
  size_t base = (size_t)chunk * 8192;
  unsigned segoff = (unsigned)(chunk & 3) * 8192u;
  for (int idx = threadIdx.x; idx < 8192; idx += 256) ld[idx] = data[base + idx];
  __syncthreads();
  for (unsigned k = k_lo; k <= k_hi; k <<= 1){
    unsigned j0 = (k >> 1) < 4096u ? (k >> 1) : 4096u;
    for (unsigned j = j0; j > 0; j >>= 1){
      for (unsigned p = threadIdx.x; p < 4096; p += 256){
        unsigned i  = ((p & ~(j-1)) << 1) | (p & (j-1));
        unsigned x2 = i | j;
        bool up = (((segoff + i) & k) == 0);
        ull a = ld[i], b = ld[x2];
        if ((a > b) == up){ ld[i] = b; ld[x2] = a; }
      }
      __syncthreads();
    }
  }
  for (int idx = threadIdx.x; idx < 8192; idx += 256) data[base + idx] = ld[idx];
}

// ---------------- bitonic sort: one global compare-exchange pass
__global__ __launch_bounds__(256) void k_sort_global(ull* __restrict__ data,
        unsigned k, unsigned j){
  unsigned t = blockIdx.x*256 + threadIdx.x;
  unsigned seg = t >> 14;
  unsigned p = t & 16383u;
  unsigned i  = ((p & ~(j-1)) << 1) | (p & (j-1));
  unsigned x2 = i | j;
  size_t base = (size_t)seg << 15;
  bool up = ((i & k) == 0);
  ull a = data[base + i], b = data[base + x2];
  if ((a > b) == up){ data[base + i] = b; data[base + x2] = a; }
}

// ---------------- bucketed kernelized attention (MFMA, split-bf16, Q/K/V in LDS)
// row layout (64 shorts): dims 0..34 data, 35 = {K: ksq, Q: 1.0},
// 36 = {K: 1.0, Q: qsq}, 37..63 = 0.  S = dot + ksq + qsq directly.
__global__ __launch_bounds__(512, 4) void k_attn(const float* __restrict__ q_hat,
        const float* __restrict__ k_hat, const float* __restrict__ val,
        const ull* __restrict__ packed, float* __restrict__ o_acc,
        float* __restrict__ logit_acc){
  __shared__ short Khi[128*64];      // 16 KB
  __shared__ short Klo[128*64];      // 16 KB
  __shared__ short Qhi[128*64];      // 16 KB (P aliases own-wave rows later)
  __shared__ short Qlo[128*64];      // 16 KB
  __shared__ short Vt[32*128];       // 8 KB [vdim][key] swizzled
  __shared__ unsigned iq_lds[128];

  int t = threadIdx.x;
  int blk = blockIdx.x;
  int seg = blk >> 8;
  int b = blk & 255;
  int h = seg & 7;
  const ull* pq = packed + ((size_t)seg << 15) + (size_t)b*BSZ;
  const ull* pk = packed + ((size_t)(NSEG + seg) << 15) + (size_t)b*BSZ;

  if (t < 256){
    int r = t & 127;
    bool isq = t >= 128;
    unsigned idx = (unsigned)((isq ? pq[r] : pk[r]) & 0xffffffffull);
    if (isq) iq_lds[r] = idx;
    const float* src = (isq ? q_hat : k_hat) + ((size_t)h*NPTS + idx)*DP;
    float f[40];
    #pragma unroll
    for (int u = 0; u < 9; ++u) *(float4*)&f[u*4] = ((const float4*)src)[u];
    float sq = 0.f;
    #pragma unroll
    for (int d = 0; d < 36; ++d) sq += f[d]*f[d];   // f[35] is 0 pad
    sq = -0.5f * sq;
    f[35] = isq ? 1.0f : sq;
    f[36] = isq ? sq : 1.0f;
    f[37] = 0.f; f[38] = 0.f; f[39] = 0.f;
    short* Hi = isq ? Qhi : Khi;
    short* Lo = isq ? Qlo : Klo;
    int rowbase = r*64;
    int sw = (r & 7) << 3;
    #pragma unroll
    for (int c = 0; c < 40; c += 4){
      unsigned short h0=f2bf(f[c]),   h1=f2bf(f[c+1]);
      unsigned short h2=f2bf(f[c+2]), h3=f2bf(f[c+3]);
      unsigned short l0=f2bf(f[c]  -bf2f(h0)), l1=f2bf(f[c+1]-bf2f(h1));
      unsigned short l2=f2bf(f[c+2]-bf2f(h2)), l3=f2bf(f[c+3]-bf2f(h3));
      int o = rowbase + (c ^ sw);
      uint2 hv, lv;
      hv.x = (unsigned)h0 | ((unsigned)h1 << 16);
      hv.y = (unsigned)h2 | ((unsigned)h3 << 16);
      lv.x = (unsigned)l0 | ((unsigned)l1 << 16);
      lv.y = (unsigned)l2 | ((unsigned)l3 << 16);
      *(uint2*)&Hi[o] = hv;
      *(uint2*)&Lo[o] = lv;
    }
    #pragma unroll
    for (int c = 40; c < 64; c += 4){
      int o = rowbase + (c ^ sw);
      *(uint2*)&Hi[o] = (uint2){0u,0u};
      *(uint2*)&Lo[o] = (uint2){0u,0u};
    }
  } else {
    int r = (t - 256) & 127;
    int half = (t - 256) >> 7;   // 0 or 1
    unsigned ik = (unsigned)(pk[r] & 0xffffffffull);
    const float* vr = val + ((size_t)h*NPTS + ik)*DIM + 16*half;
    float fv[16];
    #pragma unroll
    for (int u = 0; u < 4; ++u) *(float4*)&fv[u*4] = ((const float4*)vr)[u];
    #pragma unroll
    for (int d = 0; d < 16; ++d){
      int vd = 16*half + d;
      Vt[vd*128 + (r ^ ((vd&7)<<3))] = (short)f2bf(fv[d]);
    }
  }
  __syncthreads();

  int lane = t & 63;
  int w = t >> 6;                 // wave 0..7, owns q rows [16w, 16w+16)
  int l15 = lane & 15, g = lane >> 4;
  int qrow = 16*w + l15;
  int qsw = (qrow & 7) << 3;
  const short* qbh = &Qhi[qrow*64];
  const short* qbl = &Qlo[qrow*64];
  bf16x8 qh0 = *(const bf16x8*)&qbh[(8*g) ^ qsw];
  bf16x8 qh1 = *(const bf16x8*)&qbh[(32 + 8*g) ^ qsw];
  bf16x8 ql0 = *(const bf16x8*)&qbl[(8*g) ^ qsw];
  bf16x8 ql1 = *(const bf16x8*)&qbl[(32 + 8*g) ^ qsw];

  f32x4 acc[8];
  #pragma unroll
  for (int kt = 0; kt < 8; ++kt) acc[kt] = (f32x4){0.f,0.f,0.f,0.f};

  #pragma unroll
  for (int kt = 0; kt < 8; ++kt){
    int krow = 16*kt + l15;
    int base = krow*64;
    int sw = (krow & 7) << 3;
    bf16x8 ah0 = *(const bf16x8*)&Khi[base + ((8*g) ^ sw)];
    bf16x8 ah1 = *(const bf16x8*)&Khi[base + ((32 + 8*g) ^ sw)];
    bf16x8 al0 = *(const bf16x8*)&Klo[base + ((8*g) ^ sw)];
    bf16x8 al1 = *(const bf16x8*)&Klo[base + ((32 + 8*g) ^ sw)];
    f32x4 c = acc[kt];
    c = __builtin_amdgcn_mfma_f32_16x16x32_bf16(ah0, qh0, c, 0, 0, 0);
    c = __builtin_amdgcn_mfma_f32_16x16x32_bf16(ah1, qh1, c, 0, 0, 0);
    c = __builtin_amdgcn_mfma_f32_16x16x32_bf16(al0, qh0, c, 0, 0, 0);
    c = __builtin_amdgcn_mfma_f32_16x16x32_bf16(al1, qh1, c, 0, 0, 0);
    c = __builtin_amdgcn_mfma_f32_16x16x32_bf16(ah0, ql0, c, 0, 0, 0);
    c = __builtin_amdgcn_mfma_f32_16x16x32_bf16(ah1, ql1, c, 0, 0, 0);
    acc[kt] = c;
  }

  // exp + P -> bf16 into own-wave Q rows (dead after fragment load); fp32 denom
  float dena = 0.f;
  #pragma unroll
  for (int kt = 0; kt < 8; ++kt){
    f32x4 c = acc[kt];
    float p0 = __expf(fminf(c[0], 0.f));
    float p1 = __expf(fminf(c[1], 0.f));
    float p2 = __expf(fminf(c[2], 0.f));
    float p3 = __expf(fminf(c[3], 0.f));
    dena += p0 + p1 + p2 + p3;
    int key = 16*kt + 4*g;              // 4 consecutive keys
    uint2 pv;
    pv.x = (unsigned)f2bf(p0) | ((unsigned)f2bf(p1) << 16);
    pv.y = (unsigned)f2bf(p2) | ((unsigned)f2bf(p3) << 16);
    short* Pbuf = (key < 64) ? Qhi : Qlo;
    *(uint2*)&Pbuf[qrow*64 + ((key & 63) ^ qsw)] = pv;
  }

  // PV via MFMA: A = P (m=q), B = V^T (n=vdim)
  f32x4 oacc[2];
  oacc[0] = (f32x4){0.f,0.f,0.f,0.f};
  oacc[1] = (f32x4){0.f,0.f,0.f,0.f};
  #pragma unroll
  for (int ks = 0; ks < 4; ++ks){
    int key = 32*ks + 8*g;
    const short* Pbuf = (key < 64) ? Qhi : Qlo;
    bf16x8 pA = *(const bf16x8*)&Pbuf[qrow*64 + ((key & 63) ^ qsw)];
    #pragma unroll
    for (int nt = 0; nt < 2; ++nt){
      int vd = 16*nt + l15;
      bf16x8 vB = *(const bf16x8*)&Vt[vd*128 + ((32*ks + 8*g) ^ ((vd&7)<<3))];
      oacc[nt] = __builtin_amdgcn_mfma_f32_16x16x32_bf16(pA, vB, oacc[nt], 0, 0, 0);
    }
  }

  // denom scatter
  {
    float d = dena;
    d += __shfl_xor(d, 16);
    d += __shfl_xor(d, 32);
    if (lane < 16) atomicAdd(&logit_acc[(size_t)h*NPTS + iq_lds[qrow]], d + 1e-20f);
  }
  // O scatter
  #pragma unroll
  for (int nt = 0; nt < 2; ++nt){
    f32x4 c = oacc[nt];
    #pragma unroll
    for (int r = 0; r < 4; ++r){
      unsigned iq = iq_lds[16*w + 4*g + r];
      atomicAdd(&o_acc[((size_t)h*NPTS + iq)*DIM + 16*nt + l15], c[r]);
    }
  }
}

// ---------------- out-proj + residual + LN2 + FF + residual
__global__ __launch_bounds__(256) void k_final(const float* __restrict__ x,
        const float* __restrict__ o_acc, const float* __restrict__ logit_acc,
        const float* __restrict__ out_w, const float* __restrict__ out_b,
        const float* __restrict__ n2w, const float* __restrict__ n2b,
        const float* __restrict__ f1w, const float* __restrict__ f1b,
        const float* __restrict__ f2w, const float* __restrict__ f2b,
        float* __restrict__ out){
  __shared__ float OW[256][32];   // 32 KB
  __shared__ float F1[32][32];
  __shared__ float F2[32][32];
  int tid = threadIdx.x;
  for (int idx = tid; idx < 256*32; idx += 256) OW[idx/32][idx%32] = out_w[idx];
  for (int idx = tid; idx < 1024; idx += 256){
    F1[idx/32][idx%32] = f1w[idx];
    F2[idx/32][idx%32] = f2w[idx];
  }
  __syncthreads();
  int n = blockIdx.x*256 + tid;
  float attn[32];
  #pragma unroll
  for (int j = 0; j < 32; ++j) attn[j] = out_b[j];
  for (int h = 0; h < 8; ++h){
    float inv = 1.f / logit_acc[(size_t)h*NPTS + n];
    const float4* orow = (const float4*)(o_acc + ((size_t)h*NPTS + n)*DIM);
    #pragma unroll
    for (int u = 0; u < 8; ++u){
      float4 ov = orow[u];
      float vals[4] = {ov.x*inv, ov.y*inv, ov.z*inv, ov.w*inv};
      #pragma unroll
      for (int s = 0; s < 4; ++s){
        const float* wrow = &OW[h*32 + u*4 + s][0];
        #pragma unroll
        for (int j = 0; j < 32; ++j) attn[j] += vals[s] * wrow[j];
      }
    }
  }
  const float* xp = x + (size_t)n*DIM;
  float xr[32]; float s = 0.f;
  #pragma unroll
  for (int d = 0; d < 32; ++d){ xr[d] = xp[d] + attn[d]; s += xr[d]; }
  float mu = s * (1.f/32.f);
  float var = 0.f;
  #pragma unroll
  for (int d = 0; d < 32; ++d){ float dx = xr[d]-mu; var += dx*dx; }
  var *= (1.f/32.f);
  float rs = rsqrtf(var + 1e-5f);
  float xn2[32];
  #pragma unroll
  for (int d = 0; d < 32; ++d) xn2[d] = (xr[d]-mu)*rs*n2w[d] + n2b[d];
  float z[32];
  #pragma unroll
  for (int j = 0; j < 32; ++j) z[j] = f1b[j];
  #pragma unroll
  for (int d = 0; d < 32; ++d){
    float xd = xn2[d];
    const float* wrow = &F1[d][0];
    #pragma unroll
    for (int j = 0; j < 32; ++j) z[j] += xd * wrow[j];
  }
  #pragma unroll
  for (int j = 0; j < 32; ++j) z[j] = z[j] / (1.f + __expf(-z[j]));
  float y[32];
  #pragma unroll
  for (int d = 0; d < 32; ++d) y[d] = f2b[d];
  #pragma unroll
  for (int j = 0; j < 32; ++j){
    float zj = z[j];
    const float* wrow = &F2[j][0];
    #pragma unroll
    for (int d = 0; d < 32; ++d) y[d] += zj * wrow[d];
  }
  float* op = out + (size_t)n*DIM;
  #pragma unroll
  for (int d = 0; d < 32; ++d) op[d] = xr[d] + y[d];
}

extern "C" void kernel_launch(void* const* d_in, const int* in_sizes, int n_in,
                              void* d_out, int out_size, void* d_ws, size_t ws_size,
                              hipStream_t stream){
  const float* x      = (const float*)d_in[0];
  const float* coords = (const float*)d_in[1];
  const int*   shifts = (const int*)d_in[2];
  const float* n1w    = (const float*)d_in[3];
  const float* n1b    = (const float*)d_in[4];
  const float* wq     = (const float*)d_in[5];
  const float* wk     = (const float*)d_in[6];
  const float* wv     = (const float*)d_in[7];
  const float* w_rpe  = (const float*)d_in[8];
  const float* alpha  = (const float*)d_in[9];
  const float* out_w  = (const float*)d_in[10];
  const float* out_b  = (const float*)d_in[11];
  const float* n2w    = (const float*)d_in[12];
  const float* n2b    = (const float*)d_in[13];
  const float* f1w    = (const float*)d_in[14];
  const float* f1b    = (const float*)d_in[15];
  const float* f2w    = (const float*)d_in[16];
  const float* f2b    = (const float*)d_in[17];
  float* out = (float*)d_out;

  char* ws = (char*)d_ws;
  size_t off = 0;
  auto alloc = [&](size_t bytes){ size_t o = off; off += (bytes + 255) & ~(size_t)255; return o; };
  float*    qw_sqrt   = (float*)   (ws + alloc(24*4));
  unsigned* slots_hi  = (unsigned*)(ws + alloc(24*4));
  unsigned* slots_lo  = (unsigned*)(ws + alloc(24*4));
  float*    q_hat     = (float*)   (ws + alloc((size_t)NH*NPTS*DP*4));
  float*    k_hat     = (float*)   (ws + alloc((size_t)NH*NPTS*DP*4));
  float*    val       = (float*)   (ws + alloc((size_t)NH*NPTS*DIM*4));
  float*    qh_buf    = (float*)   (ws + alloc((size_t)NSEG*NPTS*4));
  float*    kh_buf    = (float*)   (ws + alloc((size_t)NSEG*NPTS*4));
  ull*      packed    = (ull*)     (ws + alloc((size_t)2*NSEG*NPTS*8));
  float*    o_acc     = (float*)   (ws + alloc((size_t)NH*NPTS*DIM*4));
  float*    logit_acc = (float*)   (ws + alloc((size_t)NH*NPTS*4));
  if (off > ws_size) return;

  hipMemsetAsync(o_acc, 0, (size_t)NH*NPTS*DIM*4, stream);
  hipMemsetAsync(logit_acc, 0, (size_t)NH*NPTS*4, stream);

  k_prep<<<1, 256, 0, stream>>>(w_rpe, qw_sqrt, slots_hi, slots_lo);
  k_qkv<<<NPTS/32, 256, 0, stream>>>(x, n1w, n1b, coords, wq, wk, wv, qw_sqrt,
                                     q_hat, k_hat, val);
  k_hash<<<dim3(NPTS/256, NH), 256, 0, stream>>>(q_hat, k_hat, alpha, qh_buf, kh_buf,
                                                 slots_hi, slots_lo);
  // 48 segments of 32768 -> bitonic
  k_sort_pack_local<<<2*NSEG*4, 256, 0, stream>>>(qh_buf, kh_buf, shifts,
                                                  slots_hi, slots_lo, packed);
  k_sort_global<<<(2*NSEG*16384)/256, 256, 0, stream>>>(packed, 16384u, 8192u);
  k_sort_local<<<2*NSEG*4, 256, 0, stream>>>(packed, 16384u, 16384u);
  k_sort_global<<<(2*NSEG*16384)/256, 256, 0, stream>>>(packed, 32768u, 16384u);
  k_sort_global<<<(2*NSEG*16384)/256, 256, 0, stream>>>(packed, 32768u, 8192u);
  k_sort_local<<<2*NSEG*4, 256, 0, stream>>>(packed, 32768u, 32768u);

  k_attn<<<NSEG*NB, 512, 0, stream>>>(q_hat, k_hat, val, packed, o_acc, logit_acc);
  k_final<<<NPTS/256, 256, 0, stream>>>(x, o_acc, logit_acc, out_w, out_b,
                                        n2w, n2b, f1w, f1b, f2w, f2b, out);
}

// Round 4
// 721.837 us; speedup vs baseline: 1.0002x; 1.0002x over previous
//
#include <hip/hip_runtime.h>

#define NPTS 32768
#define DIM 32
#define NH 8
#define NC 3
#define BSZ 128
#define NB 256
#define DH 35
#define DP 36
#define NSEG 24   // C*H

typedef unsigned long long ull;
typedef __attribute__((ext_vector_type(8))) short bf16x8;
typedef __attribute__((ext_vector_type(4))) float f32x4;

__device__ __forceinline__ unsigned fmap(float f){
  unsigned b = __float_as_uint(f);
  return (b & 0x80000000u) ? ~b : (b | 0x80000000u);
}
__device__ __forceinline__ float funmap(unsigned u){
  unsigned b = (u & 0x80000000u) ? (u & 0x7fffffffu) : ~u;
  return __uint_as_float(b);
}
__device__ __forceinline__ unsigned short f2bf(float f){
  unsigned u = __float_as_uint(f);
  u += 0x7fffu + ((u >> 16) & 1u);
  return (unsigned short)(u >> 16);
}
__device__ __forceinline__ float bf2f(unsigned short h){
  return __uint_as_float(((unsigned)h) << 16);
}

// ---------------- prep
__global__ __launch_bounds__(256) void k_prep(const float* __restrict__ w_rpe,
        float* __restrict__ qw_sqrt, unsigned* __restrict__ slots_hi,
        unsigned* __restrict__ slots_lo){
  int tid = threadIdx.x;
  if (tid < NSEG){ slots_hi[tid] = 0u; slots_lo[tid] = 0xFFFFFFFFu; }
  __shared__ float S[24][8];
  if (tid < 192){
    int hr = tid >> 3, kk = tid & 7;
    int h = hr / 3, r = hr % 3;
    float s = 0.f;
    #pragma unroll
    for (int d = 0; d < DIM; ++d) s += w_rpe[(h*DIM + d)*24 + (r*8 + kk)];
    S[hr][kk] = expf(fminf(s, 50.f));
  }
  __syncthreads();
  if (tid < 24){
    float q = 0.f;
    #pragma unroll
    for (int kk = 0; kk < 8; ++kk) q += S[tid][kk];
    qw_sqrt[tid] = sqrtf(2.f * q);
  }
}

// ---------------- LN1 + QKV projection fused
__global__ __launch_bounds__(256) void k_qkv(const float* __restrict__ x,
        const float* __restrict__ n1w, const float* __restrict__ n1b,
        const float* __restrict__ coords, const float* __restrict__ wq,
        const float* __restrict__ wk, const float* __restrict__ wv,
        const float* __restrict__ qw_sqrt,
        float* __restrict__ q_hat, float* __restrict__ k_hat,
        float* __restrict__ val){
  __shared__ float W[3][DIM][NH*DIM];   // 96 KB
  __shared__ float XT[32][33];
  int tid = threadIdx.x;
  for (int idx = tid; idx < 3*DIM*NH*DIM; idx += 256){
    int which = idx / (DIM*NH*DIM);
    int rem = idx % (DIM*NH*DIM);
    const float* src = which==0 ? wq : (which==1 ? wk : wv);
    W[which][rem/(NH*DIM)][rem%(NH*DIM)] = src[rem];
  }
  int base = blockIdx.x * 32;
  if (tid < 32){
    const float4* xr4 = (const float4*)(x + (size_t)(base + tid)*DIM);
    float4 v[8];
    float s = 0.f;
    #pragma unroll
    for (int u = 0; u < 8; ++u){ v[u] = xr4[u]; s += v[u].x+v[u].y+v[u].z+v[u].w; }
    float mu = s * (1.f/32.f);
    float var = 0.f;
    #pragma unroll
    for (int u = 0; u < 8; ++u){
      float a0=v[u].x-mu, a1=v[u].y-mu, a2=v[u].z-mu, a3=v[u].w-mu;
      var += a0*a0+a1*a1+a2*a2+a3*a3;
    }
    var *= (1.f/32.f);
    float rs = rsqrtf(var + 1e-5f);
    #pragma unroll
    for (int u = 0; u < 8; ++u){
      XT[tid][u*4+0] = (v[u].x-mu)*rs*n1w[u*4+0] + n1b[u*4+0];
      XT[tid][u*4+1] = (v[u].y-mu)*rs*n1w[u*4+1] + n1b[u*4+1];
      XT[tid][u*4+2] = (v[u].z-mu)*rs*n1w[u*4+2] + n1b[u*4+2];
      XT[tid][u*4+3] = (v[u].w-mu)*rs*n1w[u*4+3] + n1b[u*4+3];
    }
  }
  __syncthreads();
  int h = tid >> 5, i = tid & 31;
  int n = base + i;
  float xr[32];
  #pragma unroll
  for (int d = 0; d < 32; ++d) xr[d] = XT[i][d];
  float cpart[3];
  #pragma unroll
  for (int r = 0; r < 3; ++r) cpart[r] = qw_sqrt[h*3+r] * coords[(size_t)n*3 + r];

  float* dq = q_hat + ((size_t)h*NPTS + n)*DP;
  float* dk = k_hat + ((size_t)h*NPTS + n)*DP;
  float* dv = val   + ((size_t)h*NPTS + n)*DIM;
  #pragma unroll
  for (int which = 0; which < 3; ++which){
    for (int j0 = 0; j0 < 32; j0 += 4){
      float4 acc = {0.f,0.f,0.f,0.f};
      #pragma unroll
      for (int d = 0; d < 32; ++d){
        float4 wv4 = *(const float4*)&W[which][d][h*32 + j0];
        acc.x += xr[d]*wv4.x; acc.y += xr[d]*wv4.y;
        acc.z += xr[d]*wv4.z; acc.w += xr[d]*wv4.w;
      }
      if (which == 0)      *(float4*)&dq[j0] = acc;
      else if (which == 1) *(float4*)&dk[j0] = acc;
      else                 *(float4*)&dv[j0] = acc;
    }
  }
  dq[32]=cpart[0]; dq[33]=cpart[1]; dq[34]=cpart[2]; dq[35]=0.f;
  dk[32]=cpart[0]; dk[33]=cpart[1]; dk[34]=cpart[2]; dk[35]=0.f;
}

// ---------------- LSH hash values + per-(c,h) hi/lo
__global__ __launch_bounds__(256) void k_hash(const float* __restrict__ q_hat,
        const float* __restrict__ k_hat, const float* __restrict__ alpha,
        float* __restrict__ qh_buf, float* __restrict__ kh_buf,
        unsigned* __restrict__ slots_hi, unsigned* __restrict__ slots_lo){
  int h = blockIdx.y;
  int n = blockIdx.x*256 + threadIdx.x;
  __shared__ float A[DH][NC];
  for (int idx = threadIdx.x; idx < DH*NC; idx += 256)
    A[idx/3][idx%3] = alpha[h*DH*NC + idx];
  __syncthreads();
  float qr[36], kr[36];
  const float4* qp = (const float4*)(q_hat + ((size_t)h*NPTS + n)*DP);
  const float4* kp = (const float4*)(k_hat + ((size_t)h*NPTS + n)*DP);
  #pragma unroll
  for (int u = 0; u < 9; ++u){
    *(float4*)&qr[u*4] = qp[u];
    *(float4*)&kr[u*4] = kp[u];
  }
  #pragma unroll
  for (int c = 0; c < NC; ++c){
    float qh = 0.f, kh = 0.f;
    #pragma unroll
    for (int d = 0; d < DH; ++d){ qh += qr[d]*A[d][c]; kh += kr[d]*A[d][c]; }
    qh_buf[((size_t)(c*NH + h))*NPTS + n] = qh;
    kh_buf[((size_t)(c*NH + h))*NPTS + n] = kh;
    float hi = fmaxf(qh, kh), lo = fminf(qh, kh);
    #pragma unroll
    for (int off = 32; off; off >>= 1){
      hi = fmaxf(hi, __shfl_xor(hi, off));
      lo = fminf(lo, __shfl_xor(lo, off));
    }
    if ((threadIdx.x & 63) == 0){
      atomicMax(&slots_hi[c*NH + h], fmap(hi));
      atomicMin(&slots_lo[c*NH + h], fmap(lo));
    }
  }
}

// ---------------- pack + first bitonic stage fused (k=2..8192 within 8192-chunk)
__global__ __launch_bounds__(256) void k_sort_pack_local(
        const float* __restrict__ qh_buf, const float* __restrict__ kh_buf,
        const int* __restrict__ shifts,
        const unsigned* __restrict__ slots_hi, const unsigned* __restrict__ slots_lo,
        ull* __restrict__ packed){
  __shared__ ull ld[8192];     // 64 KB
  int chunk = blockIdx.x;            // 0..191
  int lst = chunk >> 2;              // 0..47 (0..23 q, 24..47 k)
  int seg = lst < NSEG ? lst : lst - NSEG;
  const float* buf = lst < NSEG ? qh_buf : kh_buf;
  unsigned coff = (unsigned)(chunk & 3) * 8192u;
  float hs = funmap(slots_hi[seg]) - funmap(slots_lo[seg]);
  for (int idx = threadIdx.x; idx < 8192; idx += 256){
    unsigned n = coff + idx;
    size_t gi = (size_t)seg*NPTS + n;
    float key = buf[gi] + (float)shifts[gi] * hs;
    ld[idx] = ((ull)fmap(key) << 32) | n;
  }
  __syncthreads();
  for (unsigned k = 2; k <= 8192u; k <<= 1){
    unsigned j0 = (k >> 1) < 4096u ? (k >> 1) : 4096u;
    for (unsigned j = j0; j > 0; j >>= 1){
      for (unsigned p = threadIdx.x; p < 4096; p += 256){
        unsigned i  = ((p & ~(j-1)) << 1) | (p & (j-1));
        unsigned x2 = i | j;
        bool up = (((coff + i) & k) == 0);
        ull a = ld[i], b = ld[x2];
        if ((a > b) == up){ ld[i] = b; ld[x2] = a; }
      }
      __syncthreads();
    }
  }
  size_t base = (size_t)lst*NPTS + coff;
  for (int idx = threadIdx.x; idx < 8192; idx += 256) packed[base + idx] = ld[idx];
}

// ---------------- bitonic sort: LDS chunk kernel
__global__ __launch_bounds__(256) void k_sort_local(ull* __restrict__ data,
        unsigned k_lo, unsigned k_hi){
  __shared__ ull ld[8192];     // 64 KB
  int chunk = blockIdx.x;
  size_t base = (size_t)chunk * 8192;
  unsigned segoff = (unsigned)(chunk & 3) * 8192u;
  for (int idx = threadIdx.x; idx < 8192; idx += 256) ld[idx] = data[base + idx];
  __syncthreads();
  for (unsigned k = k_lo; k <= k_hi; k <<= 1){
    unsigned j0 = (k >> 1) < 4096u ? (k >> 1) : 4096u;
    for (unsigned j = j0; j > 0; j >>= 1){
      for (unsigned p = threadIdx.x; p < 4096; p += 256){
        unsigned i  = ((p & ~(j-1)) << 1) | (p & (j-1));
        unsigned x2 = i | j;
        bool up = (((segoff + i) & k) == 0);
        ull a = ld[i], b = ld[x2];
        if ((a > b) == up){ ld[i] = b; ld[x2] = a; }
      }
      __syncthreads();
    }
  }
  for (int idx = threadIdx.x; idx < 8192; idx += 256) data[base + idx] = ld[idx];
}

// ---------------- bitonic sort: one global compare-exchange pass
__global__ __launch_bounds__(256) void k_sort_global(ull* __restrict__ data,
        unsigned k, unsigned j){
  unsigned t = blockIdx.x*256 + threadIdx.x;
  unsigned seg = t >> 14;
  unsigned p = t & 16383u;
  unsigned i  = ((p & ~(j-1)) << 1) | (p & (j-1));
  unsigned x2 = i | j;
  size_t base = (size_t)seg << 15;
  bool up = ((i & k) == 0);
  ull a = data[base + i], b = data[base + x2];
  if ((a > b) == up){ data[base + i] = b; data[base + x2] = a; }
}

// ---------------- bucketed kernelized attention (MFMA, split-bf16, Q/K/V in LDS)
// row layout (64 shorts): dims 0..34 data, 35 = {K: ksq, Q: 1.0},
// 36 = {K: 1.0, Q: qsq}, 37..63 = 0.  S = dot + ksq + qsq directly.
__global__ __launch_bounds__(512, 4) void k_attn(const float* __restrict__ q_hat,
        const float* __restrict__ k_hat, const float* __restrict__ val,
        const ull* __restrict__ packed, float* __restrict__ o_acc,
        float* __restrict__ logit_acc){
  __shared__ short Khi[128*64];      // 16 KB
  __shared__ short Klo[128*64];      // 16 KB
  __shared__ short Qhi[128*64];      // 16 KB (P aliases own-wave rows later)
  __shared__ short Qlo[128*64];      // 16 KB
  __shared__ short Vt[32*128];       // 8 KB [vdim][key] swizzled
  __shared__ unsigned iq_lds[128];

  int t = threadIdx.x;
  int blk = blockIdx.x;
  int seg = blk >> 8;
  int b = blk & 255;
  int h = seg & 7;
  const ull* pq = packed + ((size_t)seg << 15) + (size_t)b*BSZ;
  const ull* pk = packed + ((size_t)(NSEG + seg) << 15) + (size_t)b*BSZ;

  if (t < 256){
    int r = t & 127;
    bool isq = t >= 128;
    unsigned idx = (unsigned)((isq ? pq[r] : pk[r]) & 0xffffffffull);
    if (isq) iq_lds[r] = idx;
    const float* src = (isq ? q_hat : k_hat) + ((size_t)h*NPTS + idx)*DP;
    float f[40];
    #pragma unroll
    for (int u = 0; u < 9; ++u) *(float4*)&f[u*4] = ((const float4*)src)[u];
    float sq = 0.f;
    #pragma unroll
    for (int d = 0; d < 36; ++d) sq += f[d]*f[d];   // f[35] is 0 pad
    sq = -0.5f * sq;
    f[35] = isq ? 1.0f : sq;
    f[36] = isq ? sq : 1.0f;
    f[37] = 0.f; f[38] = 0.f; f[39] = 0.f;
    short* Hi = isq ? Qhi : Khi;
    short* Lo = isq ? Qlo : Klo;
    int rowbase = r*64;
    int sw = (r & 7) << 3;
    #pragma unroll
    for (int c = 0; c < 40; c += 4){
      unsigned short h0=f2bf(f[c]),   h1=f2bf(f[c+1]);
      unsigned short h2=f2bf(f[c+2]), h3=f2bf(f[c+3]);
      unsigned short l0=f2bf(f[c]  -bf2f(h0)), l1=f2bf(f[c+1]-bf2f(h1));
      unsigned short l2=f2bf(f[c+2]-bf2f(h2)), l3=f2bf(f[c+3]-bf2f(h3));
      int o = rowbase + (c ^ sw);
      uint2 hv, lv;
      hv.x = (unsigned)h0 | ((unsigned)h1 << 16);
      hv.y = (unsigned)h2 | ((unsigned)h3 << 16);
      lv.x = (unsigned)l0 | ((unsigned)l1 << 16);
      lv.y = (unsigned)l2 | ((unsigned)l3 << 16);
      *(uint2*)&Hi[o] = hv;
      *(uint2*)&Lo[o] = lv;
    }
    #pragma unroll
    for (int c = 40; c < 64; c += 4){
      int o = rowbase + (c ^ sw);
      *(uint2*)&Hi[o] = (uint2){0u,0u};
      *(uint2*)&Lo[o] = (uint2){0u,0u};
    }
  } else {
    int r = (t - 256) & 127;
    int half = (t - 256) >> 7;   // 0 or 1
    unsigned ik = (unsigned)(pk[r] & 0xffffffffull);
    const float* vr = val + ((size_t)h*NPTS + ik)*DIM + 16*half;
    float fv[16];
    #pragma unroll
    for (int u = 0; u < 4; ++u) *(float4*)&fv[u*4] = ((const float4*)vr)[u];
    #pragma unroll
    for (int d = 0; d < 16; ++d){
      int vd = 16*half + d;
      Vt[vd*128 + (r ^ ((vd&7)<<3))] = (short)f2bf(fv[d]);
    }
  }
  __syncthreads();

  int lane = t & 63;
  int w = t >> 6;                 // wave 0..7, owns q rows [16w, 16w+16)
  int l15 = lane & 15, g = lane >> 4;
  int qrow = 16*w + l15;
  int qsw = (qrow & 7) << 3;
  const short* qbh = &Qhi[qrow*64];
  const short* qbl = &Qlo[qrow*64];
  bf16x8 qh0 = *(const bf16x8*)&qbh[(8*g) ^ qsw];
  bf16x8 qh1 = *(const bf16x8*)&qbh[(32 + 8*g) ^ qsw];
  bf16x8 ql0 = *(const bf16x8*)&qbl[(8*g) ^ qsw];
  bf16x8 ql1 = *(const bf16x8*)&qbl[(32 + 8*g) ^ qsw];

  f32x4 acc[8];
  #pragma unroll
  for (int kt = 0; kt < 8; ++kt) acc[kt] = (f32x4){0.f,0.f,0.f,0.f};

  #pragma unroll
  for (int kt = 0; kt < 8; ++kt){
    int krow = 16*kt + l15;
    int base = krow*64;
    int sw = (krow & 7) << 3;
    bf16x8 ah0 = *(const bf16x8*)&Khi[base + ((8*g) ^ sw)];
    bf16x8 ah1 = *(const bf16x8*)&Khi[base + ((32 + 8*g) ^ sw)];
    bf16x8 al0 = *(const bf16x8*)&Klo[base + ((8*g) ^ sw)];
    bf16x8 al1 = *(const bf16x8*)&Klo[base + ((32 + 8*g) ^ sw)];
    f32x4 c = acc[kt];
    c = __builtin_amdgcn_mfma_f32_16x16x32_bf16(ah0, qh0, c, 0, 0, 0);
    c = __builtin_amdgcn_mfma_f32_16x16x32_bf16(ah1, qh1, c, 0, 0, 0);
    c = __builtin_amdgcn_mfma_f32_16x16x32_bf16(al0, qh0, c, 0, 0, 0);
    c = __builtin_amdgcn_mfma_f32_16x16x32_bf16(al1, qh1, c, 0, 0, 0);
    c = __builtin_amdgcn_mfma_f32_16x16x32_bf16(ah0, ql0, c, 0, 0, 0);
    c = __builtin_amdgcn_mfma_f32_16x16x32_bf16(ah1, ql1, c, 0, 0, 0);
    acc[kt] = c;
  }

  // exp + P -> bf16 into own-wave Q rows (dead after fragment load); fp32 denom
  float dena = 0.f;
  #pragma unroll
  for (int kt = 0; kt < 8; ++kt){
    f32x4 c = acc[kt];
    float p0 = __expf(fminf(c[0], 0.f));
    float p1 = __expf(fminf(c[1], 0.f));
    float p2 = __expf(fminf(c[2], 0.f));
    float p3 = __expf(fminf(c[3], 0.f));
    dena += p0 + p1 + p2 + p3;
    int key = 16*kt + 4*g;              // 4 consecutive keys
    uint2 pv;
    pv.x = (unsigned)f2bf(p0) | ((unsigned)f2bf(p1) << 16);
    pv.y = (unsigned)f2bf(p2) | ((unsigned)f2bf(p3) << 16);
    short* Pbuf = (key < 64) ? Qhi : Qlo;
    *(uint2*)&Pbuf[qrow*64 + ((key & 63) ^ qsw)] = pv;
  }

  // PV via MFMA: A = P (m=q), B = V^T (n=vdim)
  f32x4 oacc[2];
  oacc[0] = (f32x4){0.f,0.f,0.f,0.f};
  oacc[1] = (f32x4){0.f,0.f,0.f,0.f};
  #pragma unroll
  for (int ks = 0; ks < 4; ++ks){
    int key = 32*ks + 8*g;
    const short* Pbuf = (key < 64) ? Qhi : Qlo;
    bf16x8 pA = *(const bf16x8*)&Pbuf[qrow*64 + ((key & 63) ^ qsw)];
    #pragma unroll
    for (int nt = 0; nt < 2; ++nt){
      int vd = 16*nt + l15;
      bf16x8 vB = *(const bf16x8*)&Vt[vd*128 + ((32*ks + 8*g) ^ ((vd&7)<<3))];
      oacc[nt] = __builtin_amdgcn_mfma_f32_16x16x32_bf16(pA, vB, oacc[nt], 0, 0, 0);
    }
  }

  // denom scatter
  {
    float d = dena;
    d += __shfl_xor(d, 16);
    d += __shfl_xor(d, 32);
    if (lane < 16) atomicAdd(&logit_acc[(size_t)h*NPTS + iq_lds[qrow]], d + 1e-20f);
  }
  // O scatter
  #pragma unroll
  for (int nt = 0; nt < 2; ++nt){
    f32x4 c = oacc[nt];
    #pragma unroll
    for (int r = 0; r < 4; ++r){
      unsigned iq = iq_lds[16*w + 4*g + r];
      atomicAdd(&o_acc[((size_t)h*NPTS + iq)*DIM + 16*nt + l15], c[r]);
    }
  }
}

// ---------------- out-proj + residual + LN2 + FF + residual
__global__ __launch_bounds__(256) void k_final(const float* __restrict__ x,
        const float* __restrict__ o_acc, const float* __restrict__ logit_acc,
        const float* __restrict__ out_w, const float* __restrict__ out_b,
        const float* __restrict__ n2w, const float* __restrict__ n2b,
        const float* __restrict__ f1w, const float* __restrict__ f1b,
        const float* __restrict__ f2w, const float* __restrict__ f2b,
        float* __restrict__ out){
  __shared__ float OW[256][32];   // 32 KB
  __shared__ float F1[32][32];
  __shared__ float F2[32][32];
  int tid = threadIdx.x;
  for (int idx = tid; idx < 256*32; idx += 256) OW[idx/32][idx%32] = out_w[idx];
  for (int idx = tid; idx < 1024; idx += 256){
    F1[idx/32][idx%32] = f1w[idx];
    F2[idx/32][idx%32] = f2w[idx];
  }
  __syncthreads();
  int n = blockIdx.x*256 + tid;
  float attn[32];
  #pragma unroll
  for (int j = 0; j < 32; ++j) attn[j] = out_b[j];
  for (int h = 0; h < 8; ++h){
    float inv = 1.f / logit_acc[(size_t)h*NPTS + n];
    const float4* orow = (const float4*)(o_acc + ((size_t)h*NPTS + n)*DIM);
    #pragma unroll
    for (int u = 0; u < 8; ++u){
      float4 ov = orow[u];
      float vals[4] = {ov.x*inv, ov.y*inv, ov.z*inv, ov.w*inv};
      #pragma unroll
      for (int s = 0; s < 4; ++s){
        const float* wrow = &OW[h*32 + u*4 + s][0];
        #pragma unroll
        for (int j = 0; j < 32; ++j) attn[j] += vals[s] * wrow[j];
      }
    }
  }
  const float* xp = x + (size_t)n*DIM;
  float xr[32]; float s = 0.f;
  #pragma unroll
  for (int d = 0; d < 32; ++d){ xr[d] = xp[d] + attn[d]; s += xr[d]; }
  float mu = s * (1.f/32.f);
  float var = 0.f;
  #pragma unroll
  for (int d = 0; d < 32; ++d){ float dx = xr[d]-mu; var += dx*dx; }
  var *= (1.f/32.f);
  float rs = rsqrtf(var + 1e-5f);
  float xn2[32];
  #pragma unroll
  for (int d = 0; d < 32; ++d) xn2[d] = (xr[d]-mu)*rs*n2w[d] + n2b[d];
  float z[32];
  #pragma unroll
  for (int j = 0; j < 32; ++j) z[j] = f1b[j];
  #pragma unroll
  for (int d = 0; d < 32; ++d){
    float xd = xn2[d];
    const float* wrow = &F1[d][0];
    #pragma unroll
    for (int j = 0; j < 32; ++j) z[j] += xd * wrow[j];
  }
  #pragma unroll
  for (int j = 0; j < 32; ++j) z[j] = z[j] / (1.f + __expf(-z[j]));
  float y[32];
  #pragma unroll
  for (int d = 0; d < 32; ++d) y[d] = f2b[d];
  #pragma unroll
  for (int j = 0; j < 32; ++j){
    float zj = z[j];
    const float* wrow = &F2[j][0];
    #pragma unroll
    for (int d = 0; d < 32; ++d) y[d] += zj * wrow[d];
  }
  float* op = out + (size_t)n*DIM;
  #pragma unroll
  for (int d = 0; d < 32; ++d) op[d] = xr[d] + y[d];
}

extern "C" void kernel_launch(void* const* d_in, const int* in_sizes, int n_in,
                              void* d_out, int out_size, void* d_ws, size_t ws_size,
                              hipStream_t stream){
  const float* x      = (const float*)d_in[0];
  const float* coords = (const float*)d_in[1];
  const int*   shifts = (const int*)d_in[2];
  const float* n1w    = (const float*)d_in[3];
  const float* n1b    = (const float*)d_in[4];
  const float* wq     = (const float*)d_in[5];
  const float* wk     = (const float*)d_in[6];
  const float* wv     = (const float*)d_in[7];
  const float* w_rpe  = (const float*)d_in[8];
  const float* alpha  = (const float*)d_in[9];
  const float* out_w  = (const float*)d_in[10];
  const float* out_b  = (const float*)d_in[11];
  const float* n2w    = (const float*)d_in[12];
  const float* n2b    = (const float*)d_in[13];
  const float* f1w    = (const float*)d_in[14];
  const float* f1b    = (const float*)d_in[15];
  const float* f2w    = (const float*)d_in[16];
  const float* f2b    = (const float*)d_in[17];
  float* out = (float*)d_out;

  char* ws = (char*)d_ws;
  size_t off = 0;
  auto alloc = [&](size_t bytes){ size_t o = off; off += (bytes + 255) & ~(size_t)255; return o; };
  float*    qw_sqrt   = (float*)   (ws + alloc(24*4));
  unsigned* slots_hi  = (unsigned*)(ws + alloc(24*4));
  unsigned* slots_lo  = (unsigned*)(ws + alloc(24*4));
  float*    q_hat     = (float*)   (ws + alloc((size_t)NH*NPTS*DP*4));
  float*    k_hat     = (float*)   (ws + alloc((size_t)NH*NPTS*DP*4));
  float*    val       = (float*)   (ws + alloc((size_t)NH*NPTS*DIM*4));
  float*    qh_buf    = (float*)   (ws + alloc((size_t)NSEG*NPTS*4));
  float*    kh_buf    = (float*)   (ws + alloc((size_t)NSEG*NPTS*4));
  ull*      packed    = (ull*)     (ws + alloc((size_t)2*NSEG*NPTS*8));
  float*    o_acc     = (float*)   (ws + alloc((size_t)NH*NPTS*DIM*4));
  float*    logit_acc = (float*)   (ws + alloc((size_t)NH*NPTS*4));
  if (off > ws_size) return;

  hipMemsetAsync(o_acc, 0, (size_t)NH*NPTS*DIM*4, stream);
  hipMemsetAsync(logit_acc, 0, (size_t)NH*NPTS*4, stream);

  k_prep<<<1, 256, 0, stream>>>(w_rpe, qw_sqrt, slots_hi, slots_lo);
  k_qkv<<<NPTS/32, 256, 0, stream>>>(x, n1w, n1b, coords, wq, wk, wv, qw_sqrt,
                                     q_hat, k_hat, val);
  k_hash<<<dim3(NPTS/256, NH), 256, 0, stream>>>(q_hat, k_hat, alpha, qh_buf, kh_buf,
                                                 slots_hi, slots_lo);
  // 48 segments of 32768 -> bitonic
  k_sort_pack_local<<<2*NSEG*4, 256, 0, stream>>>(qh_buf, kh_buf, shifts,
                                                  slots_hi, slots_lo, packed);
  k_sort_global<<<(2*NSEG*16384)/256, 256, 0, stream>>>(packed, 16384u, 8192u);
  k_sort_local<<<2*NSEG*4, 256, 0, stream>>>(packed, 16384u, 16384u);
  k_sort_global<<<(2*NSEG*16384)/256, 256, 0, stream>>>(packed, 32768u, 16384u);
  k_sort_global<<<(2*NSEG*16384)/256, 256, 0, stream>>>(packed, 32768u, 8192u);
  k_sort_local<<<2*NSEG*4, 256, 0, stream>>>(packed, 32768u, 32768u);

  k_attn<<<NSEG*NB, 512, 0, stream>>>(q_hat, k_hat, val, packed, o_acc, logit_acc);
  k_final<<<NPTS/256, 256, 0, stream>>>(x, o_acc, logit_acc, out_w, out_b,
                                        n2w, n2b, f1w, f1b, f2w, f2b, out);
}

// Round 5
// 721.471 us; speedup vs baseline: 1.0007x; 1.0005x over previous
//
#include <hip/hip_runtime.h>

#define NPTS 32768
#define DIM 32
#define NH 8
#define NC 3
#define BSZ 128
#define NB 256
#define DH 35
#define DP 36
#define NSEG 24   // C*H

typedef unsigned long long ull;
typedef __attribute__((ext_vector_type(8))) short bf16x8;
typedef __attribute__((ext_vector_type(4))) float f32x4;

__device__ __forceinline__ unsigned fmap(float f){
  unsigned b = __float_as_uint(f);
  return (b & 0x80000000u) ? ~b : (b | 0x80000000u);
}
__device__ __forceinline__ float funmap(unsigned u){
  unsigned b = (u & 0x80000000u) ? (u & 0x7fffffffu) : ~u;
  return __uint_as_float(b);
}
__device__ __forceinline__ unsigned short f2bf(float f){
  unsigned u = __float_as_uint(f);
  u += 0x7fffu + ((u >> 16) & 1u);
  return (unsigned short)(u >> 16);
}
__device__ __forceinline__ float bf2f(unsigned short h){
  return __uint_as_float(((unsigned)h) << 16);
}

// ---------------- prep
__global__ __launch_bounds__(256) void k_prep(const float* __restrict__ w_rpe,
        float* __restrict__ qw_sqrt, unsigned* __restrict__ slots_hi,
        unsigned* __restrict__ slots_lo){
  int tid = threadIdx.x;
  if (tid < NSEG){ slots_hi[tid] = 0u; slots_lo[tid] = 0xFFFFFFFFu; }
  __shared__ float S[24][8];
  if (tid < 192){
    int hr = tid >> 3, kk = tid & 7;
    int h = hr / 3, r = hr % 3;
    float s = 0.f;
    #pragma unroll
    for (int d = 0; d < DIM; ++d) s += w_rpe[(h*DIM + d)*24 + (r*8 + kk)];
    S[hr][kk] = expf(fminf(s, 50.f));
  }
  __syncthreads();
  if (tid < 24){
    float q = 0.f;
    #pragma unroll
    for (int kk = 0; kk < 8; ++kk) q += S[tid][kk];
    qw_sqrt[tid] = sqrtf(2.f * q);
  }
}

// ---------------- LN1 + QKV projection fused
__global__ __launch_bounds__(256) void k_qkv(const float* __restrict__ x,
        const float* __restrict__ n1w, const float* __restrict__ n1b,
        const float* __restrict__ coords, const float* __restrict__ wq,
        const float* __restrict__ wk, const float* __restrict__ wv,
        const float* __restrict__ qw_sqrt,
        float* __restrict__ q_hat, float* __restrict__ k_hat,
        float* __restrict__ val){
  __shared__ float W[3][DIM][NH*DIM];   // 96 KB
  __shared__ float XT[32][33];
  int tid = threadIdx.x;
  for (int idx = tid; idx < 3*DIM*NH*DIM; idx += 256){
    int which = idx / (DIM*NH*DIM);
    int rem = idx % (DIM*NH*DIM);
    const float* src = which==0 ? wq : (which==1 ? wk : wv);
    W[which][rem/(NH*DIM)][rem%(NH*DIM)] = src[rem];
  }
  int base = blockIdx.x * 32;
  if (tid < 32){
    const float4* xr4 = (const float4*)(x + (size_t)(base + tid)*DIM);
    float4 v[8];
    float s = 0.f;
    #pragma unroll
    for (int u = 0; u < 8; ++u){ v[u] = xr4[u]; s += v[u].x+v[u].y+v[u].z+v[u].w; }
    float mu = s * (1.f/32.f);
    float var = 0.f;
    #pragma unroll
    for (int u = 0; u < 8; ++u){
      float a0=v[u].x-mu, a1=v[u].y-mu, a2=v[u].z-mu, a3=v[u].w-mu;
      var += a0*a0+a1*a1+a2*a2+a3*a3;
    }
    var *= (1.f/32.f);
    float rs = rsqrtf(var + 1e-5f);
    #pragma unroll
    for (int u = 0; u < 8; ++u){
      XT[tid][u*4+0] = (v[u].x-mu)*rs*n1w[u*4+0] + n1b[u*4+0];
      XT[tid][u*4+1] = (v[u].y-mu)*rs*n1w[u*4+1] + n1b[u*4+1];
      XT[tid][u*4+2] = (v[u].z-mu)*rs*n1w[u*4+2] + n1b[u*4+2];
      XT[tid][u*4+3] = (v[u].w-mu)*rs*n1w[u*4+3] + n1b[u*4+3];
    }
  }
  __syncthreads();
  int h = tid >> 5, i = tid & 31;
  int n = base + i;
  float xr[32];
  #pragma unroll
  for (int d = 0; d < 32; ++d) xr[d] = XT[i][d];
  float cpart[3];
  #pragma unroll
  for (int r = 0; r < 3; ++r) cpart[r] = qw_sqrt[h*3+r] * coords[(size_t)n*3 + r];

  float* dq = q_hat + ((size_t)h*NPTS + n)*DP;
  float* dk = k_hat + ((size_t)h*NPTS + n)*DP;
  float* dv = val   + ((size_t)h*NPTS + n)*DIM;
  #pragma unroll
  for (int which = 0; which < 3; ++which){
    for (int j0 = 0; j0 < 32; j0 += 4){
      float4 acc = {0.f,0.f,0.f,0.f};
      #pragma unroll
      for (int d = 0; d < 32; ++d){
        float4 wv4 = *(const float4*)&W[which][d][h*32 + j0];
        acc.x += xr[d]*wv4.x; acc.y += xr[d]*wv4.y;
        acc.z += xr[d]*wv4.z; acc.w += xr[d]*wv4.w;
      }
      if (which == 0)      *(float4*)&dq[j0] = acc;
      else if (which == 1) *(float4*)&dk[j0] = acc;
      else                 *(float4*)&dv[j0] = acc;
    }
  }
  dq[32]=cpart[0]; dq[33]=cpart[1]; dq[34]=cpart[2]; dq[35]=0.f;
  dk[32]=cpart[0]; dk[33]=cpart[1]; dk[34]=cpart[2]; dk[35]=0.f;
}

// ---------------- LSH hash values + per-(c,h) hi/lo
__global__ __launch_bounds__(256) void k_hash(const float* __restrict__ q_hat,
        const float* __restrict__ k_hat, const float* __restrict__ alpha,
        float* __restrict__ qh_buf, float* __restrict__ kh_buf,
        unsigned* __restrict__ slots_hi, unsigned* __restrict__ slots_lo){
  int h = blockIdx.y;
  int n = blockIdx.x*256 + threadIdx.x;
  __shared__ float A[DH][NC];
  for (int idx = threadIdx.x; idx < DH*NC; idx += 256)
    A[idx/3][idx%3] = alpha[h*DH*NC + idx];
  __syncthreads();
  float qr[36], kr[36];
  const float4* qp = (const float4*)(q_hat + ((size_t)h*NPTS + n)*DP);
  const float4* kp = (const float4*)(k_hat + ((size_t)h*NPTS + n)*DP);
  #pragma unroll
  for (int u = 0; u < 9; ++u){
    *(float4*)&qr[u*4] = qp[u];
    *(float4*)&kr[u*4] = kp[u];
  }
  #pragma unroll
  for (int c = 0; c < NC; ++c){
    float qh = 0.f, kh = 0.f;
    #pragma unroll
    for (int d = 0; d < DH; ++d){ qh += qr[d]*A[d][c]; kh += kr[d]*A[d][c]; }
    qh_buf[((size_t)(c*NH + h))*NPTS + n] = qh;
    kh_buf[((size_t)(c*NH + h))*NPTS + n] = kh;
    float hi = fmaxf(qh, kh), lo = fminf(qh, kh);
    #pragma unroll
    for (int off = 32; off; off >>= 1){
      hi = fmaxf(hi, __shfl_xor(hi, off));
      lo = fminf(lo, __shfl_xor(lo, off));
    }
    if ((threadIdx.x & 63) == 0){
      atomicMax(&slots_hi[c*NH + h], fmap(hi));
      atomicMin(&slots_lo[c*NH + h], fmap(lo));
    }
  }
}

// ---------------- pack + first bitonic stage fused (k=2..8192 within 8192-chunk)
__global__ __launch_bounds__(256) void k_sort_pack_local(
        const float* __restrict__ qh_buf, const float* __restrict__ kh_buf,
        const int* __restrict__ shifts,
        const unsigned* __restrict__ slots_hi, const unsigned* __restrict__ slots_lo,
        ull* __restrict__ packed){
  __shared__ ull ld[8192];     // 64 KB
  int chunk = blockIdx.x;            // 0..191
  int lst = chunk >> 2;              // 0..47 (0..23 q, 24..47 k)
  int seg = lst < NSEG ? lst : lst - NSEG;
  const float* buf = lst < NSEG ? qh_buf : kh_buf;
  unsigned coff = (unsigned)(chunk & 3) * 8192u;
  float hs = funmap(slots_hi[seg]) - funmap(slots_lo[seg]);
  for (int idx = threadIdx.x; idx < 8192; idx += 256){
    unsigned n = coff + idx;
    size_t gi = (size_t)seg*NPTS + n;
    float key = buf[gi] + (float)shifts[gi] * hs;
    ld[idx] = ((ull)fmap(key) << 32) | n;
  }
  __syncthreads();
  for (unsigned k = 2; k <= 8192u; k <<= 1){
    unsigned j0 = (k >> 1) < 4096u ? (k >> 1) : 4096u;
    for (unsigned j = j0; j > 0; j >>= 1){
      for (unsigned p = threadIdx.x; p < 4096; p += 256){
        unsigned i  = ((p & ~(j-1)) << 1) | (p & (j-1));
        unsigned x2 = i | j;
        bool up = (((coff + i) & k) == 0);
        ull a = ld[i], b = ld[x2];
        if ((a > b) == up){ ld[i] = b; ld[x2] = a; }
      }
      __syncthreads();
    }
  }
  size_t base = (size_t)lst*NPTS + coff;
  for (int idx = threadIdx.x; idx < 8192; idx += 256) packed[base + idx] = ld[idx];
}

// ---------------- bitonic sort: LDS chunk kernel
__global__ __launch_bounds__(256) void k_sort_local(ull* __restrict__ data,
        unsigned k_lo, unsigned k_hi){
  __shared__ ull ld[8192];     // 64 KB
  int chunk = blockIdx.x;
  size_t base = (size_t)chunk * 8192;
  unsigned segoff = (unsigned)(chunk & 3) * 8192u;
  for (int idx = threadIdx.x; idx < 8192; idx += 256) ld[idx] = data[base + idx];
  __syncthreads();
  for (unsigned k = k_lo; k <= k_hi; k <<= 1){
    unsigned j0 = (k >> 1) < 4096u ? (k >> 1) : 4096u;
    for (unsigned j = j0; j > 0; j >>= 1){
      for (unsigned p = threadIdx.x; p < 4096; p += 256){
        unsigned i  = ((p & ~(j-1)) << 1) | (p & (j-1));
        unsigned x2 = i | j;
        bool up = (((segoff + i) & k) == 0);
        ull a = ld[i], b = ld[x2];
        if ((a > b) == up){ ld[i] = b; ld[x2] = a; }
      }
      __syncthreads();
    }
  }
  for (int idx = threadIdx.x; idx < 8192; idx += 256) data[base + idx] = ld[idx];
}

// ---------------- bitonic sort: one global compare-exchange pass
__global__ __launch_bounds__(256) void k_sort_global(ull* __restrict__ data,
        unsigned k, unsigned j){
  unsigned t = blockIdx.x*256 + threadIdx.x;
  unsigned seg = t >> 14;
  unsigned p = t & 16383u;
  unsigned i  = ((p & ~(j-1)) << 1) | (p & (j-1));
  unsigned x2 = i | j;
  size_t base = (size_t)seg << 15;
  bool up = ((i & k) == 0);
  ull a = data[base + i], b = data[base + x2];
  if ((a > b) == up){ data[base + i] = b; data[base + x2] = a; }
}

// ---------------- bucketed kernelized attention (MFMA, split-bf16, Q/K/V in LDS)
// row layout (64 shorts): dims 0..34 data, 35 = {K: ksq, Q: 1.0},
// 36 = {K: 1.0, Q: qsq}, 37..63 = 0.  S = dot + ksq + qsq directly.
__global__ __launch_bounds__(512, 4) void k_attn(const float* __restrict__ q_hat,
        const float* __restrict__ k_hat, const float* __restrict__ val,
        const ull* __restrict__ packed, float* __restrict__ o_acc,
        float* __restrict__ logit_acc){
  __shared__ short Khi[128*64];      // 16 KB
  __shared__ short Klo[128*64];      // 16 KB
  __shared__ short Qhi[128*64];      // 16 KB (P aliases own-wave rows later)
  __shared__ short Qlo[128*64];      // 16 KB
  __shared__ short Vt[32*128];       // 8 KB [vdim][key] swizzled
  __shared__ unsigned iq_lds[128];

  int t = threadIdx.x;
  int blk = blockIdx.x;
  int seg = blk >> 8;
  int b = blk & 255;
  int h = seg & 7;
  const ull* pq = packed + ((size_t)seg << 15) + (size_t)b*BSZ;
  const ull* pk = packed + ((size_t)(NSEG + seg) << 15) + (size_t)b*BSZ;

  if (t < 256){
    int r = t & 127;
    bool isq = t >= 128;
    unsigned idx = (unsigned)((isq ? pq[r] : pk[r]) & 0xffffffffull);
    if (isq) iq_lds[r] = idx;
    const float* src = (isq ? q_hat : k_hat) + ((size_t)h*NPTS + idx)*DP;
    float f[40];
    #pragma unroll
    for (int u = 0; u < 9; ++u) *(float4*)&f[u*4] = ((const float4*)src)[u];
    float sq = 0.f;
    #pragma unroll
    for (int d = 0; d < 36; ++d) sq += f[d]*f[d];   // f[35] is 0 pad
    sq = -0.5f * sq;
    f[35] = isq ? 1.0f : sq;
    f[36] = isq ? sq : 1.0f;
    f[37] = 0.f; f[38] = 0.f; f[39] = 0.f;
    short* Hi = isq ? Qhi : Khi;
    short* Lo = isq ? Qlo : Klo;
    int rowbase = r*64;
    int sw = (r & 7) << 3;
    #pragma unroll
    for (int c = 0; c < 40; c += 4){
      unsigned short h0=f2bf(f[c]),   h1=f2bf(f[c+1]);
      unsigned short h2=f2bf(f[c+2]), h3=f2bf(f[c+3]);
      unsigned short l0=f2bf(f[c]  -bf2f(h0)), l1=f2bf(f[c+1]-bf2f(h1));
      unsigned short l2=f2bf(f[c+2]-bf2f(h2)), l3=f2bf(f[c+3]-bf2f(h3));
      int o = rowbase + (c ^ sw);
      uint2 hv, lv;
      hv.x = (unsigned)h0 | ((unsigned)h1 << 16);
      hv.y = (unsigned)h2 | ((unsigned)h3 << 16);
      lv.x = (unsigned)l0 | ((unsigned)l1 << 16);
      lv.y = (unsigned)l2 | ((unsigned)l3 << 16);
      *(uint2*)&Hi[o] = hv;
      *(uint2*)&Lo[o] = lv;
    }
    #pragma unroll
    for (int c = 40; c < 64; c += 4){
      int o = rowbase + (c ^ sw);
      *(uint2*)&Hi[o] = (uint2){0u,0u};
      *(uint2*)&Lo[o] = (uint2){0u,0u};
    }
  } else {
    int r = (t - 256) & 127;
    int half = (t - 256) >> 7;   // 0 or 1
    unsigned ik = (unsigned)(pk[r] & 0xffffffffull);
    const float* vr = val + ((size_t)h*NPTS + ik)*DIM + 16*half;
    float fv[16];
    #pragma unroll
    for (int u = 0; u < 4; ++u) *(float4*)&fv[u*4] = ((const float4*)vr)[u];
    #pragma unroll
    for (int d = 0; d < 16; ++d){
      int vd = 16*half + d;
      Vt[vd*128 + (r ^ ((vd&7)<<3))] = (short)f2bf(fv[d]);
    }
  }
  __syncthreads();

  int lane = t & 63;
  int w = t >> 6;                 // wave 0..7, owns q rows [16w, 16w+16)
  int l15 = lane & 15, g = lane >> 4;
  int qrow = 16*w + l15;
  int qsw = (qrow & 7) << 3;
  const short* qbh = &Qhi[qrow*64];
  const short* qbl = &Qlo[qrow*64];
  bf16x8 qh0 = *(const bf16x8*)&qbh[(8*g) ^ qsw];
  bf16x8 qh1 = *(const bf16x8*)&qbh[(32 + 8*g) ^ qsw];
  bf16x8 ql0 = *(const bf16x8*)&qbl[(8*g) ^ qsw];
  bf16x8 ql1 = *(const bf16x8*)&qbl[(32 + 8*g) ^ qsw];

  f32x4 acc[8];
  #pragma unroll
  for (int kt = 0; kt < 8; ++kt) acc[kt] = (f32x4){0.f,0.f,0.f,0.f};

  #pragma unroll
  for (int kt = 0; kt < 8; ++kt){
    int krow = 16*kt + l15;
    int base = krow*64;
    int sw = (krow & 7) << 3;
    bf16x8 ah0 = *(const bf16x8*)&Khi[base + ((8*g) ^ sw)];
    bf16x8 ah1 = *(const bf16x8*)&Khi[base + ((32 + 8*g) ^ sw)];
    bf16x8 al0 = *(const bf16x8*)&Klo[base + ((8*g) ^ sw)];
    bf16x8 al1 = *(const bf16x8*)&Klo[base + ((32 + 8*g) ^ sw)];
    f32x4 c = acc[kt];
    c = __builtin_amdgcn_mfma_f32_16x16x32_bf16(ah0, qh0, c, 0, 0, 0);
    c = __builtin_amdgcn_mfma_f32_16x16x32_bf16(ah1, qh1, c, 0, 0, 0);
    c = __builtin_amdgcn_mfma_f32_16x16x32_bf16(al0, qh0, c, 0, 0, 0);
    c = __builtin_amdgcn_mfma_f32_16x16x32_bf16(al1, qh1, c, 0, 0, 0);
    c = __builtin_amdgcn_mfma_f32_16x16x32_bf16(ah0, ql0, c, 0, 0, 0);
    c = __builtin_amdgcn_mfma_f32_16x16x32_bf16(ah1, ql1, c, 0, 0, 0);
    acc[kt] = c;
  }

  // exp + P -> bf16 into own-wave Q rows (dead after fragment load); fp32 denom
  float dena = 0.f;
  #pragma unroll
  for (int kt = 0; kt < 8; ++kt){
    f32x4 c = acc[kt];
    float p0 = __expf(fminf(c[0], 0.f));
    float p1 = __expf(fminf(c[1], 0.f));
    float p2 = __expf(fminf(c[2], 0.f));
    float p3 = __expf(fminf(c[3], 0.f));
    dena += p0 + p1 + p2 + p3;
    int key = 16*kt + 4*g;              // 4 consecutive keys
    uint2 pv;
    pv.x = (unsigned)f2bf(p0) | ((unsigned)f2bf(p1) << 16);
    pv.y = (unsigned)f2bf(p2) | ((unsigned)f2bf(p3) << 16);
    short* Pbuf = (key < 64) ? Qhi : Qlo;
    *(uint2*)&Pbuf[qrow*64 + ((key & 63) ^ qsw)] = pv;
  }

  // PV via MFMA: A = P (m=q), B = V^T (n=vdim)
  f32x4 oacc[2];
  oacc[0] = (f32x4){0.f,0.f,0.f,0.f};
  oacc[1] = (f32x4){0.f,0.f,0.f,0.f};
  #pragma unroll
  for (int ks = 0; ks < 4; ++ks){
    int key = 32*ks + 8*g;
    const short* Pbuf = (key < 64) ? Qhi : Qlo;
    bf16x8 pA = *(const bf16x8*)&Pbuf[qrow*64 + ((key & 63) ^ qsw)];
    #pragma unroll
    for (int nt = 0; nt < 2; ++nt){
      int vd = 16*nt + l15;
      bf16x8 vB = *(const bf16x8*)&Vt[vd*128 + ((32*ks + 8*g) ^ ((vd&7)<<3))];
      oacc[nt] = __builtin_amdgcn_mfma_f32_16x16x32_bf16(pA, vB, oacc[nt], 0, 0, 0);
    }
  }

  // denom scatter
  {
    float d = dena;
    d += __shfl_xor(d, 16);
    d += __shfl_xor(d, 32);
    if (lane < 16) atomicAdd(&logit_acc[(size_t)h*NPTS + iq_lds[qrow]], d + 1e-20f);
  }
  // O scatter
  #pragma unroll
  for (int nt = 0; nt < 2; ++nt){
    f32x4 c = oacc[nt];
    #pragma unroll
    for (int r = 0; r < 4; ++r){
      unsigned iq = iq_lds[16*w + 4*g + r];
      atomicAdd(&o_acc[((size_t)h*NPTS + iq)*DIM + 16*nt + l15], c[r]);
    }
  }
}

// ---------------- out-proj + residual + LN2 + FF + residual
__global__ __launch_bounds__(256) void k_final(const float* __restrict__ x,
        const float* __restrict__ o_acc, const float* __restrict__ logit_acc,
        const float* __restrict__ out_w, const float* __restrict__ out_b,
        const float* __restrict__ n2w, const float* __restrict__ n2b,
        const float* __restrict__ f1w, const float* __restrict__ f1b,
        const float* __restrict__ f2w, const float* __restrict__ f2b,
        float* __restrict__ out){
  __shared__ float OW[256][32];   // 32 KB
  __shared__ float F1[32][32];
  __shared__ float F2[32][32];
  int tid = threadIdx.x;
  for (int idx = tid; idx < 256*32; idx += 256) OW[idx/32][idx%32] = out_w[idx];
  for (int idx = tid; idx < 1024; idx += 256){
    F1[idx/32][idx%32] = f1w[idx];
    F2[idx/32][idx%32] = f2w[idx];
  }
  __syncthreads();
  int n = blockIdx.x*256 + tid;
  float attn[32];
  #pragma unroll
  for (int j = 0; j < 32; ++j) attn[j] = out_b[j];
  for (int h = 0; h < 8; ++h){
    float inv = 1.f / logit_acc[(size_t)h*NPTS + n];
    const float4* orow = (const float4*)(o_acc + ((size_t)h*NPTS + n)*DIM);
    #pragma unroll
    for (int u = 0; u < 8; ++u){
      float4 ov = orow[u];
      float vals[4] = {ov.x*inv, ov.y*inv, ov.z*inv, ov.w*inv};
      #pragma unroll
      for (int s = 0; s < 4; ++s){
        const float* wrow = &OW[h*32 + u*4 + s][0];
        #pragma unroll
        for (int j = 0; j < 32; ++j) attn[j] += vals[s] * wrow[j];
      }
    }
  }
  const float* xp = x + (size_t)n*DIM;
  float xr[32]; float s = 0.f;
  #pragma unroll
  for (int d = 0; d < 32; ++d){ xr[d] = xp[d] + attn[d]; s += xr[d]; }
  float mu = s * (1.f/32.f);
  float var = 0.f;
  #pragma unroll
  for (int d = 0; d < 32; ++d){ float dx = xr[d]-mu; var += dx*dx; }
  var *= (1.f/32.f);
  float rs = rsqrtf(var + 1e-5f);
  float xn2[32];
  #pragma unroll
  for (int d = 0; d < 32; ++d) xn2[d] = (xr[d]-mu)*rs*n2w[d] + n2b[d];
  float z[32];
  #pragma unroll
  for (int j = 0; j < 32; ++j) z[j] = f1b[j];
  #pragma unroll
  for (int d = 0; d < 32; ++d){
    float xd = xn2[d];
    const float* wrow = &F1[d][0];
    #pragma unroll
    for (int j = 0; j < 32; ++j) z[j] += xd * wrow[j];
  }
  #pragma unroll
  for (int j = 0; j < 32; ++j) z[j] = z[j] / (1.f + __expf(-z[j]));
  float y[32];
  #pragma unroll
  for (int d = 0; d < 32; ++d) y[d] = f2b[d];
  #pragma unroll
  for (int j = 0; j < 32; ++j){
    float zj = z[j];
    const float* wrow = &F2[j][0];
    #pragma unroll
    for (int d = 0; d < 32; ++d) y[d] += zj * wrow[d];
  }
  float* op = out + (size_t)n*DIM;
  #pragma unroll
  for (int d = 0; d < 32; ++d) op[d] = xr[d] + y[d];
}

extern "C" void kernel_launch(void* const* d_in, const int* in_sizes, int n_in,
                              void* d_out, int out_size, void* d_ws, size_t ws_size,
                              hipStream_t stream){
  const float* x      = (const float*)d_in[0];
  const float* coords = (const float*)d_in[1];
  const int*   shifts = (const int*)d_in[2];
  const float* n1w    = (const float*)d_in[3];
  const float* n1b    = (const float*)d_in[4];
  const float* wq     = (const float*)d_in[5];
  const float* wk     = (const float*)d_in[6];
  const float* wv     = (const float*)d_in[7];
  const float* w_rpe  = (const float*)d_in[8];
  const float* alpha  = (const float*)d_in[9];
  const float* out_w  = (const float*)d_in[10];
  const float* out_b  = (const float*)d_in[11];
  const float* n2w    = (const float*)d_in[12];
  const float* n2b    = (const float*)d_in[13];
  const float* f1w    = (const float*)d_in[14];
  const float* f1b    = (const float*)d_in[15];
  const float* f2w    = (const float*)d_in[16];
  const float* f2b    = (const float*)d_in[17];
  float* out = (float*)d_out;

  char* ws = (char*)d_ws;
  size_t off = 0;
  auto alloc = [&](size_t bytes){ size_t o = off; off += (bytes + 255) & ~(size_t)255; return o; };
  float*    qw_sqrt   = (float*)   (ws + alloc(24*4));
  unsigned* slots_hi  = (unsigned*)(ws + alloc(24*4));
  unsigned* slots_lo  = (unsigned*)(ws + alloc(24*4));
  float*    q_hat     = (float*)   (ws + alloc((size_t)NH*NPTS*DP*4));
  float*    k_hat     = (float*)   (ws + alloc((size_t)NH*NPTS*DP*4));
  float*    val       = (float*)   (ws + alloc((size_t)NH*NPTS*DIM*4));
  float*    qh_buf    = (float*)   (ws + alloc((size_t)NSEG*NPTS*4));
  float*    kh_buf    = (float*)   (ws + alloc((size_t)NSEG*NPTS*4));
  ull*      packed    = (ull*)     (ws + alloc((size_t)2*NSEG*NPTS*8));
  float*    o_acc     = (float*)   (ws + alloc((size_t)NH*NPTS*DIM*4));
  float*    logit_acc = (float*)   (ws + alloc((size_t)NH*NPTS*4));
  if (off > ws_size) return;

  hipMemsetAsync(o_acc, 0, (size_t)NH*NPTS*DIM*4, stream);
  hipMemsetAsync(logit_acc, 0, (size_t)NH*NPTS*4, stream);

  k_prep<<<1, 256, 0, stream>>>(w_rpe, qw_sqrt, slots_hi, slots_lo);
  k_qkv<<<NPTS/32, 256, 0, stream>>>(x, n1w, n1b, coords, wq, wk, wv, qw_sqrt,
                                     q_hat, k_hat, val);
  k_hash<<<dim3(NPTS/256, NH), 256, 0, stream>>>(q_hat, k_hat, alpha, qh_buf, kh_buf,
                                                 slots_hi, slots_lo);
  // 48 segments of 32768 -> bitonic
  k_sort_pack_local<<<2*NSEG*4, 256, 0, stream>>>(qh_buf, kh_buf, shifts,
                                                  slots_hi, slots_lo, packed);
  k_sort_global<<<(2*NSEG*16384)/256, 256, 0, stream>>>(packed, 16384u, 8192u);
  k_sort_local<<<2*NSEG*4, 256, 0, stream>>>(packed, 16384u, 16384u);
  k_sort_global<<<(2*NSEG*16384)/256, 256, 0, stream>>>(packed, 32768u, 16384u);
  k_sort_global<<<(2*NSEG*16384)/256, 256, 0, stream>>>(packed, 32768u, 8192u);
  k_sort_local<<<2*NSEG*4, 256, 0, stream>>>(packed, 32768u, 32768u);

  k_attn<<<NSEG*NB, 512, 0, stream>>>(q_hat, k_hat, val, packed, o_acc, logit_acc);
  k_final<<<NPTS/256, 256, 0, stream>>>(x, o_acc, logit_acc, out_w, out_b,
                                        n2w, n2b, f1w, f1b, f2w, f2b, out);
}

// Round 6
// 564.035 us; speedup vs baseline: 1.2801x; 1.2791x over previous
//
#include <hip/hip_runtime.h>

#define NPTS 32768
#define DIM 32
#define NH 8
#define NC 3
#define BSZ 128
#define NB 256
#define DH 35
#define DP 36
#define NSEG 24   // C*H

typedef unsigned long long ull;
typedef __attribute__((ext_vector_type(8))) short bf16x8;
typedef __attribute__((ext_vector_type(4))) float f32x4;

__device__ __forceinline__ unsigned fmap(float f){
  unsigned b = __float_as_uint(f);
  return (b & 0x80000000u) ? ~b : (b | 0x80000000u);
}
__device__ __forceinline__ float funmap(unsigned u){
  unsigned b = (u & 0x80000000u) ? (u & 0x7fffffffu) : ~u;
  return __uint_as_float(b);
}
__device__ __forceinline__ unsigned short f2bf(float f){
  unsigned u = __float_as_uint(f);
  u += 0x7fffu + ((u >> 16) & 1u);
  return (unsigned short)(u >> 16);
}
__device__ __forceinline__ float bf2f(unsigned short h){
  return __uint_as_float(((unsigned)h) << 16);
}

__device__ __forceinline__ void cswap(ull& a, ull& b, bool up){
  if ((a > b) == up){ ull t = a; a = b; b = t; }
}
// bitonic stages k=2,4,8 on 8 contiguous elements whose global index starts at gbase (gbase%8==0)
__device__ __forceinline__ void bitonic8_initial(ull r[8], unsigned gbase){
  #pragma unroll
  for (int p = 0; p < 4; ++p){
    bool up = (((gbase + 2*p) & 2) == 0);
    cswap(r[2*p], r[2*p+1], up);
  }
  #pragma unroll
  for (int b = 0; b < 2; ++b){
    bool up = (((gbase + 4*b) & 4) == 0);
    cswap(r[4*b+0], r[4*b+2], up);
    cswap(r[4*b+1], r[4*b+3], up);
    cswap(r[4*b+0], r[4*b+1], up);
    cswap(r[4*b+2], r[4*b+3], up);
  }
  bool up = ((gbase & 8) == 0);
  #pragma unroll
  for (int i = 0; i < 4; ++i) cswap(r[i], r[i+4], up);
  #pragma unroll
  for (int b = 0; b < 2; ++b){
    cswap(r[4*b+0], r[4*b+2], up);
    cswap(r[4*b+1], r[4*b+3], up);
  }
  #pragma unroll
  for (int p = 0; p < 4; ++p) cswap(r[2*p], r[2*p+1], up);
}
// j=4,2,1 finish of a stage k>=16; direction uniform across the 8
__device__ __forceinline__ void bitonic8_finish(ull r[8], bool up){
  #pragma unroll
  for (int i = 0; i < 4; ++i) cswap(r[i], r[i+4], up);
  #pragma unroll
  for (int b = 0; b < 2; ++b){
    cswap(r[4*b+0], r[4*b+2], up);
    cswap(r[4*b+1], r[4*b+3], up);
  }
  #pragma unroll
  for (int p = 0; p < 4; ++p) cswap(r[2*p], r[2*p+1], up);
}

// ---------------- prep
__global__ __launch_bounds__(256) void k_prep(const float* __restrict__ w_rpe,
        float* __restrict__ qw_sqrt, unsigned* __restrict__ slots_hi,
        unsigned* __restrict__ slots_lo){
  int tid = threadIdx.x;
  if (tid < NSEG){ slots_hi[tid] = 0u; slots_lo[tid] = 0xFFFFFFFFu; }
  __shared__ float S[24][8];
  if (tid < 192){
    int hr = tid >> 3, kk = tid & 7;
    int h = hr / 3, r = hr % 3;
    float s = 0.f;
    #pragma unroll
    for (int d = 0; d < DIM; ++d) s += w_rpe[(h*DIM + d)*24 + (r*8 + kk)];
    S[hr][kk] = expf(fminf(s, 50.f));
  }
  __syncthreads();
  if (tid < 24){
    float q = 0.f;
    #pragma unroll
    for (int kk = 0; kk < 8; ++kk) q += S[tid][kk];
    qw_sqrt[tid] = sqrtf(2.f * q);
  }
}

// ---------------- LN1 + QKV projection fused
__global__ __launch_bounds__(256) void k_qkv(const float* __restrict__ x,
        const float* __restrict__ n1w, const float* __restrict__ n1b,
        const float* __restrict__ coords, const float* __restrict__ wq,
        const float* __restrict__ wk, const float* __restrict__ wv,
        const float* __restrict__ qw_sqrt,
        float* __restrict__ q_hat, float* __restrict__ k_hat,
        float* __restrict__ val){
  __shared__ float W[3][DIM][NH*DIM];   // 96 KB
  __shared__ float XT[32][33];
  int tid = threadIdx.x;
  for (int idx = tid; idx < 3*DIM*NH*DIM; idx += 256){
    int which = idx / (DIM*NH*DIM);
    int rem = idx % (DIM*NH*DIM);
    const float* src = which==0 ? wq : (which==1 ? wk : wv);
    W[which][rem/(NH*DIM)][rem%(NH*DIM)] = src[rem];
  }
  int base = blockIdx.x * 32;
  if (tid < 32){
    const float4* xr4 = (const float4*)(x + (size_t)(base + tid)*DIM);
    float4 v[8];
    float s = 0.f;
    #pragma unroll
    for (int u = 0; u < 8; ++u){ v[u] = xr4[u]; s += v[u].x+v[u].y+v[u].z+v[u].w; }
    float mu = s * (1.f/32.f);
    float var = 0.f;
    #pragma unroll
    for (int u = 0; u < 8; ++u){
      float a0=v[u].x-mu, a1=v[u].y-mu, a2=v[u].z-mu, a3=v[u].w-mu;
      var += a0*a0+a1*a1+a2*a2+a3*a3;
    }
    var *= (1.f/32.f);
    float rs = rsqrtf(var + 1e-5f);
    #pragma unroll
    for (int u = 0; u < 8; ++u){
      XT[tid][u*4+0] = (v[u].x-mu)*rs*n1w[u*4+0] + n1b[u*4+0];
      XT[tid][u*4+1] = (v[u].y-mu)*rs*n1w[u*4+1] + n1b[u*4+1];
      XT[tid][u*4+2] = (v[u].z-mu)*rs*n1w[u*4+2] + n1b[u*4+2];
      XT[tid][u*4+3] = (v[u].w-mu)*rs*n1w[u*4+3] + n1b[u*4+3];
    }
  }
  __syncthreads();
  int h = tid >> 5, i = tid & 31;
  int n = base + i;
  float xr[32];
  #pragma unroll
  for (int d = 0; d < 32; ++d) xr[d] = XT[i][d];
  float cpart[3];
  #pragma unroll
  for (int r = 0; r < 3; ++r) cpart[r] = qw_sqrt[h*3+r] * coords[(size_t)n*3 + r];

  float* dq = q_hat + ((size_t)h*NPTS + n)*DP;
  float* dk = k_hat + ((size_t)h*NPTS + n)*DP;
  float* dv = val   + ((size_t)h*NPTS + n)*DIM;
  #pragma unroll
  for (int which = 0; which < 3; ++which){
    for (int j0 = 0; j0 < 32; j0 += 4){
      float4 acc = {0.f,0.f,0.f,0.f};
      #pragma unroll
      for (int d = 0; d < 32; ++d){
        float4 wv4 = *(const float4*)&W[which][d][h*32 + j0];
        acc.x += xr[d]*wv4.x; acc.y += xr[d]*wv4.y;
        acc.z += xr[d]*wv4.z; acc.w += xr[d]*wv4.w;
      }
      if (which == 0)      *(float4*)&dq[j0] = acc;
      else if (which == 1) *(float4*)&dk[j0] = acc;
      else                 *(float4*)&dv[j0] = acc;
    }
  }
  dq[32]=cpart[0]; dq[33]=cpart[1]; dq[34]=cpart[2]; dq[35]=0.f;
  dk[32]=cpart[0]; dk[33]=cpart[1]; dk[34]=cpart[2]; dk[35]=0.f;
}

// ---------------- LSH hash values + per-(c,h) hi/lo
__global__ __launch_bounds__(256) void k_hash(const float* __restrict__ q_hat,
        const float* __restrict__ k_hat, const float* __restrict__ alpha,
        float* __restrict__ qh_buf, float* __restrict__ kh_buf,
        unsigned* __restrict__ slots_hi, unsigned* __restrict__ slots_lo){
  int h = blockIdx.y;
  int n = blockIdx.x*256 + threadIdx.x;
  __shared__ float A[DH][NC];
  for (int idx = threadIdx.x; idx < DH*NC; idx += 256)
    A[idx/3][idx%3] = alpha[h*DH*NC + idx];
  __syncthreads();
  float qr[36], kr[36];
  const float4* qp = (const float4*)(q_hat + ((size_t)h*NPTS + n)*DP);
  const float4* kp = (const float4*)(k_hat + ((size_t)h*NPTS + n)*DP);
  #pragma unroll
  for (int u = 0; u < 9; ++u){
    *(float4*)&qr[u*4] = qp[u];
    *(float4*)&kr[u*4] = kp[u];
  }
  #pragma unroll
  for (int c = 0; c < NC; ++c){
    float qh = 0.f, kh = 0.f;
    #pragma unroll
    for (int d = 0; d < DH; ++d){ qh += qr[d]*A[d][c]; kh += kr[d]*A[d][c]; }
    qh_buf[((size_t)(c*NH + h))*NPTS + n] = qh;
    kh_buf[((size_t)(c*NH + h))*NPTS + n] = kh;
    float hi = fmaxf(qh, kh), lo = fminf(qh, kh);
    #pragma unroll
    for (int off = 32; off; off >>= 1){
      hi = fmaxf(hi, __shfl_xor(hi, off));
      lo = fminf(lo, __shfl_xor(lo, off));
    }
    if ((threadIdx.x & 63) == 0){
      atomicMax(&slots_hi[c*NH + h], fmap(hi));
      atomicMin(&slots_lo[c*NH + h], fmap(lo));
    }
  }
}

// ---------------- pack + bitonic k=2..8192 within 8192-chunk
// LDS layout padded: phys(i) = i + (i>>3)  (72 KB). Thread owns 8 contiguous.
__global__ __launch_bounds__(1024) void k_sort_pack_local(
        const float* __restrict__ qh_buf, const float* __restrict__ kh_buf,
        const int* __restrict__ shifts,
        const unsigned* __restrict__ slots_hi, const unsigned* __restrict__ slots_lo,
        ull* __restrict__ packed){
  __shared__ ull ld[9216];
  int chunk = blockIdx.x;            // 0..191
  int lst = chunk >> 2;              // 0..47 (0..23 q, 24..47 k)
  int seg = lst < NSEG ? lst : lst - NSEG;
  const float* buf = lst < NSEG ? qh_buf : kh_buf;
  unsigned coff = (unsigned)(chunk & 3) * 8192u;
  float hs = funmap(slots_hi[seg]) - funmap(slots_lo[seg]);
  unsigned tid = threadIdx.x;

  // pack own 8 + in-register k=2..8
  {
    ull r[8];
    unsigned gb = coff + 8u*tid;
    #pragma unroll
    for (int e = 0; e < 8; ++e){
      unsigned n = gb + e;
      size_t gi = (size_t)seg*NPTS + n;
      float key = buf[gi] + (float)shifts[gi] * hs;
      r[e] = ((ull)fmap(key) << 32) | n;
    }
    bitonic8_initial(r, gb);
    #pragma unroll
    for (int e = 0; e < 8; ++e) ld[9u*tid + e] = r[e];
  }
  __syncthreads();

  for (unsigned k = 16; k <= 8192u; k <<= 1){
    for (unsigned j = k >> 1; j >= 8; j >>= 1){
      #pragma unroll
      for (int it = 0; it < 4; ++it){
        unsigned p = tid + 1024u*it;
        unsigned i  = ((p & ~(j-1)) << 1) | (p & (j-1));
        unsigned x2 = i | j;
        bool up = (((coff + i) & k) == 0);
        unsigned pi = i + (i>>3), px = x2 + (x2>>3);
        ull a = ld[pi], b2 = ld[px];
        if ((a > b2) == up){ ld[pi] = b2; ld[px] = a; }
      }
      __syncthreads();
    }
    {
      ull r[8];
      #pragma unroll
      for (int e = 0; e < 8; ++e) r[e] = ld[9u*tid + e];
      bool up = (((coff + 8u*tid) & k) == 0);
      bitonic8_finish(r, up);
      #pragma unroll
      for (int e = 0; e < 8; ++e) ld[9u*tid + e] = r[e];
    }
    __syncthreads();
  }
  size_t base = (size_t)lst*NPTS + coff;
  for (unsigned idx = tid; idx < 8192; idx += 1024)
    packed[base + idx] = ld[idx + (idx>>3)];
}

// ---------------- bitonic: LDS chunk stages (k_lo..k_hi), j<=4096 handled here
__global__ __launch_bounds__(1024) void k_sort_local(ull* __restrict__ data,
        unsigned k_lo, unsigned k_hi){
  __shared__ ull ld[9216];
  int chunk = blockIdx.x;
  size_t base = (size_t)chunk * 8192;
  unsigned coff = (unsigned)(chunk & 3) * 8192u;
  unsigned tid = threadIdx.x;
  for (unsigned idx = tid; idx < 8192; idx += 1024)
    ld[idx + (idx>>3)] = data[base + idx];
  __syncthreads();
  for (unsigned k = k_lo; k <= k_hi; k <<= 1){
    unsigned j0 = (k >> 1) < 4096u ? (k >> 1) : 4096u;
    for (unsigned j = j0; j >= 8; j >>= 1){
      #pragma unroll
      for (int it = 0; it < 4; ++it){
        unsigned p = tid + 1024u*it;
        unsigned i  = ((p & ~(j-1)) << 1) | (p & (j-1));
        unsigned x2 = i | j;
        bool up = (((coff + i) & k) == 0);
        unsigned pi = i + (i>>3), px = x2 + (x2>>3);
        ull a = ld[pi], b2 = ld[px];
        if ((a > b2) == up){ ld[pi] = b2; ld[px] = a; }
      }
      __syncthreads();
    }
    {
      ull r[8];
      #pragma unroll
      for (int e = 0; e < 8; ++e) r[e] = ld[9u*tid + e];
      bool up = (((coff + 8u*tid) & k) == 0);
      bitonic8_finish(r, up);
      #pragma unroll
      for (int e = 0; e < 8; ++e) ld[9u*tid + e] = r[e];
    }
    __syncthreads();
  }
  for (unsigned idx = tid; idx < 8192; idx += 1024)
    data[base + idx] = ld[idx + (idx>>3)];
}

// ---------------- bitonic sort: one global compare-exchange pass
__global__ __launch_bounds__(256) void k_sort_global(ull* __restrict__ data,
        unsigned k, unsigned j){
  unsigned t = blockIdx.x*256 + threadIdx.x;
  unsigned seg = t >> 14;
  unsigned p = t & 16383u;
  unsigned i  = ((p & ~(j-1)) << 1) | (p & (j-1));
  unsigned x2 = i | j;
  size_t base = (size_t)seg << 15;
  bool up = ((i & k) == 0);
  ull a = data[base + i], b = data[base + x2];
  if ((a > b) == up){ data[base + i] = b; data[base + x2] = a; }
}

// ---------------- bucketed kernelized attention (MFMA, split-bf16, Q/K/V in LDS)
__global__ __launch_bounds__(512, 4) void k_attn(const float* __restrict__ q_hat,
        const float* __restrict__ k_hat, const float* __restrict__ val,
        const ull* __restrict__ packed, float* __restrict__ o_acc,
        float* __restrict__ logit_acc){
  __shared__ short Khi[128*64];      // 16 KB
  __shared__ short Klo[128*64];      // 16 KB
  __shared__ short Qhi[128*64];      // 16 KB (P aliases own-wave rows later)
  __shared__ short Qlo[128*64];      // 16 KB
  __shared__ short Vt[32*128];       // 8 KB [vdim][key] swizzled
  __shared__ unsigned iq_lds[128];

  int t = threadIdx.x;
  int blk = blockIdx.x;
  int seg = blk >> 8;
  int b = blk & 255;
  int h = seg & 7;
  const ull* pq = packed + ((size_t)seg << 15) + (size_t)b*BSZ;
  const ull* pk = packed + ((size_t)(NSEG + seg) << 15) + (size_t)b*BSZ;

  if (t < 256){
    int r = t & 127;
    bool isq = t >= 128;
    unsigned idx = (unsigned)((isq ? pq[r] : pk[r]) & 0xffffffffull);
    if (isq) iq_lds[r] = idx;
    const float* src = (isq ? q_hat : k_hat) + ((size_t)h*NPTS + idx)*DP;
    float f[40];
    #pragma unroll
    for (int u = 0; u < 9; ++u) *(float4*)&f[u*4] = ((const float4*)src)[u];
    float sq = 0.f;
    #pragma unroll
    for (int d = 0; d < 36; ++d) sq += f[d]*f[d];   // f[35] is 0 pad
    sq = -0.5f * sq;
    f[35] = isq ? 1.0f : sq;
    f[36] = isq ? sq : 1.0f;
    f[37] = 0.f; f[38] = 0.f; f[39] = 0.f;
    short* Hi = isq ? Qhi : Khi;
    short* Lo = isq ? Qlo : Klo;
    int rowbase = r*64;
    int sw = (r & 7) << 3;
    #pragma unroll
    for (int c = 0; c < 40; c += 4){
      unsigned short h0=f2bf(f[c]),   h1=f2bf(f[c+1]);
      unsigned short h2=f2bf(f[c+2]), h3=f2bf(f[c+3]);
      unsigned short l0=f2bf(f[c]  -bf2f(h0)), l1=f2bf(f[c+1]-bf2f(h1));
      unsigned short l2=f2bf(f[c+2]-bf2f(h2)), l3=f2bf(f[c+3]-bf2f(h3));
      int o = rowbase + (c ^ sw);
      uint2 hv, lv;
      hv.x = (unsigned)h0 | ((unsigned)h1 << 16);
      hv.y = (unsigned)h2 | ((unsigned)h3 << 16);
      lv.x = (unsigned)l0 | ((unsigned)l1 << 16);
      lv.y = (unsigned)l2 | ((unsigned)l3 << 16);
      *(uint2*)&Hi[o] = hv;
      *(uint2*)&Lo[o] = lv;
    }
    #pragma unroll
    for (int c = 40; c < 64; c += 4){
      int o = rowbase + (c ^ sw);
      *(uint2*)&Hi[o] = (uint2){0u,0u};
      *(uint2*)&Lo[o] = (uint2){0u,0u};
    }
  } else {
    int r = (t - 256) & 127;
    int half = (t - 256) >> 7;   // 0 or 1
    unsigned ik = (unsigned)(pk[r] & 0xffffffffull);
    const float* vr = val + ((size_t)h*NPTS + ik)*DIM + 16*half;
    float fv[16];
    #pragma unroll
    for (int u = 0; u < 4; ++u) *(float4*)&fv[u*4] = ((const float4*)vr)[u];
    #pragma unroll
    for (int d = 0; d < 16; ++d){
      int vd = 16*half + d;
      Vt[vd*128 + (r ^ ((vd&7)<<3))] = (short)f2bf(fv[d]);
    }
  }
  __syncthreads();

  int lane = t & 63;
  int w = t >> 6;                 // wave 0..7, owns q rows [16w, 16w+16)
  int l15 = lane & 15, g = lane >> 4;
  int qrow = 16*w + l15;
  int qsw = (qrow & 7) << 3;
  const short* qbh = &Qhi[qrow*64];
  const short* qbl = &Qlo[qrow*64];
  bf16x8 qh0 = *(const bf16x8*)&qbh[(8*g) ^ qsw];
  bf16x8 qh1 = *(const bf16x8*)&qbh[(32 + 8*g) ^ qsw];
  bf16x8 ql0 = *(const bf16x8*)&qbl[(8*g) ^ qsw];
  bf16x8 ql1 = *(const bf16x8*)&qbl[(32 + 8*g) ^ qsw];

  f32x4 acc[8];
  #pragma unroll
  for (int kt = 0; kt < 8; ++kt) acc[kt] = (f32x4){0.f,0.f,0.f,0.f};

  #pragma unroll
  for (int kt = 0; kt < 8; ++kt){
    int krow = 16*kt + l15;
    int base = krow*64;
    int sw = (krow & 7) << 3;
    bf16x8 ah0 = *(const bf16x8*)&Khi[base + ((8*g) ^ sw)];
    bf16x8 ah1 = *(const bf16x8*)&Khi[base + ((32 + 8*g) ^ sw)];
    bf16x8 al0 = *(const bf16x8*)&Klo[base + ((8*g) ^ sw)];
    bf16x8 al1 = *(const bf16x8*)&Klo[base + ((32 + 8*g) ^ sw)];
    f32x4 c = acc[kt];
    c = __builtin_amdgcn_mfma_f32_16x16x32_bf16(ah0, qh0, c, 0, 0, 0);
    c = __builtin_amdgcn_mfma_f32_16x16x32_bf16(ah1, qh1, c, 0, 0, 0);
    c = __builtin_amdgcn_mfma_f32_16x16x32_bf16(al0, qh0, c, 0, 0, 0);
    c = __builtin_amdgcn_mfma_f32_16x16x32_bf16(al1, qh1, c, 0, 0, 0);
    c = __builtin_amdgcn_mfma_f32_16x16x32_bf16(ah0, ql0, c, 0, 0, 0);
    c = __builtin_amdgcn_mfma_f32_16x16x32_bf16(ah1, ql1, c, 0, 0, 0);
    acc[kt] = c;
  }

  // exp + P -> bf16 into own-wave Q rows (dead after fragment load); fp32 denom
  float dena = 0.f;
  #pragma unroll
  for (int kt = 0; kt < 8; ++kt){
    f32x4 c = acc[kt];
    float p0 = __expf(fminf(c[0], 0.f));
    float p1 = __expf(fminf(c[1], 0.f));
    float p2 = __expf(fminf(c[2], 0.f));
    float p3 = __expf(fminf(c[3], 0.f));
    dena += p0 + p1 + p2 + p3;
    int key = 16*kt + 4*g;              // 4 consecutive keys
    uint2 pv;
    pv.x = (unsigned)f2bf(p0) | ((unsigned)f2bf(p1) << 16);
    pv.y = (unsigned)f2bf(p2) | ((unsigned)f2bf(p3) << 16);
    short* Pbuf = (key < 64) ? Qhi : Qlo;
    *(uint2*)&Pbuf[qrow*64 + ((key & 63) ^ qsw)] = pv;
  }

  // PV via MFMA: A = P (m=q), B = V^T (n=vdim)
  f32x4 oacc[2];
  oacc[0] = (f32x4){0.f,0.f,0.f,0.f};
  oacc[1] = (f32x4){0.f,0.f,0.f,0.f};
  #pragma unroll
  for (int ks = 0; ks < 4; ++ks){
    int key = 32*ks + 8*g;
    const short* Pbuf = (key < 64) ? Qhi : Qlo;
    bf16x8 pA = *(const bf16x8*)&Pbuf[qrow*64 + ((key & 63) ^ qsw)];
    #pragma unroll
    for (int nt = 0; nt < 2; ++nt){
      int vd = 16*nt + l15;
      bf16x8 vB = *(const bf16x8*)&Vt[vd*128 + ((32*ks + 8*g) ^ ((vd&7)<<3))];
      oacc[nt] = __builtin_amdgcn_mfma_f32_16x16x32_bf16(pA, vB, oacc[nt], 0, 0, 0);
    }
  }

  // denom scatter
  {
    float d = dena;
    d += __shfl_xor(d, 16);
    d += __shfl_xor(d, 32);
    if (lane < 16) atomicAdd(&logit_acc[(size_t)h*NPTS + iq_lds[qrow]], d + 1e-20f);
  }
  // O scatter
  #pragma unroll
  for (int nt = 0; nt < 2; ++nt){
    f32x4 c = oacc[nt];
    #pragma unroll
    for (int r = 0; r < 4; ++r){
      unsigned iq = iq_lds[16*w + 4*g + r];
      atomicAdd(&o_acc[((size_t)h*NPTS + iq)*DIM + 16*nt + l15], c[r]);
    }
  }
}

// ---------------- out-proj + residual + LN2 + FF + residual
__global__ __launch_bounds__(256) void k_final(const float* __restrict__ x,
        const float* __restrict__ o_acc, const float* __restrict__ logit_acc,
        const float* __restrict__ out_w, const float* __restrict__ out_b,
        const float* __restrict__ n2w, const float* __restrict__ n2b,
        const float* __restrict__ f1w, const float* __restrict__ f1b,
        const float* __restrict__ f2w, const float* __restrict__ f2b,
        float* __restrict__ out){
  __shared__ float OW[256][32];   // 32 KB
  __shared__ float F1[32][32];
  __shared__ float F2[32][32];
  int tid = threadIdx.x;
  for (int idx = tid; idx < 256*32; idx += 256) OW[idx/32][idx%32] = out_w[idx];
  for (int idx = tid; idx < 1024; idx += 256){
    F1[idx/32][idx%32] = f1w[idx];
    F2[idx/32][idx%32] = f2w[idx];
  }
  __syncthreads();
  int n = blockIdx.x*256 + tid;
  float attn[32];
  #pragma unroll
  for (int j = 0; j < 32; ++j) attn[j] = out_b[j];
  for (int h = 0; h < 8; ++h){
    float inv = 1.f / logit_acc[(size_t)h*NPTS + n];
    const float4* orow = (const float4*)(o_acc + ((size_t)h*NPTS + n)*DIM);
    #pragma unroll
    for (int u = 0; u < 8; ++u){
      float4 ov = orow[u];
      float vals[4] = {ov.x*inv, ov.y*inv, ov.z*inv, ov.w*inv};
      #pragma unroll
      for (int s = 0; s < 4; ++s){
        const float* wrow = &OW[h*32 + u*4 + s][0];
        #pragma unroll
        for (int j = 0; j < 32; ++j) attn[j] += vals[s] * wrow[j];
      }
    }
  }
  const float* xp = x + (size_t)n*DIM;
  float xr[32]; float s = 0.f;
  #pragma unroll
  for (int d = 0; d < 32; ++d){ xr[d] = xp[d] + attn[d]; s += xr[d]; }
  float mu = s * (1.f/32.f);
  float var = 0.f;
  #pragma unroll
  for (int d = 0; d < 32; ++d){ float dx = xr[d]-mu; var += dx*dx; }
  var *= (1.f/32.f);
  float rs = rsqrtf(var + 1e-5f);
  float xn2[32];
  #pragma unroll
  for (int d = 0; d < 32; ++d) xn2[d] = (xr[d]-mu)*rs*n2w[d] + n2b[d];
  float z[32];
  #pragma unroll
  for (int j = 0; j < 32; ++j) z[j] = f1b[j];
  #pragma unroll
  for (int d = 0; d < 32; ++d){
    float xd = xn2[d];
    const float* wrow = &F1[d][0];
    #pragma unroll
    for (int j = 0; j < 32; ++j) z[j] += xd * wrow[j];
  }
  #pragma unroll
  for (int j = 0; j < 32; ++j) z[j] = z[j] / (1.f + __expf(-z[j]));
  float y[32];
  #pragma unroll
  for (int d = 0; d < 32; ++d) y[d] = f2b[d];
  #pragma unroll
  for (int j = 0; j < 32; ++j){
    float zj = z[j];
    const float* wrow = &F2[j][0];
    #pragma unroll
    for (int d = 0; d < 32; ++d) y[d] += zj * wrow[d];
  }
  float* op = out + (size_t)n*DIM;
  #pragma unroll
  for (int d = 0; d < 32; ++d) op[d] = xr[d] + y[d];
}

extern "C" void kernel_launch(void* const* d_in, const int* in_sizes, int n_in,
                              void* d_out, int out_size, void* d_ws, size_t ws_size,
                              hipStream_t stream){
  const float* x      = (const float*)d_in[0];
  const float* coords = (const float*)d_in[1];
  const int*   shifts = (const int*)d_in[2];
  const float* n1w    = (const float*)d_in[3];
  const float* n1b    = (const float*)d_in[4];
  const float* wq     = (const float*)d_in[5];
  const float* wk     = (const float*)d_in[6];
  const float* wv     = (const float*)d_in[7];
  const float* w_rpe  = (const float*)d_in[8];
  const float* alpha  = (const float*)d_in[9];
  const float* out_w  = (const float*)d_in[10];
  const float* out_b  = (const float*)d_in[11];
  const float* n2w    = (const float*)d_in[12];
  const float* n2b    = (const float*)d_in[13];
  const float* f1w    = (const float*)d_in[14];
  const float* f1b    = (const float*)d_in[15];
  const float* f2w    = (const float*)d_in[16];
  const float* f2b    = (const float*)d_in[17];
  float* out = (float*)d_out;

  char* ws = (char*)d_ws;
  size_t off = 0;
  auto alloc = [&](size_t bytes){ size_t o = off; off += (bytes + 255) & ~(size_t)255; return o; };
  float*    qw_sqrt   = (float*)   (ws + alloc(24*4));
  unsigned* slots_hi  = (unsigned*)(ws + alloc(24*4));
  unsigned* slots_lo  = (unsigned*)(ws + alloc(24*4));
  float*    q_hat     = (float*)   (ws + alloc((size_t)NH*NPTS*DP*4));
  float*    k_hat     = (float*)   (ws + alloc((size_t)NH*NPTS*DP*4));
  float*    val       = (float*)   (ws + alloc((size_t)NH*NPTS*DIM*4));
  float*    qh_buf    = (float*)   (ws + alloc((size_t)NSEG*NPTS*4));
  float*    kh_buf    = (float*)   (ws + alloc((size_t)NSEG*NPTS*4));
  ull*      packed    = (ull*)     (ws + alloc((size_t)2*NSEG*NPTS*8));
  float*    o_acc     = (float*)   (ws + alloc((size_t)NH*NPTS*DIM*4));
  float*    logit_acc = (float*)   (ws + alloc((size_t)NH*NPTS*4));
  if (off > ws_size) return;

  hipMemsetAsync(o_acc, 0, (size_t)NH*NPTS*DIM*4, stream);
  hipMemsetAsync(logit_acc, 0, (size_t)NH*NPTS*4, stream);

  k_prep<<<1, 256, 0, stream>>>(w_rpe, qw_sqrt, slots_hi, slots_lo);
  k_qkv<<<NPTS/32, 256, 0, stream>>>(x, n1w, n1b, coords, wq, wk, wv, qw_sqrt,
                                     q_hat, k_hat, val);
  k_hash<<<dim3(NPTS/256, NH), 256, 0, stream>>>(q_hat, k_hat, alpha, qh_buf, kh_buf,
                                                 slots_hi, slots_lo);
  // 48 segments of 32768 -> bitonic
  k_sort_pack_local<<<2*NSEG*4, 1024, 0, stream>>>(qh_buf, kh_buf, shifts,
                                                   slots_hi, slots_lo, packed);
  k_sort_global<<<(2*NSEG*16384)/256, 256, 0, stream>>>(packed, 16384u, 8192u);
  k_sort_local<<<2*NSEG*4, 1024, 0, stream>>>(packed, 16384u, 16384u);
  k_sort_global<<<(2*NSEG*16384)/256, 256, 0, stream>>>(packed, 32768u, 16384u);
  k_sort_global<<<(2*NSEG*16384)/256, 256, 0, stream>>>(packed, 32768u, 8192u);
  k_sort_local<<<2*NSEG*4, 1024, 0, stream>>>(packed, 32768u, 32768u);

  k_attn<<<NSEG*NB, 512, 0, stream>>>(q_hat, k_hat, val, packed, o_acc, logit_acc);
  k_final<<<NPTS/256, 256, 0, stream>>>(x, o_acc, logit_acc, out_w, out_b,
                                        n2w, n2b, f1w, f1b, f2w, f2b, out);
}

// Round 7
// 525.699 us; speedup vs baseline: 1.3734x; 1.0729x over previous
//
#include <hip/hip_runtime.h>

#define NPTS 32768
#define DIM 32
#define NH 8
#define NC 3
#define BSZ 128
#define NB 256
#define DH 35
#define DP 36
#define NSEG 24   // C*H

typedef unsigned long long ull;
typedef __attribute__((ext_vector_type(8))) short bf16x8;
typedef __attribute__((ext_vector_type(4))) float f32x4;

__device__ __forceinline__ unsigned fmap(float f){
  unsigned b = __float_as_uint(f);
  return (b & 0x80000000u) ? ~b : (b | 0x80000000u);
}
__device__ __forceinline__ float funmap(unsigned u){
  unsigned b = (u & 0x80000000u) ? (u & 0x7fffffffu) : ~u;
  return __uint_as_float(b);
}
__device__ __forceinline__ unsigned short f2bf(float f){
  unsigned u = __float_as_uint(f);
  u += 0x7fffu + ((u >> 16) & 1u);
  return (unsigned short)(u >> 16);
}
__device__ __forceinline__ float bf2f(unsigned short h){
  return __uint_as_float(((unsigned)h) << 16);
}
__device__ __forceinline__ void cvt8(const float* f, bf16x8& hi, bf16x8& lo){
  #pragma unroll
  for (int j = 0; j < 8; ++j){
    unsigned short hb = f2bf(f[j]);
    hi[j] = (short)hb;
    lo[j] = (short)f2bf(f[j] - bf2f(hb));
  }
}

__device__ __forceinline__ void cswap(ull& a, ull& b, bool up){
  if ((a > b) == up){ ull t = a; a = b; b = t; }
}
// bitonic stages k=2,4,8 on 8 contiguous elements starting at gbase (gbase%8==0)
__device__ __forceinline__ void bitonic8_initial(ull r[8], unsigned gbase){
  #pragma unroll
  for (int p = 0; p < 4; ++p){
    bool up = (((gbase + 2*p) & 2) == 0);
    cswap(r[2*p], r[2*p+1], up);
  }
  #pragma unroll
  for (int b = 0; b < 2; ++b){
    bool up = (((gbase + 4*b) & 4) == 0);
    cswap(r[4*b+0], r[4*b+2], up);
    cswap(r[4*b+1], r[4*b+3], up);
    cswap(r[4*b+0], r[4*b+1], up);
    cswap(r[4*b+2], r[4*b+3], up);
  }
  bool up = ((gbase & 8) == 0);
  #pragma unroll
  for (int i = 0; i < 4; ++i) cswap(r[i], r[i+4], up);
  #pragma unroll
  for (int b = 0; b < 2; ++b){
    cswap(r[4*b+0], r[4*b+2], up);
    cswap(r[4*b+1], r[4*b+3], up);
  }
  #pragma unroll
  for (int p = 0; p < 4; ++p) cswap(r[2*p], r[2*p+1], up);
}
// j=4,2,1 finish of a stage k>=16; direction uniform across the 8
__device__ __forceinline__ void bitonic8_finish(ull r[8], bool up){
  #pragma unroll
  for (int i = 0; i < 4; ++i) cswap(r[i], r[i+4], up);
  #pragma unroll
  for (int b = 0; b < 2; ++b){
    cswap(r[4*b+0], r[4*b+2], up);
    cswap(r[4*b+1], r[4*b+3], up);
  }
  #pragma unroll
  for (int p = 0; p < 4; ++p) cswap(r[2*p], r[2*p+1], up);
}

// ---------------- prep
__global__ __launch_bounds__(256) void k_prep(const float* __restrict__ w_rpe,
        float* __restrict__ qw_sqrt, unsigned* __restrict__ slots_hi,
        unsigned* __restrict__ slots_lo){
  int tid = threadIdx.x;
  if (tid < NSEG){ slots_hi[tid] = 0u; slots_lo[tid] = 0xFFFFFFFFu; }
  __shared__ float S[24][8];
  if (tid < 192){
    int hr = tid >> 3, kk = tid & 7;
    int h = hr / 3, r = hr % 3;
    float s = 0.f;
    #pragma unroll
    for (int d = 0; d < DIM; ++d) s += w_rpe[(h*DIM + d)*24 + (r*8 + kk)];
    S[hr][kk] = expf(fminf(s, 50.f));
  }
  __syncthreads();
  if (tid < 24){
    float q = 0.f;
    #pragma unroll
    for (int kk = 0; kk < 8; ++kk) q += S[tid][kk];
    qw_sqrt[tid] = sqrtf(2.f * q);
  }
}

// ---------------- LN1 + QKV projection fused (128 tokens/block)
__global__ __launch_bounds__(256) void k_qkv(const float* __restrict__ x,
        const float* __restrict__ n1w, const float* __restrict__ n1b,
        const float* __restrict__ coords, const float* __restrict__ wq,
        const float* __restrict__ wk, const float* __restrict__ wv,
        const float* __restrict__ qw_sqrt,
        float* __restrict__ q_hat, float* __restrict__ k_hat,
        float* __restrict__ val){
  __shared__ float W[3][DIM][NH*DIM];   // 96 KB
  __shared__ float XT[128][33];         // 16.9 KB
  int tid = threadIdx.x;
  for (int idx = tid; idx < 3*DIM*NH*DIM; idx += 256){
    int which = idx / (DIM*NH*DIM);
    int rem = idx % (DIM*NH*DIM);
    const float* src = which==0 ? wq : (which==1 ? wk : wv);
    W[which][rem/(NH*DIM)][rem%(NH*DIM)] = src[rem];
  }
  int base = blockIdx.x * 128;
  if (tid < 128){
    const float4* xr4 = (const float4*)(x + (size_t)(base + tid)*DIM);
    float4 v[8];
    float s = 0.f;
    #pragma unroll
    for (int u = 0; u < 8; ++u){ v[u] = xr4[u]; s += v[u].x+v[u].y+v[u].z+v[u].w; }
    float mu = s * (1.f/32.f);
    float var = 0.f;
    #pragma unroll
    for (int u = 0; u < 8; ++u){
      float a0=v[u].x-mu, a1=v[u].y-mu, a2=v[u].z-mu, a3=v[u].w-mu;
      var += a0*a0+a1*a1+a2*a2+a3*a3;
    }
    var *= (1.f/32.f);
    float rs = rsqrtf(var + 1e-5f);
    #pragma unroll
    for (int u = 0; u < 8; ++u){
      XT[tid][u*4+0] = (v[u].x-mu)*rs*n1w[u*4+0] + n1b[u*4+0];
      XT[tid][u*4+1] = (v[u].y-mu)*rs*n1w[u*4+1] + n1b[u*4+1];
      XT[tid][u*4+2] = (v[u].z-mu)*rs*n1w[u*4+2] + n1b[u*4+2];
      XT[tid][u*4+3] = (v[u].w-mu)*rs*n1w[u*4+3] + n1b[u*4+3];
    }
  }
  __syncthreads();
  int h = tid >> 5, i = tid & 31;
  #pragma unroll
  for (int rep = 0; rep < 4; ++rep){
    int tl = i + 32*rep;
    int n = base + tl;
    float xr[32];
    #pragma unroll
    for (int d = 0; d < 32; ++d) xr[d] = XT[tl][d];
    float cpart[3];
    #pragma unroll
    for (int r = 0; r < 3; ++r) cpart[r] = qw_sqrt[h*3+r] * coords[(size_t)n*3 + r];

    float* dq = q_hat + ((size_t)h*NPTS + n)*DP;
    float* dk = k_hat + ((size_t)h*NPTS + n)*DP;
    float* dv = val   + ((size_t)h*NPTS + n)*DIM;
    #pragma unroll
    for (int which = 0; which < 3; ++which){
      for (int j0 = 0; j0 < 32; j0 += 4){
        float4 acc = {0.f,0.f,0.f,0.f};
        #pragma unroll
        for (int d = 0; d < 32; ++d){
          float4 wv4 = *(const float4*)&W[which][d][h*32 + j0];
          acc.x += xr[d]*wv4.x; acc.y += xr[d]*wv4.y;
          acc.z += xr[d]*wv4.z; acc.w += xr[d]*wv4.w;
        }
        if (which == 0)      *(float4*)&dq[j0] = acc;
        else if (which == 1) *(float4*)&dk[j0] = acc;
        else                 *(float4*)&dv[j0] = acc;
      }
    }
    dq[32]=cpart[0]; dq[33]=cpart[1]; dq[34]=cpart[2]; dq[35]=0.f;
    dk[32]=cpart[0]; dk[33]=cpart[1]; dk[34]=cpart[2]; dk[35]=0.f;
  }
}

// ---------------- LSH hash values + per-(c,h) hi/lo
__global__ __launch_bounds__(256) void k_hash(const float* __restrict__ q_hat,
        const float* __restrict__ k_hat, const float* __restrict__ alpha,
        float* __restrict__ qh_buf, float* __restrict__ kh_buf,
        unsigned* __restrict__ slots_hi, unsigned* __restrict__ slots_lo){
  int h = blockIdx.y;
  int n = blockIdx.x*256 + threadIdx.x;
  __shared__ float A[DH][NC];
  for (int idx = threadIdx.x; idx < DH*NC; idx += 256)
    A[idx/3][idx%3] = alpha[h*DH*NC + idx];
  __syncthreads();
  float qr[36], kr[36];
  const float4* qp = (const float4*)(q_hat + ((size_t)h*NPTS + n)*DP);
  const float4* kp = (const float4*)(k_hat + ((size_t)h*NPTS + n)*DP);
  #pragma unroll
  for (int u = 0; u < 9; ++u){
    *(float4*)&qr[u*4] = qp[u];
    *(float4*)&kr[u*4] = kp[u];
  }
  #pragma unroll
  for (int c = 0; c < NC; ++c){
    float qh = 0.f, kh = 0.f;
    #pragma unroll
    for (int d = 0; d < DH; ++d){ qh += qr[d]*A[d][c]; kh += kr[d]*A[d][c]; }
    qh_buf[((size_t)(c*NH + h))*NPTS + n] = qh;
    kh_buf[((size_t)(c*NH + h))*NPTS + n] = kh;
    float hi = fmaxf(qh, kh), lo = fminf(qh, kh);
    #pragma unroll
    for (int off = 32; off; off >>= 1){
      hi = fmaxf(hi, __shfl_xor(hi, off));
      lo = fminf(lo, __shfl_xor(lo, off));
    }
    if ((threadIdx.x & 63) == 0){
      atomicMax(&slots_hi[c*NH + h], fmap(hi));
      atomicMin(&slots_lo[c*NH + h], fmap(lo));
    }
  }
}

// ---------------- pack + bitonic k=2..8192 within 8192-chunk
__global__ __launch_bounds__(1024) void k_sort_pack_local(
        const float* __restrict__ qh_buf, const float* __restrict__ kh_buf,
        const int* __restrict__ shifts,
        const unsigned* __restrict__ slots_hi, const unsigned* __restrict__ slots_lo,
        ull* __restrict__ packed){
  __shared__ ull ld[9216];
  int chunk = blockIdx.x;            // 0..191
  int lst = chunk >> 2;              // 0..47 (0..23 q, 24..47 k)
  int seg = lst < NSEG ? lst : lst - NSEG;
  const float* buf = lst < NSEG ? qh_buf : kh_buf;
  unsigned coff = (unsigned)(chunk & 3) * 8192u;
  float hs = funmap(slots_hi[seg]) - funmap(slots_lo[seg]);
  unsigned tid = threadIdx.x;

  {
    ull r[8];
    unsigned gb = coff + 8u*tid;
    #pragma unroll
    for (int e = 0; e < 8; ++e){
      unsigned n = gb + e;
      size_t gi = (size_t)seg*NPTS + n;
      float key = buf[gi] + (float)shifts[gi] * hs;
      r[e] = ((ull)fmap(key) << 32) | n;
    }
    bitonic8_initial(r, gb);
    #pragma unroll
    for (int e = 0; e < 8; ++e) ld[9u*tid + e] = r[e];
  }
  __syncthreads();

  for (unsigned k = 16; k <= 8192u; k <<= 1){
    for (unsigned j = k >> 1; j >= 8; j >>= 1){
      #pragma unroll
      for (int it = 0; it < 4; ++it){
        unsigned p = tid + 1024u*it;
        unsigned i  = ((p & ~(j-1)) << 1) | (p & (j-1));
        unsigned x2 = i | j;
        bool up = (((coff + i) & k) == 0);
        unsigned pi = i + (i>>3), px = x2 + (x2>>3);
        ull a = ld[pi], b2 = ld[px];
        if ((a > b2) == up){ ld[pi] = b2; ld[px] = a; }
      }
      __syncthreads();
    }
    {
      ull r[8];
      #pragma unroll
      for (int e = 0; e < 8; ++e) r[e] = ld[9u*tid + e];
      bool up = (((coff + 8u*tid) & k) == 0);
      bitonic8_finish(r, up);
      #pragma unroll
      for (int e = 0; e < 8; ++e) ld[9u*tid + e] = r[e];
    }
    __syncthreads();
  }
  size_t base = (size_t)lst*NPTS + coff;
  for (unsigned idx = tid; idx < 8192; idx += 1024)
    packed[base + idx] = ld[idx + (idx>>3)];
}

// ---------------- bitonic: LDS chunk stages
__global__ __launch_bounds__(1024) void k_sort_local(ull* __restrict__ data,
        unsigned k_lo, unsigned k_hi){
  __shared__ ull ld[9216];
  int chunk = blockIdx.x;
  size_t base = (size_t)chunk * 8192;
  unsigned coff = (unsigned)(chunk & 3) * 8192u;
  unsigned tid = threadIdx.x;
  for (unsigned idx = tid; idx < 8192; idx += 1024)
    ld[idx + (idx>>3)] = data[base + idx];
  __syncthreads();
  for (unsigned k = k_lo; k <= k_hi; k <<= 1){
    unsigned j0 = (k >> 1) < 4096u ? (k >> 1) : 4096u;
    for (unsigned j = j0; j >= 8; j >>= 1){
      #pragma unroll
      for (int it = 0; it < 4; ++it){
        unsigned p = tid + 1024u*it;
        unsigned i  = ((p & ~(j-1)) << 1) | (p & (j-1));
        unsigned x2 = i | j;
        bool up = (((coff + i) & k) == 0);
        unsigned pi = i + (i>>3), px = x2 + (x2>>3);
        ull a = ld[pi], b2 = ld[px];
        if ((a > b2) == up){ ld[pi] = b2; ld[px] = a; }
      }
      __syncthreads();
    }
    {
      ull r[8];
      #pragma unroll
      for (int e = 0; e < 8; ++e) r[e] = ld[9u*tid + e];
      bool up = (((coff + 8u*tid) & k) == 0);
      bitonic8_finish(r, up);
      #pragma unroll
      for (int e = 0; e < 8; ++e) ld[9u*tid + e] = r[e];
    }
    __syncthreads();
  }
  for (unsigned idx = tid; idx < 8192; idx += 1024)
    data[base + idx] = ld[idx + (idx>>3)];
}

// ---------------- bitonic sort: one global compare-exchange pass
__global__ __launch_bounds__(256) void k_sort_global(ull* __restrict__ data,
        unsigned k, unsigned j){
  unsigned t = blockIdx.x*256 + threadIdx.x;
  unsigned seg = t >> 14;
  unsigned p = t & 16383u;
  unsigned i  = ((p & ~(j-1)) << 1) | (p & (j-1));
  unsigned x2 = i | j;
  size_t base = (size_t)seg << 15;
  bool up = ((i & k) == 0);
  ull a = data[base + i], b = data[base + x2];
  if ((a > b) == up){ data[base + i] = b; data[base + x2] = a; }
}

// ---------------- bucketed kernelized attention
// LDS 40 KB: KP union (Khi[128][64] @0 / Klo[128][64] @8192; P[128][128] after
// the post-QK barrier) + Vt[32][128]. Q lives in registers (per-lane global
// gather + in-lane hi/lo split); qsq via shfl_xor over the 4 g-lanes.
__global__ __launch_bounds__(512, 6) void k_attn(const float* __restrict__ q_hat,
        const float* __restrict__ k_hat, const float* __restrict__ val,
        const ull* __restrict__ packed, float* __restrict__ o_acc,
        float* __restrict__ logit_acc){
  __shared__ short KP[16384];   // 32 KB
  __shared__ short Vt[4096];    // 8 KB [vdim][key] swizzled

  int t = threadIdx.x;
  int blk = blockIdx.x;
  int seg = blk >> 8;
  int b = blk & 255;
  int h = seg & 7;
  const ull* pq = packed + ((size_t)seg << 15) + (size_t)b*BSZ;
  const ull* pk = packed + ((size_t)(NSEG + seg) << 15) + (size_t)b*BSZ;

  int lane = t & 63;
  int w = t >> 6;                 // wave 0..7, owns q rows [16w, 16w+16)
  int l15 = lane & 15, g = lane >> 4;
  int qrow = 16*w + l15;

  // per-lane Q gather (issued early, overlaps staging)
  unsigned iqr = (unsigned)(pq[qrow] & 0xffffffffull);
  const float* qr = q_hat + ((size_t)h*NPTS + iqr)*DP;
  float4 qa = ((const float4*)qr)[2*g];
  float4 qb = ((const float4*)qr)[2*g+1];
  float4 qt = ((const float4*)qr)[8];      // dims 32..35 (35 is 0)

  // staging: t<128 -> K row t; t in [128,384) -> V half-rows
  if (t < 128){
    unsigned ik = (unsigned)(pk[t] & 0xffffffffull);
    const float* kr = k_hat + ((size_t)h*NPTS + ik)*DP;
    float f[40];
    #pragma unroll
    for (int u = 0; u < 9; ++u) *(float4*)&f[u*4] = ((const float4*)kr)[u];
    float sq = 0.f;
    #pragma unroll
    for (int d = 0; d < 36; ++d) sq += f[d]*f[d];   // f[35] is 0 pad
    f[35] = -0.5f * sq;
    f[36] = 1.0f;
    f[37] = 0.f; f[38] = 0.f; f[39] = 0.f;
    int rowbase = t*64;
    int sw = (t & 7) << 3;
    #pragma unroll
    for (int c = 0; c < 40; c += 4){
      unsigned short h0=f2bf(f[c]),   h1=f2bf(f[c+1]);
      unsigned short h2=f2bf(f[c+2]), h3=f2bf(f[c+3]);
      unsigned short l0=f2bf(f[c]  -bf2f(h0)), l1=f2bf(f[c+1]-bf2f(h1));
      unsigned short l2=f2bf(f[c+2]-bf2f(h2)), l3=f2bf(f[c+3]-bf2f(h3));
      int o = rowbase + (c ^ sw);
      uint2 hv, lv;
      hv.x = (unsigned)h0 | ((unsigned)h1 << 16);
      hv.y = (unsigned)h2 | ((unsigned)h3 << 16);
      lv.x = (unsigned)l0 | ((unsigned)l1 << 16);
      lv.y = (unsigned)l2 | ((unsigned)l3 << 16);
      *(uint2*)&KP[o] = hv;
      *(uint2*)&KP[8192 + o] = lv;
    }
    #pragma unroll
    for (int c = 40; c < 64; c += 4){
      int o = rowbase + (c ^ sw);
      *(uint2*)&KP[o] = (uint2){0u,0u};
      *(uint2*)&KP[8192 + o] = (uint2){0u,0u};
    }
  } else if (t < 384){
    int r = (t - 128) & 127;
    int half = (t - 128) >> 7;   // 0 or 1
    unsigned ik = (unsigned)(pk[r] & 0xffffffffull);
    const float* vr = val + ((size_t)h*NPTS + ik)*DIM + 16*half;
    float fv[16];
    #pragma unroll
    for (int u = 0; u < 4; ++u) *(float4*)&fv[u*4] = ((const float4*)vr)[u];
    #pragma unroll
    for (int d = 0; d < 16; ++d){
      int vd = 16*half + d;
      Vt[vd*128 + (r ^ ((vd&7)<<3))] = (short)f2bf(fv[d]);
    }
  }

  // build Q fragments in registers
  float f0[8] = {qa.x,qa.y,qa.z,qa.w, qb.x,qb.y,qb.z,qb.w};
  float psq = 0.f;
  #pragma unroll
  for (int j = 0; j < 8; ++j) psq += f0[j]*f0[j];
  if (g == 0) psq += qt.x*qt.x + qt.y*qt.y + qt.z*qt.z;
  psq += __shfl_xor(psq, 16);
  psq += __shfl_xor(psq, 32);
  float qsq = -0.5f * psq;
  bf16x8 qh0, ql0, qh1, ql1;
  cvt8(f0, qh0, ql0);
  float f1[8] = {0.f,0.f,0.f,0.f,0.f,0.f,0.f,0.f};
  if (g == 0){
    f1[0] = qt.x; f1[1] = qt.y; f1[2] = qt.z;
    f1[3] = 1.0f;      // pairs with ksq at dim35
    f1[4] = qsq;       // pairs with 1.0 at dim36
  }
  cvt8(f1, qh1, ql1);

  __syncthreads();

  // QK^T: S^T = K.Q^T
  f32x4 acc[8];
  #pragma unroll
  for (int kt = 0; kt < 8; ++kt) acc[kt] = (f32x4){0.f,0.f,0.f,0.f};
  #pragma unroll
  for (int kt = 0; kt < 8; ++kt){
    int krow = 16*kt + l15;
    int base = krow*64;
    int sw = (krow & 7) << 3;
    bf16x8 ah0 = *(const bf16x8*)&KP[base + ((8*g) ^ sw)];
    bf16x8 ah1 = *(const bf16x8*)&KP[base + ((32 + 8*g) ^ sw)];
    bf16x8 al0 = *(const bf16x8*)&KP[8192 + base + ((8*g) ^ sw)];
    bf16x8 al1 = *(const bf16x8*)&KP[8192 + base + ((32 + 8*g) ^ sw)];
    f32x4 c = acc[kt];
    c = __builtin_amdgcn_mfma_f32_16x16x32_bf16(ah0, qh0, c, 0, 0, 0);
    c = __builtin_amdgcn_mfma_f32_16x16x32_bf16(ah1, qh1, c, 0, 0, 0);
    c = __builtin_amdgcn_mfma_f32_16x16x32_bf16(al0, qh0, c, 0, 0, 0);
    c = __builtin_amdgcn_mfma_f32_16x16x32_bf16(al1, qh1, c, 0, 0, 0);
    c = __builtin_amdgcn_mfma_f32_16x16x32_bf16(ah0, ql0, c, 0, 0, 0);
    c = __builtin_amdgcn_mfma_f32_16x16x32_bf16(ah1, ql1, c, 0, 0, 0);
    acc[kt] = c;
  }

  __syncthreads();   // all QK done -> K region dead, P may overwrite

  // exp + P(bf16) into KP as [q=128][key=128], swizzled; fp32 denom per lane
  int qsw = (qrow & 7) << 3;
  float dena = 0.f;
  #pragma unroll
  for (int kt = 0; kt < 8; ++kt){
    f32x4 c = acc[kt];
    float p0 = __expf(fminf(c[0], 0.f));
    float p1 = __expf(fminf(c[1], 0.f));
    float p2 = __expf(fminf(c[2], 0.f));
    float p3 = __expf(fminf(c[3], 0.f));
    dena += p0 + p1 + p2 + p3;
    int key = 16*kt + 4*g;
    uint2 pv;
    pv.x = (unsigned)f2bf(p0) | ((unsigned)f2bf(p1) << 16);
    pv.y = (unsigned)f2bf(p2) | ((unsigned)f2bf(p3) << 16);
    *(uint2*)&KP[qrow*128 + (key ^ qsw)] = pv;
  }
  // P write->read is within-wave (each wave only touches its own 16 q-rows): no barrier

  // PV via MFMA: A = P (m=q), B = V^T (n=vdim)
  f32x4 oacc[2];
  oacc[0] = (f32x4){0.f,0.f,0.f,0.f};
  oacc[1] = (f32x4){0.f,0.f,0.f,0.f};
  #pragma unroll
  for (int ks = 0; ks < 4; ++ks){
    bf16x8 pA = *(const bf16x8*)&KP[qrow*128 + ((32*ks + 8*g) ^ qsw)];
    #pragma unroll
    for (int nt = 0; nt < 2; ++nt){
      int vd = 16*nt + l15;
      bf16x8 vB = *(const bf16x8*)&Vt[vd*128 + ((32*ks + 8*g) ^ ((vd&7)<<3))];
      oacc[nt] = __builtin_amdgcn_mfma_f32_16x16x32_bf16(pA, vB, oacc[nt], 0, 0, 0);
    }
  }

  // denom scatter
  {
    float d = dena;
    d += __shfl_xor(d, 16);
    d += __shfl_xor(d, 32);
    if (lane < 16) atomicAdd(&logit_acc[(size_t)h*NPTS + iqr], d + 1e-20f);
  }
  // O scatter (iq via intra-wave shuffle of the per-lane iqr)
  #pragma unroll
  for (int nt = 0; nt < 2; ++nt){
    f32x4 c = oacc[nt];
    #pragma unroll
    for (int r = 0; r < 4; ++r){
      unsigned iq = (unsigned)__shfl((int)iqr, 4*g + r);
      atomicAdd(&o_acc[((size_t)h*NPTS + iq)*DIM + 16*nt + l15], c[r]);
    }
  }
}

// ---------------- out-proj + residual + LN2 + FF + residual
__global__ __launch_bounds__(256) void k_final(const float* __restrict__ x,
        const float* __restrict__ o_acc, const float* __restrict__ logit_acc,
        const float* __restrict__ out_w, const float* __restrict__ out_b,
        const float* __restrict__ n2w, const float* __restrict__ n2b,
        const float* __restrict__ f1w, const float* __restrict__ f1b,
        const float* __restrict__ f2w, const float* __restrict__ f2b,
        float* __restrict__ out){
  __shared__ float OW[256][32];   // 32 KB
  __shared__ float F1[32][32];
  __shared__ float F2[32][32];
  int tid = threadIdx.x;
  for (int idx = tid; idx < 256*32; idx += 256) OW[idx/32][idx%32] = out_w[idx];
  for (int idx = tid; idx < 1024; idx += 256){
    F1[idx/32][idx%32] = f1w[idx];
    F2[idx/32][idx%32] = f2w[idx];
  }
  __syncthreads();
  int n = blockIdx.x*256 + tid;
  float attn[32];
  #pragma unroll
  for (int j = 0; j < 32; ++j) attn[j] = out_b[j];
  for (int h = 0; h < 8; ++h){
    float inv = 1.f / logit_acc[(size_t)h*NPTS + n];
    const float4* orow = (const float4*)(o_acc + ((size_t)h*NPTS + n)*DIM);
    #pragma unroll
    for (int u = 0; u < 8; ++u){
      float4 ov = orow[u];
      float vals[4] = {ov.x*inv, ov.y*inv, ov.z*inv, ov.w*inv};
      #pragma unroll
      for (int s = 0; s < 4; ++s){
        const float* wrow = &OW[h*32 + u*4 + s][0];
        #pragma unroll
        for (int j = 0; j < 32; ++j) attn[j] += vals[s] * wrow[j];
      }
    }
  }
  const float* xp = x + (size_t)n*DIM;
  float xr[32]; float s = 0.f;
  #pragma unroll
  for (int d = 0; d < 32; ++d){ xr[d] = xp[d] + attn[d]; s += xr[d]; }
  float mu = s * (1.f/32.f);
  float var = 0.f;
  #pragma unroll
  for (int d = 0; d < 32; ++d){ float dx = xr[d]-mu; var += dx*dx; }
  var *= (1.f/32.f);
  float rs = rsqrtf(var + 1e-5f);
  float xn2[32];
  #pragma unroll
  for (int d = 0; d < 32; ++d) xn2[d] = (xr[d]-mu)*rs*n2w[d] + n2b[d];
  float z[32];
  #pragma unroll
  for (int j = 0; j < 32; ++j) z[j] = f1b[j];
  #pragma unroll
  for (int d = 0; d < 32; ++d){
    float xd = xn2[d];
    const float* wrow = &F1[d][0];
    #pragma unroll
    for (int j = 0; j < 32; ++j) z[j] += xd * wrow[j];
  }
  #pragma unroll
  for (int j = 0; j < 32; ++j) z[j] = z[j] / (1.f + __expf(-z[j]));
  float y[32];
  #pragma unroll
  for (int d = 0; d < 32; ++d) y[d] = f2b[d];
  #pragma unroll
  for (int j = 0; j < 32; ++j){
    float zj = z[j];
    const float* wrow = &F2[j][0];
    #pragma unroll
    for (int d = 0; d < 32; ++d) y[d] += zj * wrow[d];
  }
  float* op = out + (size_t)n*DIM;
  #pragma unroll
  for (int d = 0; d < 32; ++d) op[d] = xr[d] + y[d];
}

extern "C" void kernel_launch(void* const* d_in, const int* in_sizes, int n_in,
                              void* d_out, int out_size, void* d_ws, size_t ws_size,
                              hipStream_t stream){
  const float* x      = (const float*)d_in[0];
  const float* coords = (const float*)d_in[1];
  const int*   shifts = (const int*)d_in[2];
  const float* n1w    = (const float*)d_in[3];
  const float* n1b    = (const float*)d_in[4];
  const float* wq     = (const float*)d_in[5];
  const float* wk     = (const float*)d_in[6];
  const float* wv     = (const float*)d_in[7];
  const float* w_rpe  = (const float*)d_in[8];
  const float* alpha  = (const float*)d_in[9];
  const float* out_w  = (const float*)d_in[10];
  const float* out_b  = (const float*)d_in[11];
  const float* n2w    = (const float*)d_in[12];
  const float* n2b    = (const float*)d_in[13];
  const float* f1w    = (const float*)d_in[14];
  const float* f1b    = (const float*)d_in[15];
  const float* f2w    = (const float*)d_in[16];
  const float* f2b    = (const float*)d_in[17];
  float* out = (float*)d_out;

  char* ws = (char*)d_ws;
  size_t off = 0;
  auto alloc = [&](size_t bytes){ size_t o = off; off += (bytes + 255) & ~(size_t)255; return o; };
  float*    qw_sqrt   = (float*)   (ws + alloc(24*4));
  unsigned* slots_hi  = (unsigned*)(ws + alloc(24*4));
  unsigned* slots_lo  = (unsigned*)(ws + alloc(24*4));
  float*    q_hat     = (float*)   (ws + alloc((size_t)NH*NPTS*DP*4));
  float*    k_hat     = (float*)   (ws + alloc((size_t)NH*NPTS*DP*4));
  float*    val       = (float*)   (ws + alloc((size_t)NH*NPTS*DIM*4));
  float*    qh_buf    = (float*)   (ws + alloc((size_t)NSEG*NPTS*4));
  float*    kh_buf    = (float*)   (ws + alloc((size_t)NSEG*NPTS*4));
  ull*      packed    = (ull*)     (ws + alloc((size_t)2*NSEG*NPTS*8));
  float*    o_acc     = (float*)   (ws + alloc((size_t)NH*NPTS*DIM*4));
  float*    logit_acc = (float*)   (ws + alloc((size_t)NH*NPTS*4));
  if (off > ws_size) return;

  hipMemsetAsync(o_acc, 0, (size_t)NH*NPTS*DIM*4, stream);
  hipMemsetAsync(logit_acc, 0, (size_t)NH*NPTS*4, stream);

  k_prep<<<1, 256, 0, stream>>>(w_rpe, qw_sqrt, slots_hi, slots_lo);
  k_qkv<<<NPTS/128, 256, 0, stream>>>(x, n1w, n1b, coords, wq, wk, wv, qw_sqrt,
                                      q_hat, k_hat, val);
  k_hash<<<dim3(NPTS/256, NH), 256, 0, stream>>>(q_hat, k_hat, alpha, qh_buf, kh_buf,
                                                 slots_hi, slots_lo);
  // 48 segments of 32768 -> bitonic
  k_sort_pack_local<<<2*NSEG*4, 1024, 0, stream>>>(qh_buf, kh_buf, shifts,
                                                   slots_hi, slots_lo, packed);
  k_sort_global<<<(2*NSEG*16384)/256, 256, 0, stream>>>(packed, 16384u, 8192u);
  k_sort_local<<<2*NSEG*4, 1024, 0, stream>>>(packed, 16384u, 16384u);
  k_sort_global<<<(2*NSEG*16384)/256, 256, 0, stream>>>(packed, 32768u, 16384u);
  k_sort_global<<<(2*NSEG*16384)/256, 256, 0, stream>>>(packed, 32768u, 8192u);
  k_sort_local<<<2*NSEG*4, 1024, 0, stream>>>(packed, 32768u, 32768u);

  k_attn<<<NSEG*NB, 512, 0, stream>>>(q_hat, k_hat, val, packed, o_acc, logit_acc);
  k_final<<<NPTS/256, 256, 0, stream>>>(x, o_acc, logit_acc, out_w, out_b,
                                        n2w, n2b, f1w, f1b, f2w, f2b, out);
}

// Round 8
// 498.907 us; speedup vs baseline: 1.4472x; 1.0537x over previous
//
#include <hip/hip_runtime.h>

#define NPTS 32768
#define DIM 32
#define NH 8
#define NC 3
#define BSZ 128
#define NB 256
#define DH 35
#define DP 36
#define NSEG 24   // C*H

typedef unsigned long long ull;
typedef __attribute__((ext_vector_type(8))) short bf16x8;
typedef __attribute__((ext_vector_type(4))) float f32x4;

__device__ __forceinline__ unsigned fmap(float f){
  unsigned b = __float_as_uint(f);
  return (b & 0x80000000u) ? ~b : (b | 0x80000000u);
}
__device__ __forceinline__ float funmap(unsigned u){
  unsigned b = (u & 0x80000000u) ? (u & 0x7fffffffu) : ~u;
  return __uint_as_float(b);
}
__device__ __forceinline__ unsigned short f2bf(float f){
  unsigned u = __float_as_uint(f);
  u += 0x7fffu + ((u >> 16) & 1u);
  return (unsigned short)(u >> 16);
}
__device__ __forceinline__ float bf2f(unsigned short h){
  return __uint_as_float(((unsigned)h) << 16);
}
__device__ __forceinline__ void cvt8(const float* f, bf16x8& hi, bf16x8& lo){
  #pragma unroll
  for (int j = 0; j < 8; ++j){
    unsigned short hb = f2bf(f[j]);
    hi[j] = (short)hb;
    lo[j] = (short)f2bf(f[j] - bf2f(hb));
  }
}

__device__ __forceinline__ void cswap(ull& a, ull& b, bool up){
  if ((a > b) == up){ ull t = a; a = b; b = t; }
}
// bitonic stages k=2,4,8 on 8 contiguous elements starting at gbase (gbase%8==0)
__device__ __forceinline__ void bitonic8_initial(ull r[8], unsigned gbase){
  #pragma unroll
  for (int p = 0; p < 4; ++p){
    bool up = (((gbase + 2*p) & 2) == 0);
    cswap(r[2*p], r[2*p+1], up);
  }
  #pragma unroll
  for (int b = 0; b < 2; ++b){
    bool up = (((gbase + 4*b) & 4) == 0);
    cswap(r[4*b+0], r[4*b+2], up);
    cswap(r[4*b+1], r[4*b+3], up);
    cswap(r[4*b+0], r[4*b+1], up);
    cswap(r[4*b+2], r[4*b+3], up);
  }
  bool up = ((gbase & 8) == 0);
  #pragma unroll
  for (int i = 0; i < 4; ++i) cswap(r[i], r[i+4], up);
  #pragma unroll
  for (int b = 0; b < 2; ++b){
    cswap(r[4*b+0], r[4*b+2], up);
    cswap(r[4*b+1], r[4*b+3], up);
  }
  #pragma unroll
  for (int p = 0; p < 4; ++p) cswap(r[2*p], r[2*p+1], up);
}
// j=4,2,1 finish of a stage k>=16; direction uniform across the 8
__device__ __forceinline__ void bitonic8_finish(ull r[8], bool up){
  #pragma unroll
  for (int i = 0; i < 4; ++i) cswap(r[i], r[i+4], up);
  #pragma unroll
  for (int b = 0; b < 2; ++b){
    cswap(r[4*b+0], r[4*b+2], up);
    cswap(r[4*b+1], r[4*b+3], up);
  }
  #pragma unroll
  for (int p = 0; p < 4; ++p) cswap(r[2*p], r[2*p+1], up);
}

// ---------------- prep
__global__ __launch_bounds__(256) void k_prep(const float* __restrict__ w_rpe,
        float* __restrict__ qw_sqrt, unsigned* __restrict__ slots_hi,
        unsigned* __restrict__ slots_lo){
  int tid = threadIdx.x;
  if (tid < NSEG){ slots_hi[tid] = 0u; slots_lo[tid] = 0xFFFFFFFFu; }
  __shared__ float S[24][8];
  if (tid < 192){
    int hr = tid >> 3, kk = tid & 7;
    int h = hr / 3, r = hr % 3;
    float s = 0.f;
    #pragma unroll
    for (int d = 0; d < DIM; ++d) s += w_rpe[(h*DIM + d)*24 + (r*8 + kk)];
    S[hr][kk] = expf(fminf(s, 50.f));
  }
  __syncthreads();
  if (tid < 24){
    float q = 0.f;
    #pragma unroll
    for (int kk = 0; kk < 8; ++kk) q += S[tid][kk];
    qw_sqrt[tid] = sqrtf(2.f * q);
  }
}

// ---------------- LN1 + QKV projection fused (128 tokens/block, 4-token W reuse)
__global__ __launch_bounds__(256, 1) void k_qkv(const float* __restrict__ x,
        const float* __restrict__ n1w, const float* __restrict__ n1b,
        const float* __restrict__ coords, const float* __restrict__ wq,
        const float* __restrict__ wk, const float* __restrict__ wv,
        const float* __restrict__ qw_sqrt,
        float* __restrict__ q_hat, float* __restrict__ k_hat,
        float* __restrict__ val){
  __shared__ float W[3][DIM][NH*DIM];   // 96 KB
  __shared__ float XT[128][33];         // 16.9 KB
  int tid = threadIdx.x;
  for (int idx = tid; idx < 3*DIM*NH*DIM; idx += 256){
    int which = idx / (DIM*NH*DIM);
    int rem = idx % (DIM*NH*DIM);
    const float* src = which==0 ? wq : (which==1 ? wk : wv);
    W[which][rem/(NH*DIM)][rem%(NH*DIM)] = src[rem];
  }
  int base = blockIdx.x * 128;
  if (tid < 128){
    const float4* xr4 = (const float4*)(x + (size_t)(base + tid)*DIM);
    float4 v[8];
    float s = 0.f;
    #pragma unroll
    for (int u = 0; u < 8; ++u){ v[u] = xr4[u]; s += v[u].x+v[u].y+v[u].z+v[u].w; }
    float mu = s * (1.f/32.f);
    float var = 0.f;
    #pragma unroll
    for (int u = 0; u < 8; ++u){
      float a0=v[u].x-mu, a1=v[u].y-mu, a2=v[u].z-mu, a3=v[u].w-mu;
      var += a0*a0+a1*a1+a2*a2+a3*a3;
    }
    var *= (1.f/32.f);
    float rs = rsqrtf(var + 1e-5f);
    #pragma unroll
    for (int u = 0; u < 8; ++u){
      XT[tid][u*4+0] = (v[u].x-mu)*rs*n1w[u*4+0] + n1b[u*4+0];
      XT[tid][u*4+1] = (v[u].y-mu)*rs*n1w[u*4+1] + n1b[u*4+1];
      XT[tid][u*4+2] = (v[u].z-mu)*rs*n1w[u*4+2] + n1b[u*4+2];
      XT[tid][u*4+3] = (v[u].w-mu)*rs*n1w[u*4+3] + n1b[u*4+3];
    }
  }
  __syncthreads();
  int h = tid >> 5, i = tid & 31;
  // 4 tokens per thread: i, i+32, i+64, i+96 — each W float4 feeds 4 FMAs
  float xr0[32], xr1[32], xr2[32], xr3[32];
  #pragma unroll
  for (int d = 0; d < 32; ++d){
    xr0[d] = XT[i][d]; xr1[d] = XT[i+32][d];
    xr2[d] = XT[i+64][d]; xr3[d] = XT[i+96][d];
  }
  float cp[4][3];
  #pragma unroll
  for (int rep = 0; rep < 4; ++rep)
    #pragma unroll
    for (int r = 0; r < 3; ++r)
      cp[rep][r] = qw_sqrt[h*3+r] * coords[(size_t)(base + i + 32*rep)*3 + r];

  #pragma unroll
  for (int which = 0; which < 3; ++which){
    for (int j0 = 0; j0 < 32; j0 += 4){
      float4 a0 = {0,0,0,0}, a1 = {0,0,0,0}, a2 = {0,0,0,0}, a3 = {0,0,0,0};
      #pragma unroll
      for (int d = 0; d < 32; ++d){
        float4 w4 = *(const float4*)&W[which][d][h*32 + j0];
        a0.x += xr0[d]*w4.x; a0.y += xr0[d]*w4.y; a0.z += xr0[d]*w4.z; a0.w += xr0[d]*w4.w;
        a1.x += xr1[d]*w4.x; a1.y += xr1[d]*w4.y; a1.z += xr1[d]*w4.z; a1.w += xr1[d]*w4.w;
        a2.x += xr2[d]*w4.x; a2.y += xr2[d]*w4.y; a2.z += xr2[d]*w4.z; a2.w += xr2[d]*w4.w;
        a3.x += xr3[d]*w4.x; a3.y += xr3[d]*w4.y; a3.z += xr3[d]*w4.z; a3.w += xr3[d]*w4.w;
      }
      #pragma unroll
      for (int rep = 0; rep < 4; ++rep){
        int n = base + i + 32*rep;
        float4 a = rep==0 ? a0 : (rep==1 ? a1 : (rep==2 ? a2 : a3));
        float* dst = which==0 ? (q_hat + ((size_t)h*NPTS + n)*DP)
                   : (which==1 ? (k_hat + ((size_t)h*NPTS + n)*DP)
                               : (val   + ((size_t)h*NPTS + n)*DIM));
        *(float4*)&dst[j0] = a;
      }
    }
  }
  #pragma unroll
  for (int rep = 0; rep < 4; ++rep){
    int n = base + i + 32*rep;
    float* dq = q_hat + ((size_t)h*NPTS + n)*DP;
    float* dk = k_hat + ((size_t)h*NPTS + n)*DP;
    dq[32]=cp[rep][0]; dq[33]=cp[rep][1]; dq[34]=cp[rep][2]; dq[35]=0.f;
    dk[32]=cp[rep][0]; dk[33]=cp[rep][1]; dk[34]=cp[rep][2]; dk[35]=0.f;
  }
}

// ---------------- LSH hash values + per-(c,h) hi/lo
__global__ __launch_bounds__(256) void k_hash(const float* __restrict__ q_hat,
        const float* __restrict__ k_hat, const float* __restrict__ alpha,
        float* __restrict__ qh_buf, float* __restrict__ kh_buf,
        unsigned* __restrict__ slots_hi, unsigned* __restrict__ slots_lo){
  int h = blockIdx.y;
  int n = blockIdx.x*256 + threadIdx.x;
  __shared__ float A[DH][NC];
  for (int idx = threadIdx.x; idx < DH*NC; idx += 256)
    A[idx/3][idx%3] = alpha[h*DH*NC + idx];
  __syncthreads();
  float qr[36], kr[36];
  const float4* qp = (const float4*)(q_hat + ((size_t)h*NPTS + n)*DP);
  const float4* kp = (const float4*)(k_hat + ((size_t)h*NPTS + n)*DP);
  #pragma unroll
  for (int u = 0; u < 9; ++u){
    *(float4*)&qr[u*4] = qp[u];
    *(float4*)&kr[u*4] = kp[u];
  }
  #pragma unroll
  for (int c = 0; c < NC; ++c){
    float qh = 0.f, kh = 0.f;
    #pragma unroll
    for (int d = 0; d < DH; ++d){ qh += qr[d]*A[d][c]; kh += kr[d]*A[d][c]; }
    qh_buf[((size_t)(c*NH + h))*NPTS + n] = qh;
    kh_buf[((size_t)(c*NH + h))*NPTS + n] = kh;
    float hi = fmaxf(qh, kh), lo = fminf(qh, kh);
    #pragma unroll
    for (int off = 32; off; off >>= 1){
      hi = fmaxf(hi, __shfl_xor(hi, off));
      lo = fminf(lo, __shfl_xor(lo, off));
    }
    if ((threadIdx.x & 63) == 0){
      atomicMax(&slots_hi[c*NH + h], fmap(hi));
      atomicMin(&slots_lo[c*NH + h], fmap(lo));
    }
  }
}

// ---------------- pack + bitonic k=2..8192 within 8192-chunk
__global__ __launch_bounds__(1024) void k_sort_pack_local(
        const float* __restrict__ qh_buf, const float* __restrict__ kh_buf,
        const int* __restrict__ shifts,
        const unsigned* __restrict__ slots_hi, const unsigned* __restrict__ slots_lo,
        ull* __restrict__ packed){
  __shared__ ull ld[9216];
  int chunk = blockIdx.x;            // 0..191
  int lst = chunk >> 2;              // 0..47 (0..23 q, 24..47 k)
  int seg = lst < NSEG ? lst : lst - NSEG;
  const float* buf = lst < NSEG ? qh_buf : kh_buf;
  unsigned coff = (unsigned)(chunk & 3) * 8192u;
  float hs = funmap(slots_hi[seg]) - funmap(slots_lo[seg]);
  unsigned tid = threadIdx.x;

  {
    ull r[8];
    unsigned gb = coff + 8u*tid;
    #pragma unroll
    for (int e = 0; e < 8; ++e){
      unsigned n = gb + e;
      size_t gi = (size_t)seg*NPTS + n;
      float key = buf[gi] + (float)shifts[gi] * hs;
      r[e] = ((ull)fmap(key) << 32) | n;
    }
    bitonic8_initial(r, gb);
    #pragma unroll
    for (int e = 0; e < 8; ++e) ld[9u*tid + e] = r[e];
  }
  __syncthreads();

  for (unsigned k = 16; k <= 8192u; k <<= 1){
    for (unsigned j = k >> 1; j >= 8; j >>= 1){
      #pragma unroll
      for (int it = 0; it < 4; ++it){
        unsigned p = tid + 1024u*it;
        unsigned i  = ((p & ~(j-1)) << 1) | (p & (j-1));
        unsigned x2 = i | j;
        bool up = (((coff + i) & k) == 0);
        unsigned pi = i + (i>>3), px = x2 + (x2>>3);
        ull a = ld[pi], b2 = ld[px];
        if ((a > b2) == up){ ld[pi] = b2; ld[px] = a; }
      }
      __syncthreads();
    }
    {
      ull r[8];
      #pragma unroll
      for (int e = 0; e < 8; ++e) r[e] = ld[9u*tid + e];
      bool up = (((coff + 8u*tid) & k) == 0);
      bitonic8_finish(r, up);
      #pragma unroll
      for (int e = 0; e < 8; ++e) ld[9u*tid + e] = r[e];
    }
    __syncthreads();
  }
  size_t base = (size_t)lst*NPTS + coff;
  for (unsigned idx = tid; idx < 8192; idx += 1024)
    packed[base + idx] = ld[idx + (idx>>3)];
}

// ---------------- bitonic: LDS chunk stages
__global__ __launch_bounds__(1024) void k_sort_local(ull* __restrict__ data,
        unsigned k_lo, unsigned k_hi){
  __shared__ ull ld[9216];
  int chunk = blockIdx.x;
  size_t base = (size_t)chunk * 8192;
  unsigned coff = (unsigned)(chunk & 3) * 8192u;
  unsigned tid = threadIdx.x;
  for (unsigned idx = tid; idx < 8192; idx += 1024)
    ld[idx + (idx>>3)] = data[base + idx];
  __syncthreads();
  for (unsigned k = k_lo; k <= k_hi; k <<= 1){
    unsigned j0 = (k >> 1) < 4096u ? (k >> 1) : 4096u;
    for (unsigned j = j0; j >= 8; j >>= 1){
      #pragma unroll
      for (int it = 0; it < 4; ++it){
        unsigned p = tid + 1024u*it;
        unsigned i  = ((p & ~(j-1)) << 1) | (p & (j-1));
        unsigned x2 = i | j;
        bool up = (((coff + i) & k) == 0);
        unsigned pi = i + (i>>3), px = x2 + (x2>>3);
        ull a = ld[pi], b2 = ld[px];
        if ((a > b2) == up){ ld[pi] = b2; ld[px] = a; }
      }
      __syncthreads();
    }
    {
      ull r[8];
      #pragma unroll
      for (int e = 0; e < 8; ++e) r[e] = ld[9u*tid + e];
      bool up = (((coff + 8u*tid) & k) == 0);
      bitonic8_finish(r, up);
      #pragma unroll
      for (int e = 0; e < 8; ++e) ld[9u*tid + e] = r[e];
    }
    __syncthreads();
  }
  for (unsigned idx = tid; idx < 8192; idx += 1024)
    data[base + idx] = ld[idx + (idx>>3)];
}

// ---------------- bitonic sort: one global compare-exchange pass
__global__ __launch_bounds__(256) void k_sort_global(ull* __restrict__ data,
        unsigned k, unsigned j){
  unsigned t = blockIdx.x*256 + threadIdx.x;
  unsigned seg = t >> 14;
  unsigned p = t & 16383u;
  unsigned i  = ((p & ~(j-1)) << 1) | (p & (j-1));
  unsigned x2 = i | j;
  size_t base = (size_t)seg << 15;
  bool up = ((i & k) == 0);
  ull a = data[base + i], b = data[base + x2];
  if ((a > b) == up){ data[base + i] = b; data[base + x2] = a; }
}

// ---------------- bucketed kernelized attention
// LDS 40 KB: KP union (Khi[128][64] @0 / Klo[128][64] @8192; P[128][128] after
// the post-QK barrier) + Vt[32][128]. Q in registers. Staging is spread over
// all 512 threads: each thread stages a quarter-row of K and a quarter-row of V.
__global__ __launch_bounds__(512, 6) void k_attn(const float* __restrict__ q_hat,
        const float* __restrict__ k_hat, const float* __restrict__ val,
        const ull* __restrict__ packed, float* __restrict__ o_acc,
        float* __restrict__ logit_acc){
  __shared__ short KP[16384];   // 32 KB
  __shared__ short Vt[4096];    // 8 KB [vdim][key] swizzled

  int t = threadIdx.x;
  int blk = blockIdx.x;
  int seg = blk >> 8;
  int b = blk & 255;
  int h = seg & 7;
  const ull* pq = packed + ((size_t)seg << 15) + (size_t)b*BSZ;
  const ull* pk = packed + ((size_t)(NSEG + seg) << 15) + (size_t)b*BSZ;

  int lane = t & 63;
  int w = t >> 6;                 // wave 0..7, owns q rows [16w, 16w+16)
  int l15 = lane & 15, g = lane >> 4;
  int qrow = 16*w + l15;

  // per-lane Q gather (issued early, overlaps staging)
  unsigned iqr = (unsigned)(pq[qrow] & 0xffffffffull);
  const float* qr = q_hat + ((size_t)h*NPTS + iqr)*DP;
  float4 qa = ((const float4*)qr)[2*g];
  float4 qb = ((const float4*)qr)[2*g+1];
  float4 qt = ((const float4*)qr)[8];      // dims 32..35 (35 is 0)

  // ---- K staging: row r = t>>2, quarter qd = t&3 handles dims [16qd,16qd+16)
  {
    int r = t >> 2;
    int qd = t & 3;
    unsigned ik = (unsigned)(pk[r] & 0xffffffffull);
    const float* kr = k_hat + ((size_t)h*NPTS + ik)*DP;
    float fk[3] = {0.f, 0.f, 0.f};
    float vals[16];
    float psqk = 0.f;
    if (qd < 2){
      #pragma unroll
      for (int u = 0; u < 4; ++u)
        *(float4*)&vals[u*4] = ((const float4*)(kr + 16*qd))[u];
      #pragma unroll
      for (int d2 = 0; d2 < 16; ++d2) psqk += vals[d2]*vals[d2];
    } else if (qd == 2){
      float4 k4 = *(const float4*)(kr + 32);   // dims 32..35 (35 == 0)
      fk[0] = k4.x; fk[1] = k4.y; fk[2] = k4.z;
      psqk = k4.x*k4.x + k4.y*k4.y + k4.z*k4.z;
    }
    psqk += __shfl_xor(psqk, 1);
    psqk += __shfl_xor(psqk, 2);
    float ksq = -0.5f * psqk;
    if (qd == 2){
      vals[0]=fk[0]; vals[1]=fk[1]; vals[2]=fk[2];
      vals[3]=ksq; vals[4]=1.0f;
      #pragma unroll
      for (int d2 = 5; d2 < 16; ++d2) vals[d2] = 0.f;
    } else if (qd == 3){
      #pragma unroll
      for (int d2 = 0; d2 < 16; ++d2) vals[d2] = 0.f;
    }
    int rowbase = r*64;
    int sw = (r & 7) << 3;
    #pragma unroll
    for (int c0 = 0; c0 < 16; c0 += 4){
      int c = 16*qd + c0;
      unsigned short h0=f2bf(vals[c0]),   h1=f2bf(vals[c0+1]);
      unsigned short h2=f2bf(vals[c0+2]), h3=f2bf(vals[c0+3]);
      unsigned short l0=f2bf(vals[c0]  -bf2f(h0)), l1=f2bf(vals[c0+1]-bf2f(h1));
      unsigned short l2=f2bf(vals[c0+2]-bf2f(h2)), l3=f2bf(vals[c0+3]-bf2f(h3));
      int o = rowbase + (c ^ sw);
      uint2 hv, lv;
      hv.x = (unsigned)h0 | ((unsigned)h1 << 16);
      hv.y = (unsigned)h2 | ((unsigned)h3 << 16);
      lv.x = (unsigned)l0 | ((unsigned)l1 << 16);
      lv.y = (unsigned)l2 | ((unsigned)l3 << 16);
      *(uint2*)&KP[o] = hv;
      *(uint2*)&KP[8192 + o] = lv;
    }
    // ---- V staging: same row r, dims [8qd, 8qd+8)
    const float* vr = val + ((size_t)h*NPTS + ik)*DIM + 8*qd;
    float fv[8];
    *(float4*)&fv[0] = ((const float4*)vr)[0];
    *(float4*)&fv[4] = ((const float4*)vr)[1];
    #pragma unroll
    for (int d2 = 0; d2 < 8; ++d2){
      int vd = 8*qd + d2;
      Vt[vd*128 + (r ^ ((vd&7)<<3))] = (short)f2bf(fv[d2]);
    }
  }

  // build Q fragments in registers
  float f0[8] = {qa.x,qa.y,qa.z,qa.w, qb.x,qb.y,qb.z,qb.w};
  float psq = 0.f;
  #pragma unroll
  for (int j = 0; j < 8; ++j) psq += f0[j]*f0[j];
  if (g == 0) psq += qt.x*qt.x + qt.y*qt.y + qt.z*qt.z;
  psq += __shfl_xor(psq, 16);
  psq += __shfl_xor(psq, 32);
  float qsq = -0.5f * psq;
  bf16x8 qh0, ql0, qh1, ql1;
  cvt8(f0, qh0, ql0);
  float f1[8] = {0.f,0.f,0.f,0.f,0.f,0.f,0.f,0.f};
  if (g == 0){
    f1[0] = qt.x; f1[1] = qt.y; f1[2] = qt.z;
    f1[3] = 1.0f;      // pairs with ksq at dim35
    f1[4] = qsq;       // pairs with 1.0 at dim36
  }
  cvt8(f1, qh1, ql1);

  __syncthreads();

  // QK^T: S^T = K.Q^T
  f32x4 acc[8];
  #pragma unroll
  for (int kt = 0; kt < 8; ++kt) acc[kt] = (f32x4){0.f,0.f,0.f,0.f};
  #pragma unroll
  for (int kt = 0; kt < 8; ++kt){
    int krow = 16*kt + l15;
    int base = krow*64;
    int sw = (krow & 7) << 3;
    bf16x8 ah0 = *(const bf16x8*)&KP[base + ((8*g) ^ sw)];
    bf16x8 ah1 = *(const bf16x8*)&KP[base + ((32 + 8*g) ^ sw)];
    bf16x8 al0 = *(const bf16x8*)&KP[8192 + base + ((8*g) ^ sw)];
    bf16x8 al1 = *(const bf16x8*)&KP[8192 + base + ((32 + 8*g) ^ sw)];
    f32x4 c = acc[kt];
    c = __builtin_amdgcn_mfma_f32_16x16x32_bf16(ah0, qh0, c, 0, 0, 0);
    c = __builtin_amdgcn_mfma_f32_16x16x32_bf16(ah1, qh1, c, 0, 0, 0);
    c = __builtin_amdgcn_mfma_f32_16x16x32_bf16(al0, qh0, c, 0, 0, 0);
    c = __builtin_amdgcn_mfma_f32_16x16x32_bf16(al1, qh1, c, 0, 0, 0);
    c = __builtin_amdgcn_mfma_f32_16x16x32_bf16(ah0, ql0, c, 0, 0, 0);
    c = __builtin_amdgcn_mfma_f32_16x16x32_bf16(ah1, ql1, c, 0, 0, 0);
    acc[kt] = c;
  }

  __syncthreads();   // all QK done -> K region dead, P may overwrite

  // exp + P(bf16) into KP as [q=128][key=128], swizzled; fp32 denom per lane
  int qsw = (qrow & 7) << 3;
  float dena = 0.f;
  #pragma unroll
  for (int kt = 0; kt < 8; ++kt){
    f32x4 c = acc[kt];
    float p0 = __expf(fminf(c[0], 0.f));
    float p1 = __expf(fminf(c[1], 0.f));
    float p2 = __expf(fminf(c[2], 0.f));
    float p3 = __expf(fminf(c[3], 0.f));
    dena += p0 + p1 + p2 + p3;
    int key = 16*kt + 4*g;
    uint2 pv;
    pv.x = (unsigned)f2bf(p0) | ((unsigned)f2bf(p1) << 16);
    pv.y = (unsigned)f2bf(p2) | ((unsigned)f2bf(p3) << 16);
    *(uint2*)&KP[qrow*128 + (key ^ qsw)] = pv;
  }
  // P write->read is within-wave (each wave only touches its own 16 q-rows): no barrier

  // PV via MFMA: A = P (m=q), B = V^T (n=vdim)
  f32x4 oacc[2];
  oacc[0] = (f32x4){0.f,0.f,0.f,0.f};
  oacc[1] = (f32x4){0.f,0.f,0.f,0.f};
  #pragma unroll
  for (int ks = 0; ks < 4; ++ks){
    bf16x8 pA = *(const bf16x8*)&KP[qrow*128 + ((32*ks + 8*g) ^ qsw)];
    #pragma unroll
    for (int nt = 0; nt < 2; ++nt){
      int vd = 16*nt + l15;
      bf16x8 vB = *(const bf16x8*)&Vt[vd*128 + ((32*ks + 8*g) ^ ((vd&7)<<3))];
      oacc[nt] = __builtin_amdgcn_mfma_f32_16x16x32_bf16(pA, vB, oacc[nt], 0, 0, 0);
    }
  }

  // denom scatter
  {
    float d = dena;
    d += __shfl_xor(d, 16);
    d += __shfl_xor(d, 32);
    if (lane < 16) atomicAdd(&logit_acc[(size_t)h*NPTS + iqr], d + 1e-20f);
  }
  // O scatter (iq via intra-wave shuffle of the per-lane iqr)
  #pragma unroll
  for (int nt = 0; nt < 2; ++nt){
    f32x4 c = oacc[nt];
    #pragma unroll
    for (int r = 0; r < 4; ++r){
      unsigned iq = (unsigned)__shfl((int)iqr, 4*g + r);
      atomicAdd(&o_acc[((size_t)h*NPTS + iq)*DIM + 16*nt + l15], c[r]);
    }
  }
}

// ---------------- out-proj + residual + LN2 + FF + residual
__global__ __launch_bounds__(256) void k_final(const float* __restrict__ x,
        const float* __restrict__ o_acc, const float* __restrict__ logit_acc,
        const float* __restrict__ out_w, const float* __restrict__ out_b,
        const float* __restrict__ n2w, const float* __restrict__ n2b,
        const float* __restrict__ f1w, const float* __restrict__ f1b,
        const float* __restrict__ f2w, const float* __restrict__ f2b,
        float* __restrict__ out){
  __shared__ float OW[256][32];   // 32 KB
  __shared__ float F1[32][32];
  __shared__ float F2[32][32];
  int tid = threadIdx.x;
  for (int idx = tid; idx < 256*32; idx += 256) OW[idx/32][idx%32] = out_w[idx];
  for (int idx = tid; idx < 1024; idx += 256){
    F1[idx/32][idx%32] = f1w[idx];
    F2[idx/32][idx%32] = f2w[idx];
  }
  __syncthreads();
  int n = blockIdx.x*256 + tid;
  float attn[32];
  #pragma unroll
  for (int j = 0; j < 32; ++j) attn[j] = out_b[j];
  for (int h = 0; h < 8; ++h){
    float inv = 1.f / logit_acc[(size_t)h*NPTS + n];
    const float4* orow = (const float4*)(o_acc + ((size_t)h*NPTS + n)*DIM);
    #pragma unroll
    for (int u = 0; u < 8; ++u){
      float4 ov = orow[u];
      float vals[4] = {ov.x*inv, ov.y*inv, ov.z*inv, ov.w*inv};
      #pragma unroll
      for (int s = 0; s < 4; ++s){
        const float* wrow = &OW[h*32 + u*4 + s][0];
        #pragma unroll
        for (int j = 0; j < 32; ++j) attn[j] += vals[s] * wrow[j];
      }
    }
  }
  const float* xp = x + (size_t)n*DIM;
  float xr[32]; float s = 0.f;
  #pragma unroll
  for (int d = 0; d < 32; ++d){ xr[d] = xp[d] + attn[d]; s += xr[d]; }
  float mu = s * (1.f/32.f);
  float var = 0.f;
  #pragma unroll
  for (int d = 0; d < 32; ++d){ float dx = xr[d]-mu; var += dx*dx; }
  var *= (1.f/32.f);
  float rs = rsqrtf(var + 1e-5f);
  float xn2[32];
  #pragma unroll
  for (int d = 0; d < 32; ++d) xn2[d] = (xr[d]-mu)*rs*n2w[d] + n2b[d];
  float z[32];
  #pragma unroll
  for (int j = 0; j < 32; ++j) z[j] = f1b[j];
  #pragma unroll
  for (int d = 0; d < 32; ++d){
    float xd = xn2[d];
    const float* wrow = &F1[d][0];
    #pragma unroll
    for (int j = 0; j < 32; ++j) z[j] += xd * wrow[j];
  }
  #pragma unroll
  for (int j = 0; j < 32; ++j) z[j] = z[j] / (1.f + __expf(-z[j]));
  float y[32];
  #pragma unroll
  for (int d = 0; d < 32; ++d) y[d] = f2b[d];
  #pragma unroll
  for (int j = 0; j < 32; ++j){
    float zj = z[j];
    const float* wrow = &F2[j][0];
    #pragma unroll
    for (int d = 0; d < 32; ++d) y[d] += zj * wrow[d];
  }
  float* op = out + (size_t)n*DIM;
  #pragma unroll
  for (int d = 0; d < 32; ++d) op[d] = xr[d] + y[d];
}

extern "C" void kernel_launch(void* const* d_in, const int* in_sizes, int n_in,
                              void* d_out, int out_size, void* d_ws, size_t ws_size,
                              hipStream_t stream){
  const float* x      = (const float*)d_in[0];
  const float* coords = (const float*)d_in[1];
  const int*   shifts = (const int*)d_in[2];
  const float* n1w    = (const float*)d_in[3];
  const float* n1b    = (const float*)d_in[4];
  const float* wq     = (const float*)d_in[5];
  const float* wk     = (const float*)d_in[6];
  const float* wv     = (const float*)d_in[7];
  const float* w_rpe  = (const float*)d_in[8];
  const float* alpha  = (const float*)d_in[9];
  const float* out_w  = (const float*)d_in[10];
  const float* out_b  = (const float*)d_in[11];
  const float* n2w    = (const float*)d_in[12];
  const float* n2b    = (const float*)d_in[13];
  const float* f1w    = (const float*)d_in[14];
  const float* f1b    = (const float*)d_in[15];
  const float* f2w    = (const float*)d_in[16];
  const float* f2b    = (const float*)d_in[17];
  float* out = (float*)d_out;

  char* ws = (char*)d_ws;
  size_t off = 0;
  auto alloc = [&](size_t bytes){ size_t o = off; off += (bytes + 255) & ~(size_t)255; return o; };
  float*    qw_sqrt   = (float*)   (ws + alloc(24*4));
  unsigned* slots_hi  = (unsigned*)(ws + alloc(24*4));
  unsigned* slots_lo  = (unsigned*)(ws + alloc(24*4));
  float*    q_hat     = (float*)   (ws + alloc((size_t)NH*NPTS*DP*4));
  float*    k_hat     = (float*)   (ws + alloc((size_t)NH*NPTS*DP*4));
  float*    val       = (float*)   (ws + alloc((size_t)NH*NPTS*DIM*4));
  float*    qh_buf    = (float*)   (ws + alloc((size_t)NSEG*NPTS*4));
  float*    kh_buf    = (float*)   (ws + alloc((size_t)NSEG*NPTS*4));
  ull*      packed    = (ull*)     (ws + alloc((size_t)2*NSEG*NPTS*8));
  float*    o_acc     = (float*)   (ws + alloc((size_t)NH*NPTS*DIM*4));
  float*    logit_acc = (float*)   (ws + alloc((size_t)NH*NPTS*4));
  if (off > ws_size) return;

  hipMemsetAsync(o_acc, 0, (size_t)NH*NPTS*DIM*4, stream);
  hipMemsetAsync(logit_acc, 0, (size_t)NH*NPTS*4, stream);

  k_prep<<<1, 256, 0, stream>>>(w_rpe, qw_sqrt, slots_hi, slots_lo);
  k_qkv<<<NPTS/128, 256, 0, stream>>>(x, n1w, n1b, coords, wq, wk, wv, qw_sqrt,
                                      q_hat, k_hat, val);
  k_hash<<<dim3(NPTS/256, NH), 256, 0, stream>>>(q_hat, k_hat, alpha, qh_buf, kh_buf,
                                                 slots_hi, slots_lo);
  // 48 segments of 32768 -> bitonic
  k_sort_pack_local<<<2*NSEG*4, 1024, 0, stream>>>(qh_buf, kh_buf, shifts,
                                                   slots_hi, slots_lo, packed);
  k_sort_global<<<(2*NSEG*16384)/256, 256, 0, stream>>>(packed, 16384u, 8192u);
  k_sort_local<<<2*NSEG*4, 1024, 0, stream>>>(packed, 16384u, 16384u);
  k_sort_global<<<(2*NSEG*16384)/256, 256, 0, stream>>>(packed, 32768u, 16384u);
  k_sort_global<<<(2*NSEG*16384)/256, 256, 0, stream>>>(packed, 32768u, 8192u);
  k_sort_local<<<2*NSEG*4, 1024, 0, stream>>>(packed, 32768u, 32768u);

  k_attn<<<NSEG*NB, 512, 0, stream>>>(q_hat, k_hat, val, packed, o_acc, logit_acc);
  k_final<<<NPTS/256, 256, 0, stream>>>(x, o_acc, logit_acc, out_w, out_b,
                                        n2w, n2b, f1w, f1b, f2w, f2b, out);
}

// Round 9
// 460.379 us; speedup vs baseline: 1.5683x; 1.0837x over previous
//
#include <hip/hip_runtime.h>

#define NPTS 32768
#define DIM 32
#define NH 8
#define NC 3
#define BSZ 128
#define NB 256
#define DH 35
#define DP 36
#define NSEG 24   // C*H

typedef unsigned long long ull;
typedef __attribute__((ext_vector_type(8))) short bf16x8;
typedef __attribute__((ext_vector_type(4))) float f32x4;

__device__ __forceinline__ unsigned fmap(float f){
  unsigned b = __float_as_uint(f);
  return (b & 0x80000000u) ? ~b : (b | 0x80000000u);
}
__device__ __forceinline__ float funmap(unsigned u){
  unsigned b = (u & 0x80000000u) ? (u & 0x7fffffffu) : ~u;
  return __uint_as_float(b);
}
__device__ __forceinline__ unsigned short f2bf(float f){
  unsigned u = __float_as_uint(f);
  u += 0x7fffu + ((u >> 16) & 1u);
  return (unsigned short)(u >> 16);
}
__device__ __forceinline__ float bf2f(unsigned short h){
  return __uint_as_float(((unsigned)h) << 16);
}
__device__ __forceinline__ unsigned cvtpk_bf16(float a, float b){
  unsigned r;
  asm("v_cvt_pk_bf16_f32 %0, %1, %2" : "=v"(r) : "v"(a), "v"(b));
  return r;
}

__device__ __forceinline__ void cswap(ull& a, ull& b, bool up){
  if ((a > b) == up){ ull t = a; a = b; b = t; }
}
// bitonic stages k=2,4,8 on 8 contiguous elements starting at gbase (gbase%8==0)
__device__ __forceinline__ void bitonic8_initial(ull r[8], unsigned gbase){
  #pragma unroll
  for (int p = 0; p < 4; ++p){
    bool up = (((gbase + 2*p) & 2) == 0);
    cswap(r[2*p], r[2*p+1], up);
  }
  #pragma unroll
  for (int b = 0; b < 2; ++b){
    bool up = (((gbase + 4*b) & 4) == 0);
    cswap(r[4*b+0], r[4*b+2], up);
    cswap(r[4*b+1], r[4*b+3], up);
    cswap(r[4*b+0], r[4*b+1], up);
    cswap(r[4*b+2], r[4*b+3], up);
  }
  bool up = ((gbase & 8) == 0);
  #pragma unroll
  for (int i = 0; i < 4; ++i) cswap(r[i], r[i+4], up);
  #pragma unroll
  for (int b = 0; b < 2; ++b){
    cswap(r[4*b+0], r[4*b+2], up);
    cswap(r[4*b+1], r[4*b+3], up);
  }
  #pragma unroll
  for (int p = 0; p < 4; ++p) cswap(r[2*p], r[2*p+1], up);
}
// j=4,2,1 finish of a stage k>=16; direction uniform across the 8
__device__ __forceinline__ void bitonic8_finish(ull r[8], bool up){
  #pragma unroll
  for (int i = 0; i < 4; ++i) cswap(r[i], r[i+4], up);
  #pragma unroll
  for (int b = 0; b < 2; ++b){
    cswap(r[4*b+0], r[4*b+2], up);
    cswap(r[4*b+1], r[4*b+3], up);
  }
  #pragma unroll
  for (int p = 0; p < 4; ++p) cswap(r[2*p], r[2*p+1], up);
}

// ---------------- prep
__global__ __launch_bounds__(256) void k_prep(const float* __restrict__ w_rpe,
        float* __restrict__ qw_sqrt, unsigned* __restrict__ slots_hi,
        unsigned* __restrict__ slots_lo){
  int tid = threadIdx.x;
  if (tid < NSEG){ slots_hi[tid] = 0u; slots_lo[tid] = 0xFFFFFFFFu; }
  __shared__ float S[24][8];
  if (tid < 192){
    int hr = tid >> 3, kk = tid & 7;
    int h = hr / 3, r = hr % 3;
    float s = 0.f;
    #pragma unroll
    for (int d = 0; d < DIM; ++d) s += w_rpe[(h*DIM + d)*24 + (r*8 + kk)];
    S[hr][kk] = expf(fminf(s, 50.f));
  }
  __syncthreads();
  if (tid < 24){
    float q = 0.f;
    #pragma unroll
    for (int kk = 0; kk < 8; ++kk) q += S[tid][kk];
    qw_sqrt[tid] = sqrtf(2.f * q);
  }
}

// ---------------- LN1 + QKV projection + hash + bf16 hi/lo pre-pack, all fused
// Packed row layout (96 shorts): [0..47] hi bf16 of dims 0..47, [48..95] lo.
// Dims: 0..31 = projected q/k; 32..34 = sqrt_w_r*coords; Q: 35=1.0, 36=qsq;
// K: 35=ksq, 36=1.0; 37..47 = 0.
__global__ __launch_bounds__(256, 1) void k_qkv(const float* __restrict__ x,
        const float* __restrict__ n1w, const float* __restrict__ n1b,
        const float* __restrict__ coords, const float* __restrict__ wq,
        const float* __restrict__ wk, const float* __restrict__ wv,
        const float* __restrict__ qw_sqrt, const float* __restrict__ alpha,
        short* __restrict__ qpk, short* __restrict__ kpk, short* __restrict__ vbf,
        float* __restrict__ qh_buf, float* __restrict__ kh_buf,
        unsigned* __restrict__ slots_hi, unsigned* __restrict__ slots_lo){
  __shared__ float W[3][DIM][NH*DIM];   // 96 KB
  __shared__ float XT[128][33];         // 16.9 KB
  __shared__ float AL[NH][DH][NC];      // 3.4 KB
  int tid = threadIdx.x;
  for (int idx = tid; idx < 3*DIM*NH*DIM; idx += 256){
    int which = idx / (DIM*NH*DIM);
    int rem = idx % (DIM*NH*DIM);
    const float* src = which==0 ? wq : (which==1 ? wk : wv);
    W[which][rem/(NH*DIM)][rem%(NH*DIM)] = src[rem];
  }
  for (int idx = tid; idx < NH*DH*NC; idx += 256)
    ((float*)AL)[idx] = alpha[idx];
  int base = blockIdx.x * 128;
  if (tid < 128){
    const float4* xr4 = (const float4*)(x + (size_t)(base + tid)*DIM);
    float4 v[8];
    float s = 0.f;
    #pragma unroll
    for (int u = 0; u < 8; ++u){ v[u] = xr4[u]; s += v[u].x+v[u].y+v[u].z+v[u].w; }
    float mu = s * (1.f/32.f);
    float var = 0.f;
    #pragma unroll
    for (int u = 0; u < 8; ++u){
      float a0=v[u].x-mu, a1=v[u].y-mu, a2=v[u].z-mu, a3=v[u].w-mu;
      var += a0*a0+a1*a1+a2*a2+a3*a3;
    }
    var *= (1.f/32.f);
    float rs = rsqrtf(var + 1e-5f);
    #pragma unroll
    for (int u = 0; u < 8; ++u){
      XT[tid][u*4+0] = (v[u].x-mu)*rs*n1w[u*4+0] + n1b[u*4+0];
      XT[tid][u*4+1] = (v[u].y-mu)*rs*n1w[u*4+1] + n1b[u*4+1];
      XT[tid][u*4+2] = (v[u].z-mu)*rs*n1w[u*4+2] + n1b[u*4+2];
      XT[tid][u*4+3] = (v[u].w-mu)*rs*n1w[u*4+3] + n1b[u*4+3];
    }
  }
  __syncthreads();
  int h = tid >> 5, i = tid & 31;
  float xr0[32], xr1[32], xr2[32], xr3[32];
  #pragma unroll
  for (int d = 0; d < 32; ++d){
    xr0[d] = XT[i][d]; xr1[d] = XT[i+32][d];
    xr2[d] = XT[i+64][d]; xr3[d] = XT[i+96][d];
  }
  size_t nb = (size_t)h*NPTS + base + i;
  short* qr0 = qpk + nb*96;      short* qr1 = qpk + (nb+32)*96;
  short* qr2 = qpk + (nb+64)*96; short* qr3 = qpk + (nb+96)*96;
  short* kr0 = kpk + nb*96;      short* kr1 = kpk + (nb+32)*96;
  short* kr2 = kpk + (nb+64)*96; short* kr3 = kpk + (nb+96)*96;
  short* vr0 = vbf + nb*32;      short* vr1 = vbf + (nb+32)*32;
  short* vr2 = vbf + (nb+64)*32; short* vr3 = vbf + (nb+96)*32;

  auto packrow = [&](short* row, int j0, float4 a){
    unsigned short hx=f2bf(a.x), hy=f2bf(a.y), hz=f2bf(a.z), hw=f2bf(a.w);
    uint2 hv, lv;
    hv.x = (unsigned)hx | ((unsigned)hy << 16);
    hv.y = (unsigned)hz | ((unsigned)hw << 16);
    lv.x = (unsigned)f2bf(a.x - bf2f(hx)) | ((unsigned)f2bf(a.y - bf2f(hy)) << 16);
    lv.y = (unsigned)f2bf(a.z - bf2f(hz)) | ((unsigned)f2bf(a.w - bf2f(hw)) << 16);
    *(uint2*)&row[j0] = hv;
    *(uint2*)&row[48 + j0] = lv;
  };
  auto packv = [&](short* row, int j0, float4 a){
    uint2 hv;
    hv.x = (unsigned)f2bf(a.x) | ((unsigned)f2bf(a.y) << 16);
    hv.y = (unsigned)f2bf(a.z) | ((unsigned)f2bf(a.w) << 16);
    *(uint2*)&row[j0] = hv;
  };
  auto hacc = [&](float4 a, int j0, float& sq, float (&hp)[3]){
    sq += a.x*a.x; sq += a.y*a.y; sq += a.z*a.z; sq += a.w*a.w;
    #pragma unroll
    for (int c = 0; c < 3; ++c){
      float t = hp[c];
      t += a.x*AL[h][j0][c];   t += a.y*AL[h][j0+1][c];
      t += a.z*AL[h][j0+2][c]; t += a.w*AL[h][j0+3][c];
      hp[c] = t;
    }
  };

  float qh_p0[3]={0,0,0}, qh_p1[3]={0,0,0}, qh_p2[3]={0,0,0}, qh_p3[3]={0,0,0};
  float kh_p0[3]={0,0,0}, kh_p1[3]={0,0,0}, kh_p2[3]={0,0,0}, kh_p3[3]={0,0,0};
  float qsq0=0.f,qsq1=0.f,qsq2=0.f,qsq3=0.f;
  float ksq0=0.f,ksq1=0.f,ksq2=0.f,ksq3=0.f;

  // Q projection
  for (int j0 = 0; j0 < 32; j0 += 4){
    float4 a0={0,0,0,0},a1={0,0,0,0},a2={0,0,0,0},a3={0,0,0,0};
    #pragma unroll
    for (int d = 0; d < 32; ++d){
      float4 w4 = *(const float4*)&W[0][d][h*32 + j0];
      a0.x += xr0[d]*w4.x; a0.y += xr0[d]*w4.y; a0.z += xr0[d]*w4.z; a0.w += xr0[d]*w4.w;
      a1.x += xr1[d]*w4.x; a1.y += xr1[d]*w4.y; a1.z += xr1[d]*w4.z; a1.w += xr1[d]*w4.w;
      a2.x += xr2[d]*w4.x; a2.y += xr2[d]*w4.y; a2.z += xr2[d]*w4.z; a2.w += xr2[d]*w4.w;
      a3.x += xr3[d]*w4.x; a3.y += xr3[d]*w4.y; a3.z += xr3[d]*w4.z; a3.w += xr3[d]*w4.w;
    }
    hacc(a0, j0, qsq0, qh_p0); packrow(qr0, j0, a0);
    hacc(a1, j0, qsq1, qh_p1); packrow(qr1, j0, a1);
    hacc(a2, j0, qsq2, qh_p2); packrow(qr2, j0, a2);
    hacc(a3, j0, qsq3, qh_p3); packrow(qr3, j0, a3);
  }
  // K projection
  for (int j0 = 0; j0 < 32; j0 += 4){
    float4 a0={0,0,0,0},a1={0,0,0,0},a2={0,0,0,0},a3={0,0,0,0};
    #pragma unroll
    for (int d = 0; d < 32; ++d){
      float4 w4 = *(const float4*)&W[1][d][h*32 + j0];
      a0.x += xr0[d]*w4.x; a0.y += xr0[d]*w4.y; a0.z += xr0[d]*w4.z; a0.w += xr0[d]*w4.w;
      a1.x += xr1[d]*w4.x; a1.y += xr1[d]*w4.y; a1.z += xr1[d]*w4.z; a1.w += xr1[d]*w4.w;
      a2.x += xr2[d]*w4.x; a2.y += xr2[d]*w4.y; a2.z += xr2[d]*w4.z; a2.w += xr2[d]*w4.w;
      a3.x += xr3[d]*w4.x; a3.y += xr3[d]*w4.y; a3.z += xr3[d]*w4.z; a3.w += xr3[d]*w4.w;
    }
    hacc(a0, j0, ksq0, kh_p0); packrow(kr0, j0, a0);
    hacc(a1, j0, ksq1, kh_p1); packrow(kr1, j0, a1);
    hacc(a2, j0, ksq2, kh_p2); packrow(kr2, j0, a2);
    hacc(a3, j0, ksq3, kh_p3); packrow(kr3, j0, a3);
  }
  // V projection
  for (int j0 = 0; j0 < 32; j0 += 4){
    float4 a0={0,0,0,0},a1={0,0,0,0},a2={0,0,0,0},a3={0,0,0,0};
    #pragma unroll
    for (int d = 0; d < 32; ++d){
      float4 w4 = *(const float4*)&W[2][d][h*32 + j0];
      a0.x += xr0[d]*w4.x; a0.y += xr0[d]*w4.y; a0.z += xr0[d]*w4.z; a0.w += xr0[d]*w4.w;
      a1.x += xr1[d]*w4.x; a1.y += xr1[d]*w4.y; a1.z += xr1[d]*w4.z; a1.w += xr1[d]*w4.w;
      a2.x += xr2[d]*w4.x; a2.y += xr2[d]*w4.y; a2.z += xr2[d]*w4.z; a2.w += xr2[d]*w4.w;
      a3.x += xr3[d]*w4.x; a3.y += xr3[d]*w4.y; a3.z += xr3[d]*w4.z; a3.w += xr3[d]*w4.w;
    }
    packv(vr0, j0, a0); packv(vr1, j0, a1);
    packv(vr2, j0, a2); packv(vr3, j0, a3);
  }

  auto writetail = [&](short* row, float c0, float c1, float c2, float x5, float x6){
    unsigned short h0=f2bf(c0), h1=f2bf(c1), h2=f2bf(c2), h5=f2bf(x5), h6=f2bf(x6);
    uint4 hv, lv, zz;
    zz.x = 0; zz.y = 0; zz.z = 0; zz.w = 0;
    hv.x = (unsigned)h0 | ((unsigned)h1 << 16);
    hv.y = (unsigned)h2 | ((unsigned)h5 << 16);
    hv.z = (unsigned)h6; hv.w = 0;
    lv.x = (unsigned)f2bf(c0 - bf2f(h0)) | ((unsigned)f2bf(c1 - bf2f(h1)) << 16);
    lv.y = (unsigned)f2bf(c2 - bf2f(h2)) | ((unsigned)f2bf(x5 - bf2f(h5)) << 16);
    lv.z = (unsigned)f2bf(x6 - bf2f(h6)); lv.w = 0;
    *(uint4*)&row[32] = hv;
    *(uint4*)&row[40] = zz;
    *(uint4*)&row[80] = lv;
    *(uint4*)&row[88] = zz;
  };

  float mx[3] = {-3.4e38f, -3.4e38f, -3.4e38f};
  float mn[3] = { 3.4e38f,  3.4e38f,  3.4e38f};
  auto fin = [&](int n, short* qrow, short* krow, float qsqp, float ksqp,
                 const float (&qhp)[3], const float (&khp)[3]){
    float c0 = qw_sqrt[h*3+0] * coords[(size_t)n*3+0];
    float c1 = qw_sqrt[h*3+1] * coords[(size_t)n*3+1];
    float c2 = qw_sqrt[h*3+2] * coords[(size_t)n*3+2];
    float csq = c0*c0 + c1*c1 + c2*c2;
    float qsq = -0.5f*(qsqp + csq);
    float ksq = -0.5f*(ksqp + csq);
    writetail(qrow, c0, c1, c2, 1.0f, qsq);
    writetail(krow, c0, c1, c2, ksq, 1.0f);
    #pragma unroll
    for (int c = 0; c < 3; ++c){
      float qh = qhp[c];
      qh += c0*AL[h][32][c]; qh += c1*AL[h][33][c]; qh += c2*AL[h][34][c];
      float kh = khp[c];
      kh += c0*AL[h][32][c]; kh += c1*AL[h][33][c]; kh += c2*AL[h][34][c];
      qh_buf[(size_t)(c*NH + h)*NPTS + n] = qh;
      kh_buf[(size_t)(c*NH + h)*NPTS + n] = kh;
      mx[c] = fmaxf(mx[c], fmaxf(qh, kh));
      mn[c] = fminf(mn[c], fminf(qh, kh));
    }
  };
  fin(base + i,      qr0, kr0, qsq0, ksq0, qh_p0, kh_p0);
  fin(base + i + 32, qr1, kr1, qsq1, ksq1, qh_p1, kh_p1);
  fin(base + i + 64, qr2, kr2, qsq2, ksq2, qh_p2, kh_p2);
  fin(base + i + 96, qr3, kr3, qsq3, ksq3, qh_p3, kh_p3);

  #pragma unroll
  for (int c = 0; c < 3; ++c){
    float mx_ = mx[c], mn_ = mn[c];
    #pragma unroll
    for (int off = 1; off <= 16; off <<= 1){
      mx_ = fmaxf(mx_, __shfl_xor(mx_, off));
      mn_ = fminf(mn_, __shfl_xor(mn_, off));
    }
    if ((tid & 31) == 0){
      atomicMax(&slots_hi[c*NH + h], fmap(mx_));
      atomicMin(&slots_lo[c*NH + h], fmap(mn_));
    }
  }
}

// ---------------- pack + bitonic k=2..8192 within 8192-chunk
__global__ __launch_bounds__(1024) void k_sort_pack_local(
        const float* __restrict__ qh_buf, const float* __restrict__ kh_buf,
        const int* __restrict__ shifts,
        const unsigned* __restrict__ slots_hi, const unsigned* __restrict__ slots_lo,
        ull* __restrict__ packed){
  __shared__ ull ld[9216];
  int chunk = blockIdx.x;            // 0..191
  int lst = chunk >> 2;              // 0..47 (0..23 q, 24..47 k)
  int seg = lst < NSEG ? lst : lst - NSEG;
  const float* buf = lst < NSEG ? qh_buf : kh_buf;
  unsigned coff = (unsigned)(chunk & 3) * 8192u;
  float hs = funmap(slots_hi[seg]) - funmap(slots_lo[seg]);
  unsigned tid = threadIdx.x;

  {
    ull r[8];
    unsigned gb = coff + 8u*tid;
    #pragma unroll
    for (int e = 0; e < 8; ++e){
      unsigned n = gb + e;
      size_t gi = (size_t)seg*NPTS + n;
      float key = buf[gi] + (float)shifts[gi] * hs;
      r[e] = ((ull)fmap(key) << 32) | n;
    }
    bitonic8_initial(r, gb);
    #pragma unroll
    for (int e = 0; e < 8; ++e) ld[9u*tid + e] = r[e];
  }
  __syncthreads();

  for (unsigned k = 16; k <= 8192u; k <<= 1){
    for (unsigned j = k >> 1; j >= 8; j >>= 1){
      #pragma unroll
      for (int it = 0; it < 4; ++it){
        unsigned p = tid + 1024u*it;
        unsigned i  = ((p & ~(j-1)) << 1) | (p & (j-1));
        unsigned x2 = i | j;
        bool up = (((coff + i) & k) == 0);
        unsigned pi = i + (i>>3), px = x2 + (x2>>3);
        ull a = ld[pi], b2 = ld[px];
        if ((a > b2) == up){ ld[pi] = b2; ld[px] = a; }
      }
      __syncthreads();
    }
    {
      ull r[8];
      #pragma unroll
      for (int e = 0; e < 8; ++e) r[e] = ld[9u*tid + e];
      bool up = (((coff + 8u*tid) & k) == 0);
      bitonic8_finish(r, up);
      #pragma unroll
      for (int e = 0; e < 8; ++e) ld[9u*tid + e] = r[e];
    }
    __syncthreads();
  }
  size_t base = (size_t)lst*NPTS + coff;
  for (unsigned idx = tid; idx < 8192; idx += 1024)
    packed[base + idx] = ld[idx + (idx>>3)];
}

// ---------------- bitonic: LDS chunk stages
__global__ __launch_bounds__(1024) void k_sort_local(ull* __restrict__ data,
        unsigned k_lo, unsigned k_hi){
  __shared__ ull ld[9216];
  int chunk = blockIdx.x;
  size_t base = (size_t)chunk * 8192;
  unsigned coff = (unsigned)(chunk & 3) * 8192u;
  unsigned tid = threadIdx.x;
  for (unsigned idx = tid; idx < 8192; idx += 1024)
    ld[idx + (idx>>3)] = data[base + idx];
  __syncthreads();
  for (unsigned k = k_lo; k <= k_hi; k <<= 1){
    unsigned j0 = (k >> 1) < 4096u ? (k >> 1) : 4096u;
    for (unsigned j = j0; j >= 8; j >>= 1){
      #pragma unroll
      for (int it = 0; it < 4; ++it){
        unsigned p = tid + 1024u*it;
        unsigned i  = ((p & ~(j-1)) << 1) | (p & (j-1));
        unsigned x2 = i | j;
        bool up = (((coff + i) & k) == 0);
        unsigned pi = i + (i>>3), px = x2 + (x2>>3);
        ull a = ld[pi], b2 = ld[px];
        if ((a > b2) == up){ ld[pi] = b2; ld[px] = a; }
      }
      __syncthreads();
    }
    {
      ull r[8];
      #pragma unroll
      for (int e = 0; e < 8; ++e) r[e] = ld[9u*tid + e];
      bool up = (((coff + 8u*tid) & k) == 0);
      bitonic8_finish(r, up);
      #pragma unroll
      for (int e = 0; e < 8; ++e) ld[9u*tid + e] = r[e];
    }
    __syncthreads();
  }
  for (unsigned idx = tid; idx < 8192; idx += 1024)
    data[base + idx] = ld[idx + (idx>>3)];
}

// ---------------- bitonic sort: one global compare-exchange pass
__global__ __launch_bounds__(256) void k_sort_global(ull* __restrict__ data,
        unsigned k, unsigned j){
  unsigned t = blockIdx.x*256 + threadIdx.x;
  unsigned seg = t >> 14;
  unsigned p = t & 16383u;
  unsigned i  = ((p & ~(j-1)) << 1) | (p & (j-1));
  unsigned x2 = i | j;
  size_t base = (size_t)seg << 15;
  bool up = ((i & k) == 0);
  ull a = data[base + i], b = data[base + x2];
  if ((a > b) == up){ data[base + i] = b; data[base + x2] = a; }
}

// ---------------- fused k=32768 global passes j=16384 and j=8192 (4 elems/thread)
__global__ __launch_bounds__(256) void k_sort_global2(ull* __restrict__ data){
  unsigned t = blockIdx.x*256 + threadIdx.x;   // 48*8192 threads
  unsigned seg = t >> 13;
  unsigned i = t & 8191u;
  size_t base = ((size_t)seg << 15) + i;
  ull e0 = data[base], e1 = data[base + 8192], e2 = data[base + 16384], e3 = data[base + 24576];
  cswap(e0, e2, true); cswap(e1, e3, true);   // j = 16384
  cswap(e0, e1, true); cswap(e2, e3, true);   // j = 8192
  data[base] = e0; data[base + 8192] = e1;
  data[base + 16384] = e2; data[base + 24576] = e3;
}

// ---------------- bucketed kernelized attention (pure copy staging + MFMA)
__global__ __launch_bounds__(512, 8) void k_attn(const short* __restrict__ qpk,
        const short* __restrict__ kpk, const short* __restrict__ vbf,
        const ull* __restrict__ packed, float* __restrict__ o_acc,
        float* __restrict__ logit_acc){
  __shared__ short KP[16384];   // 32 KB: K hi rows [128][64] @0, lo @8192; P after barrier
  __shared__ short Vt[4096];    // 8 KB [vdim][key] swizzled

  int t = threadIdx.x;
  int blk = blockIdx.x;
  int seg = blk >> 8;
  int b = blk & 255;
  int h = seg & 7;
  const ull* pq = packed + ((size_t)seg << 15) + (size_t)b*BSZ;
  const ull* pk = packed + ((size_t)(NSEG + seg) << 15) + (size_t)b*BSZ;

  int lane = t & 63;
  int w = t >> 6;
  int l15 = lane & 15, g = lane >> 4;
  int qrow = 16*w + l15;

  // per-lane Q fragments straight from pre-packed global rows
  unsigned iqr = (unsigned)(pq[qrow] & 0xffffffffull);
  const short* qrp = qpk + ((size_t)h*NPTS + iqr)*96;
  bf16x8 qh0 = *(const bf16x8*)&qrp[8*g];
  bf16x8 ql0 = *(const bf16x8*)&qrp[48 + 8*g];
  bf16x8 qh1 = (bf16x8){0,0,0,0,0,0,0,0};
  bf16x8 ql1 = (bf16x8){0,0,0,0,0,0,0,0};
  if (g < 2){
    qh1 = *(const bf16x8*)&qrp[32 + 8*g];
    ql1 = *(const bf16x8*)&qrp[80 + 8*g];
  }

  // staging: row r = t>>2, quarter qd = t&3 — pure 16B copies
  {
    int r = t >> 2;
    int qd = t & 3;
    unsigned ik = (unsigned)(pk[r] & 0xffffffffull);
    int rowbase = r*64;
    int sw = (r & 7) << 3;
    const short* krp = kpk + ((size_t)h*NPTS + ik)*96;
    if (qd < 3){
      bf16x8 h0 = *(const bf16x8*)&krp[16*qd];
      bf16x8 h1 = *(const bf16x8*)&krp[16*qd + 8];
      bf16x8 l0 = *(const bf16x8*)&krp[48 + 16*qd];
      bf16x8 l1 = *(const bf16x8*)&krp[56 + 16*qd];
      *(bf16x8*)&KP[rowbase + ((16*qd) ^ sw)] = h0;
      *(bf16x8*)&KP[rowbase + ((16*qd + 8) ^ sw)] = h1;
      *(bf16x8*)&KP[8192 + rowbase + ((16*qd) ^ sw)] = l0;
      *(bf16x8*)&KP[8192 + rowbase + ((16*qd + 8) ^ sw)] = l1;
    } else {
      bf16x8 z = (bf16x8){0,0,0,0,0,0,0,0};
      *(bf16x8*)&KP[rowbase + (48 ^ sw)] = z;
      *(bf16x8*)&KP[rowbase + (56 ^ sw)] = z;
      *(bf16x8*)&KP[8192 + rowbase + (48 ^ sw)] = z;
      *(bf16x8*)&KP[8192 + rowbase + (56 ^ sw)] = z;
    }
    const short* vrp = vbf + ((size_t)h*NPTS + ik)*32 + 8*qd;
    bf16x8 vv = *(const bf16x8*)vrp;
    #pragma unroll
    for (int d2 = 0; d2 < 8; ++d2){
      int vd = 8*qd + d2;
      Vt[vd*128 + (r ^ ((vd & 7) << 3))] = vv[d2];
    }
  }
  __syncthreads();

  // QK^T: S^T = K.Q^T
  f32x4 acc[8];
  #pragma unroll
  for (int kt = 0; kt < 8; ++kt) acc[kt] = (f32x4){0.f,0.f,0.f,0.f};
  #pragma unroll
  for (int kt = 0; kt < 8; ++kt){
    int krow = 16*kt + l15;
    int base = krow*64;
    int sw = (krow & 7) << 3;
    bf16x8 ah0 = *(const bf16x8*)&KP[base + ((8*g) ^ sw)];
    bf16x8 ah1 = *(const bf16x8*)&KP[base + ((32 + 8*g) ^ sw)];
    bf16x8 al0 = *(const bf16x8*)&KP[8192 + base + ((8*g) ^ sw)];
    bf16x8 al1 = *(const bf16x8*)&KP[8192 + base + ((32 + 8*g) ^ sw)];
    f32x4 c = acc[kt];
    c = __builtin_amdgcn_mfma_f32_16x16x32_bf16(ah0, qh0, c, 0, 0, 0);
    c = __builtin_amdgcn_mfma_f32_16x16x32_bf16(ah1, qh1, c, 0, 0, 0);
    c = __builtin_amdgcn_mfma_f32_16x16x32_bf16(al0, qh0, c, 0, 0, 0);
    c = __builtin_amdgcn_mfma_f32_16x16x32_bf16(al1, qh1, c, 0, 0, 0);
    c = __builtin_amdgcn_mfma_f32_16x16x32_bf16(ah0, ql0, c, 0, 0, 0);
    c = __builtin_amdgcn_mfma_f32_16x16x32_bf16(ah1, ql1, c, 0, 0, 0);
    acc[kt] = c;
  }

  __syncthreads();   // K region dead -> P may overwrite

  // exp + P(bf16 via cvt_pk) into KP as [q=128][key=128]; fp32 denom per lane
  int qsw = (qrow & 7) << 3;
  float dena = 0.f;
  #pragma unroll
  for (int kt = 0; kt < 8; ++kt){
    f32x4 c = acc[kt];
    float p0 = __expf(fminf(c[0], 0.f));
    float p1 = __expf(fminf(c[1], 0.f));
    float p2 = __expf(fminf(c[2], 0.f));
    float p3 = __expf(fminf(c[3], 0.f));
    dena += p0 + p1 + p2 + p3;
    int key = 16*kt + 4*g;
    uint2 pv;
    pv.x = cvtpk_bf16(p0, p1);
    pv.y = cvtpk_bf16(p2, p3);
    *(uint2*)&KP[qrow*128 + (key ^ qsw)] = pv;
  }
  // P write->read within-wave: no barrier

  // PV via MFMA
  f32x4 oacc[2];
  oacc[0] = (f32x4){0.f,0.f,0.f,0.f};
  oacc[1] = (f32x4){0.f,0.f,0.f,0.f};
  #pragma unroll
  for (int ks = 0; ks < 4; ++ks){
    bf16x8 pA = *(const bf16x8*)&KP[qrow*128 + ((32*ks + 8*g) ^ qsw)];
    #pragma unroll
    for (int nt = 0; nt < 2; ++nt){
      int vd = 16*nt + l15;
      bf16x8 vB = *(const bf16x8*)&Vt[vd*128 + ((32*ks + 8*g) ^ ((vd&7)<<3))];
      oacc[nt] = __builtin_amdgcn_mfma_f32_16x16x32_bf16(pA, vB, oacc[nt], 0, 0, 0);
    }
  }

  // denom scatter
  {
    float d = dena;
    d += __shfl_xor(d, 16);
    d += __shfl_xor(d, 32);
    if (lane < 16) atomicAdd(&logit_acc[(size_t)h*NPTS + iqr], d + 1e-20f);
  }
  // O scatter
  #pragma unroll
  for (int nt = 0; nt < 2; ++nt){
    f32x4 c = oacc[nt];
    #pragma unroll
    for (int r = 0; r < 4; ++r){
      unsigned iq = (unsigned)__shfl((int)iqr, 4*g + r);
      atomicAdd(&o_acc[((size_t)h*NPTS + iq)*DIM + 16*nt + l15], c[r]);
    }
  }
}

// ---------------- out-proj + residual + LN2 + FF + residual
__global__ __launch_bounds__(256) void k_final(const float* __restrict__ x,
        const float* __restrict__ o_acc, const float* __restrict__ logit_acc,
        const float* __restrict__ out_w, const float* __restrict__ out_b,
        const float* __restrict__ n2w, const float* __restrict__ n2b,
        const float* __restrict__ f1w, const float* __restrict__ f1b,
        const float* __restrict__ f2w, const float* __restrict__ f2b,
        float* __restrict__ out){
  __shared__ float OW[256][32];   // 32 KB
  __shared__ float F1[32][32];
  __shared__ float F2[32][32];
  int tid = threadIdx.x;
  for (int idx = tid; idx < 256*32; idx += 256) OW[idx/32][idx%32] = out_w[idx];
  for (int idx = tid; idx < 1024; idx += 256){
    F1[idx/32][idx%32] = f1w[idx];
    F2[idx/32][idx%32] = f2w[idx];
  }
  __syncthreads();
  int n = blockIdx.x*256 + tid;
  float attn[32];
  #pragma unroll
  for (int j = 0; j < 32; ++j) attn[j] = out_b[j];
  for (int h = 0; h < 8; ++h){
    float inv = 1.f / logit_acc[(size_t)h*NPTS + n];
    const float4* orow = (const float4*)(o_acc + ((size_t)h*NPTS + n)*DIM);
    #pragma unroll
    for (int u = 0; u < 8; ++u){
      float4 ov = orow[u];
      float vals[4] = {ov.x*inv, ov.y*inv, ov.z*inv, ov.w*inv};
      #pragma unroll
      for (int s = 0; s < 4; ++s){
        const float* wrow = &OW[h*32 + u*4 + s][0];
        #pragma unroll
        for (int j = 0; j < 32; ++j) attn[j] += vals[s] * wrow[j];
      }
    }
  }
  const float* xp = x + (size_t)n*DIM;
  float xr[32]; float s = 0.f;
  #pragma unroll
  for (int d = 0; d < 32; ++d){ xr[d] = xp[d] + attn[d]; s += xr[d]; }
  float mu = s * (1.f/32.f);
  float var = 0.f;
  #pragma unroll
  for (int d = 0; d < 32; ++d){ float dx = xr[d]-mu; var += dx*dx; }
  var *= (1.f/32.f);
  float rs = rsqrtf(var + 1e-5f);
  float xn2[32];
  #pragma unroll
  for (int d = 0; d < 32; ++d) xn2[d] = (xr[d]-mu)*rs*n2w[d] + n2b[d];
  float z[32];
  #pragma unroll
  for (int j = 0; j < 32; ++j) z[j] = f1b[j];
  #pragma unroll
  for (int d = 0; d < 32; ++d){
    float xd = xn2[d];
    const float* wrow = &F1[d][0];
    #pragma unroll
    for (int j = 0; j < 32; ++j) z[j] += xd * wrow[j];
  }
  #pragma unroll
  for (int j = 0; j < 32; ++j) z[j] = z[j] / (1.f + __expf(-z[j]));
  float y[32];
  #pragma unroll
  for (int d = 0; d < 32; ++d) y[d] = f2b[d];
  #pragma unroll
  for (int j = 0; j < 32; ++j){
    float zj = z[j];
    const float* wrow = &F2[j][0];
    #pragma unroll
    for (int d = 0; d < 32; ++d) y[d] += zj * wrow[d];
  }
  float* op = out + (size_t)n*DIM;
  #pragma unroll
  for (int d = 0; d < 32; ++d) op[d] = xr[d] + y[d];
}

extern "C" void kernel_launch(void* const* d_in, const int* in_sizes, int n_in,
                              void* d_out, int out_size, void* d_ws, size_t ws_size,
                              hipStream_t stream){
  const float* x      = (const float*)d_in[0];
  const float* coords = (const float*)d_in[1];
  const int*   shifts = (const int*)d_in[2];
  const float* n1w    = (const float*)d_in[3];
  const float* n1b    = (const float*)d_in[4];
  const float* wq     = (const float*)d_in[5];
  const float* wk     = (const float*)d_in[6];
  const float* wv     = (const float*)d_in[7];
  const float* w_rpe  = (const float*)d_in[8];
  const float* alpha  = (const float*)d_in[9];
  const float* out_w  = (const float*)d_in[10];
  const float* out_b  = (const float*)d_in[11];
  const float* n2w    = (const float*)d_in[12];
  const float* n2b    = (const float*)d_in[13];
  const float* f1w    = (const float*)d_in[14];
  const float* f1b    = (const float*)d_in[15];
  const float* f2w    = (const float*)d_in[16];
  const float* f2b    = (const float*)d_in[17];
  float* out = (float*)d_out;

  char* ws = (char*)d_ws;
  size_t off = 0;
  auto alloc = [&](size_t bytes){ size_t o = off; off += (bytes + 255) & ~(size_t)255; return o; };
  float*    qw_sqrt   = (float*)   (ws + alloc(24*4));
  unsigned* slots_hi  = (unsigned*)(ws + alloc(24*4));
  unsigned* slots_lo  = (unsigned*)(ws + alloc(24*4));
  short*    qpk       = (short*)   (ws + alloc((size_t)NH*NPTS*96*2));
  short*    kpk       = (short*)   (ws + alloc((size_t)NH*NPTS*96*2));
  short*    vbf       = (short*)   (ws + alloc((size_t)NH*NPTS*32*2));
  float*    qh_buf    = (float*)   (ws + alloc((size_t)NSEG*NPTS*4));
  float*    kh_buf    = (float*)   (ws + alloc((size_t)NSEG*NPTS*4));
  ull*      packed    = (ull*)     (ws + alloc((size_t)2*NSEG*NPTS*8));
  float*    o_acc     = (float*)   (ws + alloc((size_t)NH*NPTS*DIM*4));
  float*    logit_acc = (float*)   (ws + alloc((size_t)NH*NPTS*4));
  if (off > ws_size) return;

  hipMemsetAsync(o_acc, 0, (size_t)NH*NPTS*DIM*4, stream);
  hipMemsetAsync(logit_acc, 0, (size_t)NH*NPTS*4, stream);

  k_prep<<<1, 256, 0, stream>>>(w_rpe, qw_sqrt, slots_hi, slots_lo);
  k_qkv<<<NPTS/128, 256, 0, stream>>>(x, n1w, n1b, coords, wq, wk, wv, qw_sqrt,
                                      alpha, qpk, kpk, vbf, qh_buf, kh_buf,
                                      slots_hi, slots_lo);
  // 48 segments of 32768 -> bitonic
  k_sort_pack_local<<<2*NSEG*4, 1024, 0, stream>>>(qh_buf, kh_buf, shifts,
                                                   slots_hi, slots_lo, packed);
  k_sort_global<<<(2*NSEG*16384)/256, 256, 0, stream>>>(packed, 16384u, 8192u);
  k_sort_local<<<2*NSEG*4, 1024, 0, stream>>>(packed, 16384u, 16384u);
  k_sort_global2<<<(2*NSEG*8192)/256, 256, 0, stream>>>(packed);
  k_sort_local<<<2*NSEG*4, 1024, 0, stream>>>(packed, 32768u, 32768u);

  k_attn<<<NSEG*NB, 512, 0, stream>>>(qpk, kpk, vbf, packed, o_acc, logit_acc);
  k_final<<<NPTS/256, 256, 0, stream>>>(x, o_acc, logit_acc, out_w, out_b,
                                        n2w, n2b, f1w, f1b, f2w, f2b, out);
}